// Round 7
// baseline (326.129 us; speedup 1.0000x reference)
//
#include <hip/hip_runtime.h>
#include <math.h>

#define N_NODES 10000
#define N_EDGES 160000
#define NEL 10
#define C 64
#define NB 8
#define SHD 9
#define MLPH 16
#define CSH 576
#define R_MAX 5.0f
#define INV_AVG 0.03125f
#define SCAN_CH 40    // 256*40 = 10240 >= N_NODES
#define GRID_MSG 1024
#define NW (GRID_MSG * 4)   // total waves in k_msg3

__device__ __forceinline__ float silu_f(float v) {
    return v / (1.0f + __expf(-v));
}

// lower_bound over rowptr[0..N_NODES] (clamped to N_NODES)
__device__ __forceinline__ int lbound_rp(const int* __restrict__ rp, int target) {
    int lo = 0, hi = N_NODES;
    while (lo < hi) { int mid = (lo + hi) >> 1; if (rp[mid] < target) lo = mid + 1; else hi = mid; }
    return lo;
}

// ---------------------------------------------------------------------------
// K1: per-edge geometry + radial basis, compact active edges, degree histo,
//     FUSED node embedding (grid 2500 = N*C/256; edge work on blocks < 625)
// ---------------------------------------------------------------------------
__global__ __launch_bounds__(256) void k_edge(
    const float* __restrict__ pos, const float* __restrict__ shifts,
    const int* __restrict__ ei,
    const float* __restrict__ na, const float* __restrict__ We,
    const float* __restrict__ ae,
    int* __restrict__ cnt, int* __restrict__ deg,
    int* __restrict__ act_snd, int* __restrict__ act_rcv,
    float* __restrict__ act_u, float* __restrict__ act_ef,
    float* __restrict__ h, float* __restrict__ out)
{
    int i = blockIdx.x * 256 + threadIdx.x;

    // ---- fused embed: h = na @ We ; out = na @ ae ----
    {
        int n = i >> 6, c = i & 63;
        float acc = 0.0f, e0 = 0.0f;
        #pragma unroll
        for (int k = 0; k < NEL; k++) {
            float a = na[n * NEL + k];
            acc += a * We[k * C + c];
            e0 += a * ae[k];
        }
        h[i] = acc;
        if (c == 0) out[n] = e0;
    }

    if (blockIdx.x >= N_EDGES / 256) return;
    int e = i;
    int snd = ei[e];
    int rcv = ei[N_EDGES + e];
    float vx = pos[rcv * 3 + 0] - pos[snd * 3 + 0] + shifts[e * 3 + 0];
    float vy = pos[rcv * 3 + 1] - pos[snd * 3 + 1] + shifts[e * 3 + 1];
    float vz = pos[rcv * 3 + 2] - pos[snd * 3 + 2] + shifts[e * 3 + 2];
    float r = sqrtf(vx * vx + vy * vy + vz * vz) + 1e-9f;
    float x = r / R_MAX;
    bool active = x < 1.0f;

    unsigned long long m = __ballot(active);
    int lane = threadIdx.x & 63;
    int base = 0;
    if (m) {
        int leader = __ffsll((unsigned long long)m) - 1;
        if (lane == leader) base = atomicAdd(cnt, __popcll(m));
        base = __shfl(base, leader);
    }
    if (!active) return;

    int p = base + __popcll(m & ((1ull << lane) - 1ull));
    act_snd[p] = snd;
    act_rcv[p] = rcv;
    atomicAdd(&deg[rcv], 1);

    float inv_r = 1.0f / r;
    float4 u4 = make_float4(vx * inv_r, vy * inv_r, vz * inv_r, r);
    *(float4*)&act_u[p * 4] = u4;

    // radial: bessel * polynomial cutoff (p=6)
    float x6 = x * x * x; x6 = x6 * x6;
    float x7 = x6 * x;
    float x8 = x7 * x;
    float fc = 1.0f - 28.0f * x6 + 48.0f * x7 - 21.0f * x8;
    float theta = 3.14159265358979323846f * r / R_MAX;
    float s1 = sinf(theta), c1 = cosf(theta);
    float sn = s1, cn = c1;
    float scale = 0.6324555320336759f * inv_r * fc;   // sqrt(2/R_MAX)/r*fc
    float ef[NB];
    ef[0] = scale * sn;
    #pragma unroll
    for (int n = 1; n < NB; n++) {
        float sn1 = sn * c1 + cn * s1;
        float cn1 = cn * c1 - sn * s1;
        sn = sn1; cn = cn1;
        ef[n] = scale * sn;
    }
    *(float4*)&act_ef[p * 8 + 0] = make_float4(ef[0], ef[1], ef[2], ef[3]);
    *(float4*)&act_ef[p * 8 + 4] = make_float4(ef[4], ef[5], ef[6], ef[7]);
}

// ---------------------------------------------------------------------------
// K1b: exclusive scan of deg -> rowptr + cursor  (single block)
// ---------------------------------------------------------------------------
__global__ __launch_bounds__(256) void k_scan(
    const int* __restrict__ deg, int* __restrict__ rowptr, int* __restrict__ cursor)
{
    __shared__ int part[256];
    int tid = threadIdx.x;
    int base = tid * SCAN_CH;
    int s = 0;
    for (int i = 0; i < SCAN_CH; i++) {
        int idx = base + i;
        if (idx < N_NODES) s += deg[idx];
    }
    part[tid] = s;
    __syncthreads();
    for (int off = 1; off < 256; off <<= 1) {
        int v = (tid >= off) ? part[tid - off] : 0;
        __syncthreads();
        part[tid] += v;
        __syncthreads();
    }
    int run = part[tid] - s;
    for (int i = 0; i < SCAN_CH; i++) {
        int idx = base + i;
        if (idx < N_NODES) {
            rowptr[idx] = run;
            cursor[idx] = run;
            run += deg[idx];
        }
    }
    if (tid == 255) rowptr[N_NODES] = part[255];
}

// ---------------------------------------------------------------------------
// K1c: permute into CSR order, computing sh + hid0/hid1 at the destination.
// Spare threads (i <= NW) precompute the per-wave node partition wstart[].
// ---------------------------------------------------------------------------
__global__ __launch_bounds__(256) void k_scatter(
    const int* __restrict__ cnt, const int* __restrict__ act_snd,
    const int* __restrict__ act_rcv, const float* __restrict__ act_u,
    const float* __restrict__ act_ef, const float* __restrict__ Wr1,
    const int* __restrict__ rowptr,
    int* __restrict__ cursor, int* __restrict__ wstart,
    int* __restrict__ csnd, int* __restrict__ crcv, float* __restrict__ csh,
    float* __restrict__ chid0, float* __restrict__ chid1)
{
    int i = blockIdx.x * 256 + threadIdx.x;
    int nAct = *cnt;

    // per-wave node partition for k_msg3
    if (i <= NW) {
        if (i == NW) {
            wstart[NW] = N_NODES;
        } else {
            int S = (nAct + NW - 1) / NW; if (S < 1) S = 1;
            wstart[i] = lbound_rp(rowptr, i * S);
        }
    }
    if (i >= nAct) return;

    int rcv = act_rcv[i];
    int pos = atomicAdd(&cursor[rcv], 1);
    csnd[pos] = act_snd[i];
    crcv[pos] = rcv;

    float4 u4 = *(const float4*)&act_u[i * 4];
    float ux = u4.x, uy = u4.y, uz = u4.z;
    const float s3 = 1.7320508075688772f;
    const float s5 = 2.23606797749979f;
    const float s15 = 3.872983346207417f;
    *(float4*)&csh[pos * 16 + 0] = make_float4(1.0f, s3 * ux, s3 * uy, s3 * uz);
    *(float4*)&csh[pos * 16 + 4] = make_float4(s15 * ux * uy, s15 * uy * uz,
                                               0.5f * s5 * (3.0f * uz * uz - 1.0f),
                                               s15 * ux * uz);
    csh[pos * 16 + 8] = 0.5f * s15 * (ux * ux - uy * uy);

    float4 e0 = *(const float4*)&act_ef[i * 8 + 0];
    float4 e1 = *(const float4*)&act_ef[i * 8 + 4];
    float ef[NB] = {e0.x, e0.y, e0.z, e0.w, e1.x, e1.y, e1.z, e1.w};

    #pragma unroll
    for (int t = 0; t < 2; t++) {
        float* dst = (t == 0) ? chid0 : chid1;
        const float* W = Wr1 + t * NB * MLPH;
        float hv[MLPH];
        #pragma unroll
        for (int mm = 0; mm < MLPH; mm++) {
            float acc = 0.0f;
            #pragma unroll
            for (int b = 0; b < NB; b++) acc += ef[b] * W[b * MLPH + mm];
            hv[mm] = silu_f(acc);
        }
        #pragma unroll
        for (int mq = 0; mq < MLPH; mq += 4)
            *(float4*)&dst[pos * 16 + mq] = make_float4(hv[mq], hv[mq+1], hv[mq+2], hv[mq+3]);
    }
}

// ---------------------------------------------------------------------------
// K3: h_up = h @ W_up[t]
// ---------------------------------------------------------------------------
__global__ __launch_bounds__(256) void k_up(
    const float* __restrict__ h, const float* __restrict__ Wup, float* __restrict__ hup)
{
    __shared__ float Wl[C * C];
    for (int i = threadIdx.x; i < C * C; i += 256) Wl[i] = Wup[i];
    __syncthreads();
    int o = threadIdx.x & 63, g = threadIdx.x >> 6;
    int n = blockIdx.x * 4 + g;
    const float* hr = h + n * C;
    float acc = 0.0f;
    #pragma unroll 8
    for (int c = 0; c < C; c++) acc += hr[c] * Wl[c * C + o];
    hup[n * C + o] = acc;
}

// ---------------------------------------------------------------------------
// K4 (hot): segmented-CSR message pass, ZERO atomics.
// Each wave exclusively owns nodes [wstart[w], wstart[w+1]); processes its
// contiguous edge range in 4-edge groups, accumulates same-receiver runs in
// registers, plain-stores each finished agg row, zero-fills deg-0 rows.
// ---------------------------------------------------------------------------
__global__ __launch_bounds__(256) void k_msg3(
    const int* __restrict__ rowptr, const int* __restrict__ wstart,
    const int* __restrict__ csnd, const int* __restrict__ crcv,
    const float* __restrict__ csh, const float* __restrict__ chid,
    const float* __restrict__ Wr2, const float* __restrict__ hup,
    float* __restrict__ agg)
{
    __shared__ float Wl[MLPH * CSH];   // 36 KB
    for (int i = threadIdx.x; i < MLPH * CSH; i += 256) Wl[i] = Wr2[i];
    __syncthreads();

    int lane = threadIdx.x & 63;
    int w = (blockIdx.x << 2) | (threadIdx.x >> 6);

    int nlo = wstart[w];
    int nhi = wstart[w + 1];
    if (nlo >= nhi) return;
    int beg = rowptr[nlo], end = rowptr[nhi];

    // lane's base (c,s) for jj=0:  j = lane -> c = j/9, s = j%9
    int c0 = lane / 9;
    int s0 = lane - c0 * 9;

    float acc[9];
    int curRcv = -1;

    for (int k0 = beg; k0 < end; k0 += 4) {
        int nv = end - k0; if (nv > 4) nv = 4;

        // packed hidden load: 4 edges x 16 hidden units across the wave
        int e = lane >> 4;
        float hidS = chid[(k0 + (e < nv ? e : nv - 1)) * 16 + (lane & 15)];

        float tw0[9], tw1[9], tw2[9], tw3[9];
        #pragma unroll
        for (int jj = 0; jj < 9; jj++) { tw0[jj] = 0.f; tw1[jj] = 0.f; tw2[jj] = 0.f; tw3[jj] = 0.f; }

        #pragma unroll
        for (int m = 0; m < MLPH; m++) {
            float hm0 = __shfl(hidS, m);
            float hm1 = __shfl(hidS, 16 + m);
            float hm2 = __shfl(hidS, 32 + m);
            float hm3 = __shfl(hidS, 48 + m);
            #pragma unroll
            for (int jj = 0; jj < 9; jj++) {
                float wv = Wl[m * CSH + lane + (jj << 6)];
                tw0[jj] += hm0 * wv;
                tw1[jj] += hm1 * wv;
                tw2[jj] += hm2 * wv;
                tw3[jj] += hm3 * wv;
            }
        }

        #pragma unroll
        for (int q = 0; q < 4; q++) {
            if (q < nv) {                      // wave-uniform
                int kq = k0 + q;
                int rcv = crcv[kq];
                int snd = csnd[kq];
                float hupS = hup[snd * C + lane];
                float shS = (lane < SHD) ? csh[kq * 16 + lane] : 0.0f;
                const float* tw = (q == 0) ? tw0 : (q == 1) ? tw1 : (q == 2) ? tw2 : tw3;
                if (rcv != curRcv) {
                    int zfrom;
                    if (curRcv >= 0) {
                        float* ag = agg + (size_t)curRcv * CSH + lane;
                        #pragma unroll
                        for (int jj = 0; jj < 9; jj++) ag[jj << 6] = acc[jj];
                        zfrom = curRcv + 1;
                    } else {
                        zfrom = nlo;
                    }
                    for (int n = zfrom; n < rcv; n++) {     // zero-fill deg-0 rows
                        float* ag = agg + (size_t)n * CSH + lane;
                        #pragma unroll
                        for (int jj = 0; jj < 9; jj++) ag[jj << 6] = 0.0f;
                    }
                    curRcv = rcv;
                    int cc = c0, ss = s0;
                    #pragma unroll
                    for (int jj = 0; jj < 9; jj++) {
                        float mult = __shfl(hupS, cc) * __shfl(shS, ss);
                        acc[jj] = tw[jj] * mult;
                        cc += 7; ss += 1;
                        if (ss >= 9) { ss -= 9; cc += 1; }
                    }
                } else {
                    int cc = c0, ss = s0;
                    #pragma unroll
                    for (int jj = 0; jj < 9; jj++) {
                        float mult = __shfl(hupS, cc) * __shfl(shS, ss);
                        acc[jj] += tw[jj] * mult;
                        cc += 7; ss += 1;
                        if (ss >= 9) { ss -= 9; cc += 1; }
                    }
                }
            }
        }
    }

    int zfrom = nlo;
    if (curRcv >= 0) {
        float* ag = agg + (size_t)curRcv * CSH + lane;
        #pragma unroll
        for (int jj = 0; jj < 9; jj++) ag[jj << 6] = acc[jj];
        zfrom = curRcv + 1;
    }
    for (int n = zfrom; n < nhi; n++) {
        float* ag = agg + (size_t)n * CSH + lane;
        #pragma unroll
        for (int jj = 0; jj < 9; jj++) ag[jj << 6] = 0.0f;
    }
}

// ---------------------------------------------------------------------------
// K5: h_new = (agg/32) @ W_mix[t] + h @ W_self[t], fused readout.
// Inner loops vectorized: ds_read_b128 on the LDS tiles.
// ---------------------------------------------------------------------------
template <int RMODE>
__global__ __launch_bounds__(256) void k_mix(
    const float* __restrict__ agg, const float* __restrict__ h,
    const float* __restrict__ Wmix, const float* __restrict__ Wself,
    float* __restrict__ hnew,
    const float* __restrict__ wread, const float* __restrict__ Wm1,
    const float* __restrict__ wm2, float* __restrict__ rep)
{
    __shared__ float Al[16 * CSH];   // 36 KB
    __shared__ float Hl[16 * C];     // 4 KB
    int nb = blockIdx.x * 16;
    for (int i = threadIdx.x; i < 16 * CSH; i += 256) Al[i] = agg[nb * CSH + i] * INV_AVG;
    for (int i = threadIdx.x; i < 16 * C; i += 256) Hl[i] = h[nb * C + i];
    __syncthreads();

    int o = threadIdx.x & 63, g = threadIdx.x >> 6;
    float acc[4] = {0.0f, 0.0f, 0.0f, 0.0f};
    for (int cs = 0; cs < CSH; cs += 4) {
        float w0 = Wmix[(cs + 0) * C + o];
        float w1 = Wmix[(cs + 1) * C + o];
        float w2 = Wmix[(cs + 2) * C + o];
        float w3 = Wmix[(cs + 3) * C + o];
        #pragma unroll
        for (int q = 0; q < 4; q++) {
            float4 av = *(const float4*)&Al[(g + 4 * q) * CSH + cs];
            acc[q] += av.x * w0 + av.y * w1 + av.z * w2 + av.w * w3;
        }
    }
    for (int c = 0; c < C; c += 4) {
        float w0 = Wself[(c + 0) * C + o];
        float w1 = Wself[(c + 1) * C + o];
        float w2 = Wself[(c + 2) * C + o];
        float w3 = Wself[(c + 3) * C + o];
        #pragma unroll
        for (int q = 0; q < 4; q++) {
            float4 hv = *(const float4*)&Hl[(g + 4 * q) * C + c];
            acc[q] += hv.x * w0 + hv.y * w1 + hv.z * w2 + hv.w * w3;
        }
    }
    #pragma unroll
    for (int q = 0; q < 4; q++) hnew[(nb + g + 4 * q) * C + o] = acc[q];

    if (RMODE == 0) {
        float wr = wread[o];
        #pragma unroll
        for (int q = 0; q < 4; q++) {
            float v = acc[q] * wr;
            #pragma unroll
            for (int off = 32; off; off >>= 1) v += __shfl_xor(v, off);
            if (o == 0) rep[nb + g + 4 * q] = v;
        }
    } else {
        __syncthreads();
        float* Hn = Al;   // reuse as [16][64]
        #pragma unroll
        for (int q = 0; q < 4; q++) Hn[(g + 4 * q) * C + o] = acc[q];
        __syncthreads();
        int nl = threadIdx.x >> 4;
        int m = threadIdx.x & 15;
        float a2 = 0.0f;
        #pragma unroll 16
        for (int c = 0; c < C; c++) a2 += Hn[nl * C + c] * Wm1[c * MLPH + m];
        float rv = silu_f(a2) * wm2[m];
        #pragma unroll
        for (int off = 8; off; off >>= 1) rv += __shfl_xor(rv, off);
        if (m == 0) rep[nb + nl] = rv;
    }
}

// ---------------------------------------------------------------------------
extern "C" void kernel_launch(void* const* d_in, const int* in_sizes, int n_in,
                              void* d_out, int out_size, void* d_ws, size_t ws_size,
                              hipStream_t stream) {
    const float* pos    = (const float*)d_in[0];
    const float* na     = (const float*)d_in[1];
    const float* shifts = (const float*)d_in[2];
    const int*   ei     = (const int*)d_in[3];
    const float* ae     = (const float*)d_in[4];
    const float* We     = (const float*)d_in[5];
    const float* Wup    = (const float*)d_in[6];
    const float* Wr1    = (const float*)d_in[7];
    const float* Wr2    = (const float*)d_in[8];
    const float* Wmix   = (const float*)d_in[9];
    const float* Wself  = (const float*)d_in[10];
    const float* wread  = (const float*)d_in[11];
    const float* Wm1    = (const float*)d_in[12];
    const float* wm2    = (const float*)d_in[13];
    float* out = (float*)d_out;

    char* ws = (char*)d_ws;
    size_t off = 0;
    auto alloc = [&](size_t bytes) {
        off = (off + 255) & ~(size_t)255;
        void* p = ws + off;
        off += bytes;
        return p;
    };
    int*   cnt     = (int*)alloc(4);
    int*   deg     = (int*)alloc((size_t)N_NODES * 4);
    int*   rowptr  = (int*)alloc((size_t)(N_NODES + 1) * 4);
    int*   cursor  = (int*)alloc((size_t)N_NODES * 4);
    int*   wstart  = (int*)alloc((size_t)(NW + 1) * 4);
    int*   act_snd = (int*)alloc((size_t)N_EDGES * 4);
    int*   act_rcv = (int*)alloc((size_t)N_EDGES * 4);
    float* act_u   = (float*)alloc((size_t)N_EDGES * 4 * 4);
    float* act_ef  = (float*)alloc((size_t)N_EDGES * 8 * 4);
    int*   csnd    = (int*)alloc((size_t)N_EDGES * 4);
    int*   crcv    = (int*)alloc((size_t)N_EDGES * 4);
    float* csh     = (float*)alloc((size_t)N_EDGES * 16 * 4);
    float* chid0   = (float*)alloc((size_t)N_EDGES * 16 * 4);
    float* chid1   = (float*)alloc((size_t)N_EDGES * 16 * 4);
    float* hA      = (float*)alloc((size_t)N_NODES * C * 4);
    float* hB      = (float*)alloc((size_t)N_NODES * C * 4);
    float* hup     = (float*)alloc((size_t)N_NODES * C * 4);
    float* agg     = (float*)alloc((size_t)N_NODES * CSH * 4);

    hipMemsetAsync(cnt, 0, 4, stream);
    hipMemsetAsync(deg, 0, (size_t)N_NODES * 4, stream);

    k_edge<<<(N_NODES * C) / 256, 256, 0, stream>>>(pos, shifts, ei, na, We, ae,
                                                    cnt, deg, act_snd, act_rcv,
                                                    act_u, act_ef, hA, out);
    k_scan<<<1, 256, 0, stream>>>(deg, rowptr, cursor);
    k_scatter<<<N_EDGES / 256, 256, 0, stream>>>(cnt, act_snd, act_rcv, act_u,
                                                 act_ef, Wr1, rowptr, cursor, wstart,
                                                 csnd, crcv, csh, chid0, chid1);

    // ---- layer t = 0 ----
    k_up<<<N_NODES / 4, 256, 0, stream>>>(hA, Wup, hup);
    k_msg3<<<GRID_MSG, 256, 0, stream>>>(rowptr, wstart, csnd, crcv, csh,
                                         chid0, Wr2, hup, agg);
    k_mix<0><<<N_NODES / 16, 256, 0, stream>>>(agg, hA, Wmix, Wself, hB,
                                               wread, Wm1, wm2, out + N_NODES);

    // ---- layer t = 1 ----
    k_up<<<N_NODES / 4, 256, 0, stream>>>(hB, Wup + C * C, hup);
    k_msg3<<<GRID_MSG, 256, 0, stream>>>(rowptr, wstart, csnd, crcv, csh,
                                         chid1, Wr2 + MLPH * CSH, hup, agg);
    k_mix<1><<<N_NODES / 16, 256, 0, stream>>>(agg, hB, Wmix + C * SHD * C,
                                               Wself + C * C, hA,
                                               wread, Wm1, wm2, out + 2 * N_NODES);
}

// Round 8
// 287.063 us; speedup vs baseline: 1.1361x; 1.1361x over previous
//
#include <hip/hip_runtime.h>
#include <math.h>

#define N_NODES 10000
#define N_EDGES 160000
#define NEL 10
#define C 64
#define NB 8
#define SHD 9
#define MLPH 16
#define CSH 576
#define R_MAX 5.0f
#define INV_AVG 0.03125f
#define SCAN_CH 40     // 256*40 = 10240 >= N_NODES
#define GRID_MSG 512   // 2 blocks/CU resident (36KB LDS)
#define NWAVES (GRID_MSG * 4)

__device__ __forceinline__ float silu_f(float v) {
    return v / (1.0f + __expf(-v));
}

// lower_bound over rowptr[0..N_NODES]
__device__ __forceinline__ int lbound_rp(const int* __restrict__ rp, int target) {
    int lo = 0, hi = N_NODES;
    while (lo < hi) { int mid = (lo + hi) >> 1; if (rp[mid] < target) lo = mid + 1; else hi = mid; }
    return lo;
}

// ---------------------------------------------------------------------------
// K1: per-edge geometry + radial basis, compact active edges, degree histo,
//     FUSED node embedding (grid 2500 = N*C/256; edge work on blocks < 625)
// ---------------------------------------------------------------------------
__global__ __launch_bounds__(256) void k_edge(
    const float* __restrict__ pos, const float* __restrict__ shifts,
    const int* __restrict__ ei,
    const float* __restrict__ na, const float* __restrict__ We,
    const float* __restrict__ ae,
    int* __restrict__ cnt, int* __restrict__ deg,
    int* __restrict__ act_snd, int* __restrict__ act_rcv,
    float* __restrict__ act_u, float* __restrict__ act_ef,
    float* __restrict__ h, float* __restrict__ out)
{
    int i = blockIdx.x * 256 + threadIdx.x;

    // ---- fused embed: h = na @ We ; out = na @ ae ----
    {
        int n = i >> 6, c = i & 63;
        float acc = 0.0f, e0 = 0.0f;
        #pragma unroll
        for (int k = 0; k < NEL; k++) {
            float a = na[n * NEL + k];
            acc += a * We[k * C + c];
            e0 += a * ae[k];
        }
        h[i] = acc;
        if (c == 0) out[n] = e0;
    }

    if (blockIdx.x >= N_EDGES / 256) return;
    int e = i;
    int snd = ei[e];
    int rcv = ei[N_EDGES + e];
    float vx = pos[rcv * 3 + 0] - pos[snd * 3 + 0] + shifts[e * 3 + 0];
    float vy = pos[rcv * 3 + 1] - pos[snd * 3 + 1] + shifts[e * 3 + 1];
    float vz = pos[rcv * 3 + 2] - pos[snd * 3 + 2] + shifts[e * 3 + 2];
    float r = sqrtf(vx * vx + vy * vy + vz * vz) + 1e-9f;
    float x = r / R_MAX;
    bool active = x < 1.0f;

    unsigned long long m = __ballot(active);
    int lane = threadIdx.x & 63;
    int base = 0;
    if (m) {
        int leader = __ffsll((unsigned long long)m) - 1;
        if (lane == leader) base = atomicAdd(cnt, __popcll(m));
        base = __shfl(base, leader);
    }
    if (!active) return;

    int p = base + __popcll(m & ((1ull << lane) - 1ull));
    act_snd[p] = snd;
    act_rcv[p] = rcv;
    atomicAdd(&deg[rcv], 1);

    float inv_r = 1.0f / r;
    float4 u4 = make_float4(vx * inv_r, vy * inv_r, vz * inv_r, r);
    *(float4*)&act_u[p * 4] = u4;

    // radial: bessel * polynomial cutoff (p=6)
    float x6 = x * x * x; x6 = x6 * x6;
    float x7 = x6 * x;
    float x8 = x7 * x;
    float fc = 1.0f - 28.0f * x6 + 48.0f * x7 - 21.0f * x8;
    float theta = 3.14159265358979323846f * r / R_MAX;
    float s1 = sinf(theta), c1 = cosf(theta);
    float sn = s1, cn = c1;
    float scale = 0.6324555320336759f * inv_r * fc;   // sqrt(2/R_MAX)/r*fc
    float ef[NB];
    ef[0] = scale * sn;
    #pragma unroll
    for (int n = 1; n < NB; n++) {
        float sn1 = sn * c1 + cn * s1;
        float cn1 = cn * c1 - sn * s1;
        sn = sn1; cn = cn1;
        ef[n] = scale * sn;
    }
    *(float4*)&act_ef[p * 8 + 0] = make_float4(ef[0], ef[1], ef[2], ef[3]);
    *(float4*)&act_ef[p * 8 + 4] = make_float4(ef[4], ef[5], ef[6], ef[7]);
}

// ---------------------------------------------------------------------------
// K1b: exclusive scan of deg -> rowptr + cursor  (single block)
// ---------------------------------------------------------------------------
__global__ __launch_bounds__(256) void k_scan(
    const int* __restrict__ deg, int* __restrict__ rowptr, int* __restrict__ cursor)
{
    __shared__ int part[256];
    int tid = threadIdx.x;
    int base = tid * SCAN_CH;
    int s = 0;
    for (int i = 0; i < SCAN_CH; i++) {
        int idx = base + i;
        if (idx < N_NODES) s += deg[idx];
    }
    part[tid] = s;
    __syncthreads();
    for (int off = 1; off < 256; off <<= 1) {
        int v = (tid >= off) ? part[tid - off] : 0;
        __syncthreads();
        part[tid] += v;
        __syncthreads();
    }
    int run = part[tid] - s;
    for (int i = 0; i < SCAN_CH; i++) {
        int idx = base + i;
        if (idx < N_NODES) {
            rowptr[idx] = run;
            cursor[idx] = run;
            run += deg[idx];
        }
    }
    if (tid == 255) rowptr[N_NODES] = part[255];
}

// ---------------------------------------------------------------------------
// K1c: permute into CSR order (sh + hid at destination); spare threads build
// the per-wave node partition wstart[] and the s-major-permuted Wr2 (wlt).
// ---------------------------------------------------------------------------
__global__ __launch_bounds__(256) void k_scatter(
    const int* __restrict__ cnt, const int* __restrict__ act_snd,
    const int* __restrict__ act_rcv, const float* __restrict__ act_u,
    const float* __restrict__ act_ef, const float* __restrict__ Wr1,
    const float* __restrict__ Wr2, const int* __restrict__ rowptr,
    int* __restrict__ cursor, int* __restrict__ wstart, float* __restrict__ wlt,
    int* __restrict__ csnd, int* __restrict__ crcv, float* __restrict__ csh,
    float* __restrict__ chid0, float* __restrict__ chid1)
{
    int i = blockIdx.x * 256 + threadIdx.x;
    int nAct = *cnt;

    // per-wave node partition for k_msg4
    if (i <= NWAVES) {
        if (i == NWAVES) {
            wstart[NWAVES] = N_NODES;
        } else {
            int S = (nAct + NWAVES - 1) / NWAVES; if (S < 1) S = 1;
            wstart[i] = lbound_rp(rowptr, i * S);
        }
    }
    // s-major permute of Wr2 (both layers): wlt[t][m*576 + s*64 + c]
    {
        const int W0 = N_EDGES - 2 * MLPH * CSH;
        if (i >= W0) {
            int idx = i - W0;                 // 0 .. 18431
            int t = idx / (MLPH * CSH);
            int r = idx - t * (MLPH * CSH);
            int m = r / CSH, j = r - m * CSH;
            int c = j & 63, s = j >> 6;
            wlt[idx] = Wr2[t * MLPH * CSH + m * CSH + c * SHD + s];
        }
    }
    if (i >= nAct) return;

    int rcv = act_rcv[i];
    int pos = atomicAdd(&cursor[rcv], 1);
    csnd[pos] = act_snd[i];
    crcv[pos] = rcv;

    float4 u4 = *(const float4*)&act_u[i * 4];
    float ux = u4.x, uy = u4.y, uz = u4.z;
    const float s3 = 1.7320508075688772f;
    const float s5 = 2.23606797749979f;
    const float s15 = 3.872983346207417f;
    *(float4*)&csh[pos * 16 + 0] = make_float4(1.0f, s3 * ux, s3 * uy, s3 * uz);
    *(float4*)&csh[pos * 16 + 4] = make_float4(s15 * ux * uy, s15 * uy * uz,
                                               0.5f * s5 * (3.0f * uz * uz - 1.0f),
                                               s15 * ux * uz);
    csh[pos * 16 + 8] = 0.5f * s15 * (ux * ux - uy * uy);

    float4 e0 = *(const float4*)&act_ef[i * 8 + 0];
    float4 e1 = *(const float4*)&act_ef[i * 8 + 4];
    float ef[NB] = {e0.x, e0.y, e0.z, e0.w, e1.x, e1.y, e1.z, e1.w};

    #pragma unroll
    for (int t = 0; t < 2; t++) {
        float* dst = (t == 0) ? chid0 : chid1;
        const float* W = Wr1 + t * NB * MLPH;
        float hv[MLPH];
        #pragma unroll
        for (int mm = 0; mm < MLPH; mm++) {
            float acc = 0.0f;
            #pragma unroll
            for (int b = 0; b < NB; b++) acc += ef[b] * W[b * MLPH + mm];
            hv[mm] = silu_f(acc);
        }
        #pragma unroll
        for (int mq = 0; mq < MLPH; mq += 4)
            *(float4*)&dst[pos * 16 + mq] = make_float4(hv[mq], hv[mq+1], hv[mq+2], hv[mq+3]);
    }
}

// ---------------------------------------------------------------------------
// K3: h_up = h @ W_up[t]
// ---------------------------------------------------------------------------
__global__ __launch_bounds__(256) void k_up(
    const float* __restrict__ h, const float* __restrict__ Wup, float* __restrict__ hup)
{
    __shared__ float Wl[C * C];
    for (int i = threadIdx.x; i < C * C; i += 256) Wl[i] = Wup[i];
    __syncthreads();
    int o = threadIdx.x & 63, g = threadIdx.x >> 6;
    int n = blockIdx.x * 4 + g;
    const float* hr = h + n * C;
    float acc = 0.0f;
    #pragma unroll 8
    for (int c = 0; c < C; c++) acc += hr[c] * Wl[c * C + o];
    hup[n * C + o] = acc;
}

// ---------------------------------------------------------------------------
// K4 (hot): segmented-CSR message pass, ZERO atomics, ZERO shuffles.
// s-major output layout: j = s*64 + c  =>  lane = c, jj = s.
//   mult = hup[snd][lane] * sh[e][jj]   (lane-local x wave-uniform broadcast)
// W staged in LDS m-major [m][j]: stride-1 conflict-free b32 reads, shared
// across 8-edge groups. Each wave owns nodes [wstart[w], wstart[w+1]).
// ---------------------------------------------------------------------------
__global__ __launch_bounds__(256) void k_msg4(
    const int* __restrict__ rowptr, const int* __restrict__ wstart,
    const int* __restrict__ csnd, const int* __restrict__ crcv,
    const float* __restrict__ csh, const float* __restrict__ chid,
    const float* __restrict__ wlt, const float* __restrict__ hup,
    float* __restrict__ agg)
{
    __shared__ float Wl[MLPH * CSH];   // 36 KB, [m][j] s-major j
    for (int i = threadIdx.x; i < MLPH * CSH; i += 256) Wl[i] = wlt[i];
    __syncthreads();

    int lane = threadIdx.x & 63;
    int w = (blockIdx.x << 2) | (threadIdx.x >> 6);
    int nlo = wstart[w];
    int nhi = wstart[w + 1];
    if (nlo >= nhi) return;
    int beg = rowptr[nlo], end = rowptr[nhi];

    const float4* ch = (const float4*)chid;

    float acc[9];
    int curRcv = -1;

#define FLUSH() { float* ag = agg + (size_t)curRcv * CSH + lane; \
    _Pragma("unroll") for (int jj = 0; jj < 9; jj++) ag[jj << 6] = acc[jj]; }
#define ZFILL(FROM, TO) for (int zn = (FROM); zn < (TO); zn++) { \
    float* ag = agg + (size_t)zn * CSH + lane; \
    _Pragma("unroll") for (int jj = 0; jj < 9; jj++) ag[jj << 6] = 0.0f; }

    for (int k0 = beg; k0 < end; k0 += 8) {
        int nv = end - k0; if (nv > 8) nv = 8;

        // hoisted per-edge metadata (8 independent load chains)
#define PRE(Q) int kc##Q = (k0 + Q < end) ? k0 + Q : end - 1; \
        int rcvq##Q = crcv[kc##Q]; \
        float hupq##Q = hup[csnd[kc##Q] * C + lane];
        PRE(0) PRE(1) PRE(2) PRE(3) PRE(4) PRE(5) PRE(6) PRE(7)
#undef PRE

        float tw0[9], tw1[9], tw2[9], tw3[9], tw4[9], tw5[9], tw6[9], tw7[9];
        #pragma unroll
        for (int jj = 0; jj < 9; jj++) {
            tw0[jj] = 0.f; tw1[jj] = 0.f; tw2[jj] = 0.f; tw3[jj] = 0.f;
            tw4[jj] = 0.f; tw5[jj] = 0.f; tw6[jj] = 0.f; tw7[jj] = 0.f;
        }

        #pragma unroll
        for (int mq = 0; mq < 4; mq++) {
            // broadcast hid quads (uniform address per edge)
            float4 h0 = ch[kc0 * 4 + mq], h1 = ch[kc1 * 4 + mq];
            float4 h2 = ch[kc2 * 4 + mq], h3 = ch[kc3 * 4 + mq];
            float4 h4 = ch[kc4 * 4 + mq], h5 = ch[kc5 * 4 + mq];
            float4 h6 = ch[kc6 * 4 + mq], h7 = ch[kc7 * 4 + mq];
            #pragma unroll
            for (int jj = 0; jj < 9; jj++) {
                const float* wp = &Wl[(mq * 4) * CSH + (jj << 6) + lane];
                float w0 = wp[0], w1 = wp[CSH], w2 = wp[2 * CSH], w3 = wp[3 * CSH];
                tw0[jj] += h0.x * w0 + h0.y * w1 + h0.z * w2 + h0.w * w3;
                tw1[jj] += h1.x * w0 + h1.y * w1 + h1.z * w2 + h1.w * w3;
                tw2[jj] += h2.x * w0 + h2.y * w1 + h2.z * w2 + h2.w * w3;
                tw3[jj] += h3.x * w0 + h3.y * w1 + h3.z * w2 + h3.w * w3;
                tw4[jj] += h4.x * w0 + h4.y * w1 + h4.z * w2 + h4.w * w3;
                tw5[jj] += h5.x * w0 + h5.y * w1 + h5.z * w2 + h5.w * w3;
                tw6[jj] += h6.x * w0 + h6.y * w1 + h6.z * w2 + h6.w * w3;
                tw7[jj] += h7.x * w0 + h7.y * w1 + h7.z * w2 + h7.w * w3;
            }
        }

#define SCAT(Q) if (Q < nv) { \
        int rcv = rcvq##Q; \
        float hupS = hupq##Q; \
        float4 sA = *(const float4*)&csh[kc##Q * 16]; \
        float4 sB = *(const float4*)&csh[kc##Q * 16 + 4]; \
        float s8v = csh[kc##Q * 16 + 8]; \
        float sh9[9] = {sA.x, sA.y, sA.z, sA.w, sB.x, sB.y, sB.z, sB.w, s8v}; \
        if (rcv != curRcv) { \
            if (curRcv >= 0) { FLUSH(); ZFILL(curRcv + 1, rcv) } else { ZFILL(nlo, rcv) } \
            curRcv = rcv; \
            _Pragma("unroll") for (int jj = 0; jj < 9; jj++) acc[jj] = tw##Q[jj] * (hupS * sh9[jj]); \
        } else { \
            _Pragma("unroll") for (int jj = 0; jj < 9; jj++) acc[jj] += tw##Q[jj] * (hupS * sh9[jj]); \
        } }
        SCAT(0) SCAT(1) SCAT(2) SCAT(3) SCAT(4) SCAT(5) SCAT(6) SCAT(7)
#undef SCAT
    }

    int zfrom = nlo;
    if (curRcv >= 0) { FLUSH(); zfrom = curRcv + 1; }
    ZFILL(zfrom, nhi)
#undef FLUSH
#undef ZFILL
}

// ---------------------------------------------------------------------------
// K5: h_new = (agg/32) @ W_mix[t] + h @ W_self[t], fused readout.
// agg is s-major (j = s*64+c); Wmix row index permuted (wave-uniform).
// ---------------------------------------------------------------------------
template <int RMODE>
__global__ __launch_bounds__(256) void k_mix(
    const float* __restrict__ agg, const float* __restrict__ h,
    const float* __restrict__ Wmix, const float* __restrict__ Wself,
    float* __restrict__ hnew,
    const float* __restrict__ wread, const float* __restrict__ Wm1,
    const float* __restrict__ wm2, float* __restrict__ rep)
{
    __shared__ float Al[16 * CSH];   // 36 KB
    __shared__ float Hl[16 * C];     // 4 KB
    int nb = blockIdx.x * 16;
    for (int i = threadIdx.x; i < 16 * CSH; i += 256) Al[i] = agg[nb * CSH + i] * INV_AVG;
    for (int i = threadIdx.x; i < 16 * C; i += 256) Hl[i] = h[nb * C + i];
    __syncthreads();

    int o = threadIdx.x & 63, g = threadIdx.x >> 6;
    float acc[4] = {0.0f, 0.0f, 0.0f, 0.0f};
    for (int cs = 0; cs < CSH; cs += 4) {
        int cb = cs & 63, s = cs >> 6;
        float w0 = Wmix[((cb + 0) * SHD + s) * C + o];
        float w1 = Wmix[((cb + 1) * SHD + s) * C + o];
        float w2 = Wmix[((cb + 2) * SHD + s) * C + o];
        float w3 = Wmix[((cb + 3) * SHD + s) * C + o];
        #pragma unroll
        for (int q = 0; q < 4; q++) {
            float4 av = *(const float4*)&Al[(g + 4 * q) * CSH + cs];
            acc[q] += av.x * w0 + av.y * w1 + av.z * w2 + av.w * w3;
        }
    }
    for (int c = 0; c < C; c += 4) {
        float w0 = Wself[(c + 0) * C + o];
        float w1 = Wself[(c + 1) * C + o];
        float w2 = Wself[(c + 2) * C + o];
        float w3 = Wself[(c + 3) * C + o];
        #pragma unroll
        for (int q = 0; q < 4; q++) {
            float4 hv = *(const float4*)&Hl[(g + 4 * q) * C + c];
            acc[q] += hv.x * w0 + hv.y * w1 + hv.z * w2 + hv.w * w3;
        }
    }
    #pragma unroll
    for (int q = 0; q < 4; q++) hnew[(nb + g + 4 * q) * C + o] = acc[q];

    if (RMODE == 0) {
        float wr = wread[o];
        #pragma unroll
        for (int q = 0; q < 4; q++) {
            float v = acc[q] * wr;
            #pragma unroll
            for (int off = 32; off; off >>= 1) v += __shfl_xor(v, off);
            if (o == 0) rep[nb + g + 4 * q] = v;
        }
    } else {
        __syncthreads();
        float* Hn = Al;   // reuse as [16][64]
        #pragma unroll
        for (int q = 0; q < 4; q++) Hn[(g + 4 * q) * C + o] = acc[q];
        __syncthreads();
        int nl = threadIdx.x >> 4;
        int m = threadIdx.x & 15;
        float a2 = 0.0f;
        #pragma unroll 16
        for (int c = 0; c < C; c++) a2 += Hn[nl * C + c] * Wm1[c * MLPH + m];
        float rv = silu_f(a2) * wm2[m];
        #pragma unroll
        for (int off = 8; off; off >>= 1) rv += __shfl_xor(rv, off);
        if (m == 0) rep[nb + nl] = rv;
    }
}

// ---------------------------------------------------------------------------
extern "C" void kernel_launch(void* const* d_in, const int* in_sizes, int n_in,
                              void* d_out, int out_size, void* d_ws, size_t ws_size,
                              hipStream_t stream) {
    const float* pos    = (const float*)d_in[0];
    const float* na     = (const float*)d_in[1];
    const float* shifts = (const float*)d_in[2];
    const int*   ei     = (const int*)d_in[3];
    const float* ae     = (const float*)d_in[4];
    const float* We     = (const float*)d_in[5];
    const float* Wup    = (const float*)d_in[6];
    const float* Wr1    = (const float*)d_in[7];
    const float* Wr2    = (const float*)d_in[8];
    const float* Wmix   = (const float*)d_in[9];
    const float* Wself  = (const float*)d_in[10];
    const float* wread  = (const float*)d_in[11];
    const float* Wm1    = (const float*)d_in[12];
    const float* wm2    = (const float*)d_in[13];
    float* out = (float*)d_out;

    char* ws = (char*)d_ws;
    size_t off = 0;
    auto alloc = [&](size_t bytes) {
        off = (off + 255) & ~(size_t)255;
        void* p = ws + off;
        off += bytes;
        return p;
    };
    int*   cnt     = (int*)alloc(4);
    int*   deg     = (int*)alloc((size_t)N_NODES * 4);
    int*   rowptr  = (int*)alloc((size_t)(N_NODES + 1) * 4);
    int*   cursor  = (int*)alloc((size_t)N_NODES * 4);
    int*   wstart  = (int*)alloc((size_t)(NWAVES + 1) * 4);
    float* wlt     = (float*)alloc((size_t)2 * MLPH * CSH * 4);
    int*   act_snd = (int*)alloc((size_t)N_EDGES * 4);
    int*   act_rcv = (int*)alloc((size_t)N_EDGES * 4);
    float* act_u   = (float*)alloc((size_t)N_EDGES * 4 * 4);
    float* act_ef  = (float*)alloc((size_t)N_EDGES * 8 * 4);
    int*   csnd    = (int*)alloc((size_t)N_EDGES * 4);
    int*   crcv    = (int*)alloc((size_t)N_EDGES * 4);
    float* csh     = (float*)alloc((size_t)N_EDGES * 16 * 4);
    float* chid0   = (float*)alloc((size_t)N_EDGES * 16 * 4);
    float* chid1   = (float*)alloc((size_t)N_EDGES * 16 * 4);
    float* hA      = (float*)alloc((size_t)N_NODES * C * 4);
    float* hB      = (float*)alloc((size_t)N_NODES * C * 4);
    float* hup     = (float*)alloc((size_t)N_NODES * C * 4);
    float* agg     = (float*)alloc((size_t)N_NODES * CSH * 4);

    hipMemsetAsync(cnt, 0, 4, stream);
    hipMemsetAsync(deg, 0, (size_t)N_NODES * 4, stream);

    k_edge<<<(N_NODES * C) / 256, 256, 0, stream>>>(pos, shifts, ei, na, We, ae,
                                                    cnt, deg, act_snd, act_rcv,
                                                    act_u, act_ef, hA, out);
    k_scan<<<1, 256, 0, stream>>>(deg, rowptr, cursor);
    k_scatter<<<N_EDGES / 256, 256, 0, stream>>>(cnt, act_snd, act_rcv, act_u,
                                                 act_ef, Wr1, Wr2, rowptr,
                                                 cursor, wstart, wlt,
                                                 csnd, crcv, csh, chid0, chid1);

    // ---- layer t = 0 ----
    k_up<<<N_NODES / 4, 256, 0, stream>>>(hA, Wup, hup);
    k_msg4<<<GRID_MSG, 256, 0, stream>>>(rowptr, wstart, csnd, crcv, csh,
                                         chid0, wlt, hup, agg);
    k_mix<0><<<N_NODES / 16, 256, 0, stream>>>(agg, hA, Wmix, Wself, hB,
                                               wread, Wm1, wm2, out + N_NODES);

    // ---- layer t = 1 ----
    k_up<<<N_NODES / 4, 256, 0, stream>>>(hB, Wup + C * C, hup);
    k_msg4<<<GRID_MSG, 256, 0, stream>>>(rowptr, wstart, csnd, crcv, csh,
                                         chid1, wlt + MLPH * CSH, hup, agg);
    k_mix<1><<<N_NODES / 16, 256, 0, stream>>>(agg, hB, Wmix + C * SHD * C,
                                               Wself + C * C, hA,
                                               wread, Wm1, wm2, out + 2 * N_NODES);
}

// Round 9
// 223.053 us; speedup vs baseline: 1.4621x; 1.2870x over previous
//
#include <hip/hip_runtime.h>
#include <math.h>

#define N_NODES 10000
#define N_EDGES 160000
#define NEL 10
#define C 64
#define NB 8
#define SHD 9
#define MLPH 16
#define CSH 576
#define R_MAX 5.0f
#define INV_AVG 0.03125f
#define SCAN_CH 40     // 256*40 = 10240 >= N_NODES
#define GRID_MSG 1024  // 4 blocks/CU (18KB LDS)
#define NWAVES (GRID_MSG * 4)
#define WBASE (N_EDGES - 2 * 8 * CSH)   // side-job region in k_rank

typedef _Float16 f16x2 __attribute__((ext_vector_type(2)));

__device__ __forceinline__ float silu_f(float v) {
    return v / (1.0f + __expf(-v));
}

__device__ __forceinline__ float dot2f(f16x2 a, f16x2 b, float c) {
#if __has_builtin(__builtin_amdgcn_fdot2)
    return __builtin_amdgcn_fdot2(a, b, c, false);
#else
    return c + (float)a.x * (float)b.x + (float)a.y * (float)b.y;
#endif
}

// lower_bound over rowptr[0..N_NODES]
__device__ __forceinline__ int lbound_rp(const int* __restrict__ rp, int target) {
    int lo = 0, hi = N_NODES;
    while (lo < hi) { int mid = (lo + hi) >> 1; if (rp[mid] < target) lo = mid + 1; else hi = mid; }
    return lo;
}

// ---------------------------------------------------------------------------
// K1: per-edge geometry + radial basis, compact active edges, degree histo,
//     FUSED node embedding (grid 2500; edge work on blocks < 625)
// ---------------------------------------------------------------------------
__global__ __launch_bounds__(256) void k_edge(
    const float* __restrict__ pos, const float* __restrict__ shifts,
    const int* __restrict__ ei,
    const float* __restrict__ na, const float* __restrict__ We,
    const float* __restrict__ ae,
    int* __restrict__ cnt, int* __restrict__ deg,
    int* __restrict__ act_snd, int* __restrict__ act_rcv,
    float* __restrict__ act_u, float* __restrict__ act_ef,
    float* __restrict__ h, float* __restrict__ out)
{
    int i = blockIdx.x * 256 + threadIdx.x;

    // ---- fused embed: h = na @ We ; out = na @ ae ----
    {
        int n = i >> 6, c = i & 63;
        float acc = 0.0f, e0 = 0.0f;
        #pragma unroll
        for (int k = 0; k < NEL; k++) {
            float a = na[n * NEL + k];
            acc += a * We[k * C + c];
            e0 += a * ae[k];
        }
        h[i] = acc;
        if (c == 0) out[n] = e0;
    }

    if (blockIdx.x >= N_EDGES / 256) return;
    int e = i;
    int snd = ei[e];
    int rcv = ei[N_EDGES + e];
    float vx = pos[rcv * 3 + 0] - pos[snd * 3 + 0] + shifts[e * 3 + 0];
    float vy = pos[rcv * 3 + 1] - pos[snd * 3 + 1] + shifts[e * 3 + 1];
    float vz = pos[rcv * 3 + 2] - pos[snd * 3 + 2] + shifts[e * 3 + 2];
    float r = sqrtf(vx * vx + vy * vy + vz * vz) + 1e-9f;
    float x = r / R_MAX;
    bool active = x < 1.0f;

    unsigned long long m = __ballot(active);
    int lane = threadIdx.x & 63;
    int base = 0;
    if (m) {
        int leader = __ffsll((unsigned long long)m) - 1;
        if (lane == leader) base = atomicAdd(cnt, __popcll(m));
        base = __shfl(base, leader);
    }
    if (!active) return;

    int p = base + __popcll(m & ((1ull << lane) - 1ull));
    act_snd[p] = snd;
    act_rcv[p] = rcv;
    atomicAdd(&deg[rcv], 1);

    float inv_r = 1.0f / r;
    *(float4*)&act_u[p * 4] = make_float4(vx * inv_r, vy * inv_r, vz * inv_r, r);

    // radial: bessel * polynomial cutoff (p=6)
    float x6 = x * x * x; x6 = x6 * x6;
    float x7 = x6 * x;
    float x8 = x7 * x;
    float fc = 1.0f - 28.0f * x6 + 48.0f * x7 - 21.0f * x8;
    float theta = 3.14159265358979323846f * r / R_MAX;
    float s1 = sinf(theta), c1 = cosf(theta);
    float sn = s1, cn = c1;
    float scale = 0.6324555320336759f * inv_r * fc;   // sqrt(2/R_MAX)/r*fc
    float ef[NB];
    ef[0] = scale * sn;
    #pragma unroll
    for (int n = 1; n < NB; n++) {
        float sn1 = sn * c1 + cn * s1;
        float cn1 = cn * c1 - sn * s1;
        sn = sn1; cn = cn1;
        ef[n] = scale * sn;
    }
    *(float4*)&act_ef[p * 8 + 0] = make_float4(ef[0], ef[1], ef[2], ef[3]);
    *(float4*)&act_ef[p * 8 + 4] = make_float4(ef[4], ef[5], ef[6], ef[7]);
}

// ---------------------------------------------------------------------------
// K1b: exclusive scan of deg -> rowptr + cursor (single block, LDS-staged,
// all global traffic coalesced)
// ---------------------------------------------------------------------------
__global__ __launch_bounds__(256) void k_scan(
    const int* __restrict__ deg, int* __restrict__ rowptr, int* __restrict__ cursor)
{
    __shared__ int dl[N_NODES];   // 40 KB
    __shared__ int part[256];
    int tid = threadIdx.x;
    for (int i = tid; i < N_NODES; i += 256) dl[i] = deg[i];
    __syncthreads();

    int base = tid * SCAN_CH;
    int s = 0;
    #pragma unroll 8
    for (int i = 0; i < SCAN_CH; i++) {
        int idx = base + i;
        if (idx < N_NODES) s += dl[idx];
    }
    part[tid] = s;
    __syncthreads();
    for (int off = 1; off < 256; off <<= 1) {
        int v = (tid >= off) ? part[tid - off] : 0;
        __syncthreads();
        part[tid] += v;
        __syncthreads();
    }
    int run = part[tid] - s;
    for (int i = 0; i < SCAN_CH; i++) {
        int idx = base + i;
        if (idx < N_NODES) {
            int v = dl[idx];
            dl[idx] = run;
            run += v;
        }
    }
    __syncthreads();
    for (int i = tid; i < N_NODES; i += 256) {
        int r = dl[i];
        rowptr[i] = r;
        cursor[i] = r;
    }
    if (tid == 255) rowptr[N_NODES] = part[255];
}

// ---------------------------------------------------------------------------
// K1c: rank edges into CSR order (4B scatter only) + side jobs:
//  - wstart[] per-wave node partition
//  - wlth: s-major, m-paired, f16x2-packed Wr2 (both layers)
// ---------------------------------------------------------------------------
__global__ __launch_bounds__(256) void k_rank(
    const int* __restrict__ cnt, const int* __restrict__ act_rcv,
    const float* __restrict__ Wr2, const int* __restrict__ rowptr,
    int* __restrict__ cursor, int* __restrict__ wstart, f16x2* __restrict__ wlth,
    int* __restrict__ perm)
{
    int i = blockIdx.x * 256 + threadIdx.x;
    int nAct = *cnt;

    if (i <= NWAVES) {
        if (i == NWAVES) {
            wstart[NWAVES] = N_NODES;
        } else {
            int S = (nAct + NWAVES - 1) / NWAVES; if (S < 1) S = 1;
            wstart[i] = lbound_rp(rowptr, i * S);
        }
    }
    if (i >= WBASE) {
        int idx = i - WBASE;                  // 0 .. 9215
        int t = idx / (8 * CSH);
        int r = idx - t * (8 * CSH);
        int mq = r / CSH, j = r - mq * CSH;
        int c = j & 63, s = j >> 6;
        float lo = Wr2[t * MLPH * CSH + (2 * mq + 0) * CSH + c * SHD + s];
        float hi = Wr2[t * MLPH * CSH + (2 * mq + 1) * CSH + c * SHD + s];
        f16x2 v; v.x = (_Float16)lo; v.y = (_Float16)hi;
        wlth[idx] = v;
    }
    if (i >= nAct) return;
    int pos = atomicAdd(&cursor[act_rcv[i]], 1);
    perm[pos] = i;
}

// ---------------------------------------------------------------------------
// K1d: permute payloads into CSR order: gathered reads, COALESCED writes.
// Computes sh + f16 hid at the destination.
// ---------------------------------------------------------------------------
__global__ __launch_bounds__(256) void k_permute(
    const int* __restrict__ cnt, const int* __restrict__ perm,
    const int* __restrict__ act_snd, const int* __restrict__ act_rcv,
    const float* __restrict__ act_u, const float* __restrict__ act_ef,
    const float* __restrict__ Wr1,
    int* __restrict__ csnd, int* __restrict__ crcv, float* __restrict__ csh,
    f16x2* __restrict__ chidh0, f16x2* __restrict__ chidh1)
{
    int p = blockIdx.x * 256 + threadIdx.x;
    if (p >= *cnt) return;
    int i = perm[p];

    csnd[p] = act_snd[i];
    crcv[p] = act_rcv[i];

    float4 u4 = *(const float4*)&act_u[i * 4];
    float ux = u4.x, uy = u4.y, uz = u4.z;
    const float s3 = 1.7320508075688772f;
    const float s5 = 2.23606797749979f;
    const float s15 = 3.872983346207417f;
    *(float4*)&csh[p * 16 + 0] = make_float4(1.0f, s3 * ux, s3 * uy, s3 * uz);
    *(float4*)&csh[p * 16 + 4] = make_float4(s15 * ux * uy, s15 * uy * uz,
                                             0.5f * s5 * (3.0f * uz * uz - 1.0f),
                                             s15 * ux * uz);
    csh[p * 16 + 8] = 0.5f * s15 * (ux * ux - uy * uy);

    float4 e0 = *(const float4*)&act_ef[i * 8 + 0];
    float4 e1 = *(const float4*)&act_ef[i * 8 + 4];
    float ef[NB] = {e0.x, e0.y, e0.z, e0.w, e1.x, e1.y, e1.z, e1.w};

    #pragma unroll
    for (int t = 0; t < 2; t++) {
        f16x2* dst = (t == 0) ? chidh0 : chidh1;
        const float* W = Wr1 + t * NB * MLPH;
        f16x2 hv2[8];
        #pragma unroll
        for (int mp = 0; mp < 8; mp++) {
            float a0 = 0.0f, a1 = 0.0f;
            #pragma unroll
            for (int b = 0; b < NB; b++) {
                float efb = ef[b];
                a0 += efb * W[b * MLPH + 2 * mp + 0];
                a1 += efb * W[b * MLPH + 2 * mp + 1];
            }
            f16x2 v; v.x = (_Float16)silu_f(a0); v.y = (_Float16)silu_f(a1);
            hv2[mp] = v;
        }
        *(float4*)&dst[p * 8 + 0] = *(float4*)&hv2[0];
        *(float4*)&dst[p * 8 + 4] = *(float4*)&hv2[4];
    }
}

// ---------------------------------------------------------------------------
// K3: h_up = h @ W_up[t]
// ---------------------------------------------------------------------------
__global__ __launch_bounds__(256) void k_up(
    const float* __restrict__ h, const float* __restrict__ Wup, float* __restrict__ hup)
{
    __shared__ float Wl[C * C];
    for (int i = threadIdx.x; i < C * C; i += 256) Wl[i] = Wup[i];
    __syncthreads();
    int o = threadIdx.x & 63, g = threadIdx.x >> 6;
    int n = blockIdx.x * 4 + g;
    const float* hr = h + n * C;
    float acc = 0.0f;
    #pragma unroll 8
    for (int c = 0; c < C; c++) acc += hr[c] * Wl[c * C + o];
    hup[n * C + o] = acc;
}

// ---------------------------------------------------------------------------
// K4 (hot): segmented-CSR message pass, zero atomics, zero shuffles.
// f16x2-packed W (18 KB LDS) + v_dot2_f32_f16: half the LDS reads and half
// the VALU ops of the f32 version. s-major output: lane = c, jj = s.
// ---------------------------------------------------------------------------
__global__ __launch_bounds__(256) void k_msg5(
    const int* __restrict__ rowptr, const int* __restrict__ wstart,
    const int* __restrict__ csnd, const int* __restrict__ crcv,
    const float* __restrict__ csh, const f16x2* __restrict__ chh,
    const f16x2* __restrict__ wlth, const float* __restrict__ hup,
    float* __restrict__ agg)
{
    __shared__ f16x2 Wl[8 * CSH];   // 18 KB, [m-pair][j s-major]
    {
        const float4* src = (const float4*)wlth;
        float4* dst = (float4*)Wl;
        for (int i = threadIdx.x; i < (8 * CSH) / 4; i += 256) dst[i] = src[i];
    }
    __syncthreads();

    int lane = threadIdx.x & 63;
    int w = (blockIdx.x << 2) | (threadIdx.x >> 6);
    int nlo = wstart[w];
    int nhi = wstart[w + 1];
    if (nlo >= nhi) return;
    int beg = rowptr[nlo], end = rowptr[nhi];

    float acc[9];
    int curRcv = -1;

#define FLUSH() { float* ag = agg + (size_t)curRcv * CSH + lane; \
    _Pragma("unroll") for (int jj = 0; jj < 9; jj++) ag[jj << 6] = acc[jj]; }
#define ZFILL(FROM, TO) for (int zn = (FROM); zn < (TO); zn++) { \
    float* ag = agg + (size_t)zn * CSH + lane; \
    _Pragma("unroll") for (int jj = 0; jj < 9; jj++) ag[jj << 6] = 0.0f; }

    for (int k0 = beg; k0 < end; k0 += 8) {
        int nv = end - k0; if (nv > 8) nv = 8;

#define PRE(Q) int kc##Q = (k0 + Q < end) ? k0 + Q : end - 1; \
        int rcvq##Q = crcv[kc##Q]; \
        float hupq##Q = hup[csnd[kc##Q] * C + lane];
        PRE(0) PRE(1) PRE(2) PRE(3) PRE(4) PRE(5) PRE(6) PRE(7)
#undef PRE

        float tw0[9], tw1[9], tw2[9], tw3[9], tw4[9], tw5[9], tw6[9], tw7[9];
        #pragma unroll
        for (int jj = 0; jj < 9; jj++) {
            tw0[jj] = 0.f; tw1[jj] = 0.f; tw2[jj] = 0.f; tw3[jj] = 0.f;
            tw4[jj] = 0.f; tw5[jj] = 0.f; tw6[jj] = 0.f; tw7[jj] = 0.f;
        }

        #pragma unroll
        for (int mq = 0; mq < 8; mq++) {
            f16x2 h0 = chh[kc0 * 8 + mq], h1 = chh[kc1 * 8 + mq];
            f16x2 h2 = chh[kc2 * 8 + mq], h3 = chh[kc3 * 8 + mq];
            f16x2 h4 = chh[kc4 * 8 + mq], h5 = chh[kc5 * 8 + mq];
            f16x2 h6 = chh[kc6 * 8 + mq], h7 = chh[kc7 * 8 + mq];
            #pragma unroll
            for (int jj = 0; jj < 9; jj++) {
                f16x2 wv = Wl[mq * CSH + (jj << 6) + lane];
                tw0[jj] = dot2f(h0, wv, tw0[jj]);
                tw1[jj] = dot2f(h1, wv, tw1[jj]);
                tw2[jj] = dot2f(h2, wv, tw2[jj]);
                tw3[jj] = dot2f(h3, wv, tw3[jj]);
                tw4[jj] = dot2f(h4, wv, tw4[jj]);
                tw5[jj] = dot2f(h5, wv, tw5[jj]);
                tw6[jj] = dot2f(h6, wv, tw6[jj]);
                tw7[jj] = dot2f(h7, wv, tw7[jj]);
            }
        }

#define SCAT(Q) if (Q < nv) { \
        int rcv = rcvq##Q; \
        float hupS = hupq##Q; \
        float4 sA = *(const float4*)&csh[kc##Q * 16]; \
        float4 sB = *(const float4*)&csh[kc##Q * 16 + 4]; \
        float s8v = csh[kc##Q * 16 + 8]; \
        float sh9[9] = {sA.x, sA.y, sA.z, sA.w, sB.x, sB.y, sB.z, sB.w, s8v}; \
        if (rcv != curRcv) { \
            if (curRcv >= 0) { FLUSH(); ZFILL(curRcv + 1, rcv) } else { ZFILL(nlo, rcv) } \
            curRcv = rcv; \
            _Pragma("unroll") for (int jj = 0; jj < 9; jj++) acc[jj] = tw##Q[jj] * (hupS * sh9[jj]); \
        } else { \
            _Pragma("unroll") for (int jj = 0; jj < 9; jj++) acc[jj] += tw##Q[jj] * (hupS * sh9[jj]); \
        } }
        SCAT(0) SCAT(1) SCAT(2) SCAT(3) SCAT(4) SCAT(5) SCAT(6) SCAT(7)
#undef SCAT
    }

    int zfrom = nlo;
    if (curRcv >= 0) { FLUSH(); zfrom = curRcv + 1; }
    ZFILL(zfrom, nhi)
#undef FLUSH
#undef ZFILL
}

// ---------------------------------------------------------------------------
// K5: h_new = (agg/32) @ W_mix[t] + h @ W_self[t], fused readout.
// agg is s-major (j = s*64+c); Wmix row index permuted (wave-uniform).
// ---------------------------------------------------------------------------
template <int RMODE>
__global__ __launch_bounds__(256) void k_mix(
    const float* __restrict__ agg, const float* __restrict__ h,
    const float* __restrict__ Wmix, const float* __restrict__ Wself,
    float* __restrict__ hnew,
    const float* __restrict__ wread, const float* __restrict__ Wm1,
    const float* __restrict__ wm2, float* __restrict__ rep)
{
    __shared__ float Al[16 * CSH];   // 36 KB
    __shared__ float Hl[16 * C];     // 4 KB
    int nb = blockIdx.x * 16;
    for (int i = threadIdx.x; i < 16 * CSH; i += 256) Al[i] = agg[nb * CSH + i] * INV_AVG;
    for (int i = threadIdx.x; i < 16 * C; i += 256) Hl[i] = h[nb * C + i];
    __syncthreads();

    int o = threadIdx.x & 63, g = threadIdx.x >> 6;
    float acc[4] = {0.0f, 0.0f, 0.0f, 0.0f};
    for (int cs = 0; cs < CSH; cs += 4) {
        int cb = cs & 63, s = cs >> 6;
        float w0 = Wmix[((cb + 0) * SHD + s) * C + o];
        float w1 = Wmix[((cb + 1) * SHD + s) * C + o];
        float w2 = Wmix[((cb + 2) * SHD + s) * C + o];
        float w3 = Wmix[((cb + 3) * SHD + s) * C + o];
        #pragma unroll
        for (int q = 0; q < 4; q++) {
            float4 av = *(const float4*)&Al[(g + 4 * q) * CSH + cs];
            acc[q] += av.x * w0 + av.y * w1 + av.z * w2 + av.w * w3;
        }
    }
    for (int c = 0; c < C; c += 4) {
        float w0 = Wself[(c + 0) * C + o];
        float w1 = Wself[(c + 1) * C + o];
        float w2 = Wself[(c + 2) * C + o];
        float w3 = Wself[(c + 3) * C + o];
        #pragma unroll
        for (int q = 0; q < 4; q++) {
            float4 hv = *(const float4*)&Hl[(g + 4 * q) * C + c];
            acc[q] += hv.x * w0 + hv.y * w1 + hv.z * w2 + hv.w * w3;
        }
    }
    #pragma unroll
    for (int q = 0; q < 4; q++) hnew[(nb + g + 4 * q) * C + o] = acc[q];

    if (RMODE == 0) {
        float wr = wread[o];
        #pragma unroll
        for (int q = 0; q < 4; q++) {
            float v = acc[q] * wr;
            #pragma unroll
            for (int off = 32; off; off >>= 1) v += __shfl_xor(v, off);
            if (o == 0) rep[nb + g + 4 * q] = v;
        }
    } else {
        __syncthreads();
        float* Hn = Al;   // reuse as [16][64]
        #pragma unroll
        for (int q = 0; q < 4; q++) Hn[(g + 4 * q) * C + o] = acc[q];
        __syncthreads();
        int nl = threadIdx.x >> 4;
        int m = threadIdx.x & 15;
        float a2 = 0.0f;
        #pragma unroll 16
        for (int c = 0; c < C; c++) a2 += Hn[nl * C + c] * Wm1[c * MLPH + m];
        float rv = silu_f(a2) * wm2[m];
        #pragma unroll
        for (int off = 8; off; off >>= 1) rv += __shfl_xor(rv, off);
        if (m == 0) rep[nb + nl] = rv;
    }
}

// ---------------------------------------------------------------------------
extern "C" void kernel_launch(void* const* d_in, const int* in_sizes, int n_in,
                              void* d_out, int out_size, void* d_ws, size_t ws_size,
                              hipStream_t stream) {
    const float* pos    = (const float*)d_in[0];
    const float* na     = (const float*)d_in[1];
    const float* shifts = (const float*)d_in[2];
    const int*   ei     = (const int*)d_in[3];
    const float* ae     = (const float*)d_in[4];
    const float* We     = (const float*)d_in[5];
    const float* Wup    = (const float*)d_in[6];
    const float* Wr1    = (const float*)d_in[7];
    const float* Wr2    = (const float*)d_in[8];
    const float* Wmix   = (const float*)d_in[9];
    const float* Wself  = (const float*)d_in[10];
    const float* wread  = (const float*)d_in[11];
    const float* Wm1    = (const float*)d_in[12];
    const float* wm2    = (const float*)d_in[13];
    float* out = (float*)d_out;

    char* ws = (char*)d_ws;
    size_t off = 0;
    auto alloc = [&](size_t bytes) {
        off = (off + 255) & ~(size_t)255;
        void* p = ws + off;
        off += bytes;
        return p;
    };
    int*   cnt     = (int*)alloc(4);
    int*   deg     = (int*)alloc((size_t)N_NODES * 4);
    int*   rowptr  = (int*)alloc((size_t)(N_NODES + 1) * 4);
    int*   cursor  = (int*)alloc((size_t)N_NODES * 4);
    int*   wstart  = (int*)alloc((size_t)(NWAVES + 1) * 4);
    f16x2* wlth    = (f16x2*)alloc((size_t)2 * 8 * CSH * 4);
    int*   perm    = (int*)alloc((size_t)N_EDGES * 4);
    int*   act_snd = (int*)alloc((size_t)N_EDGES * 4);
    int*   act_rcv = (int*)alloc((size_t)N_EDGES * 4);
    float* act_u   = (float*)alloc((size_t)N_EDGES * 4 * 4);
    float* act_ef  = (float*)alloc((size_t)N_EDGES * 8 * 4);
    int*   csnd    = (int*)alloc((size_t)N_EDGES * 4);
    int*   crcv    = (int*)alloc((size_t)N_EDGES * 4);
    float* csh     = (float*)alloc((size_t)N_EDGES * 16 * 4);
    f16x2* chidh0  = (f16x2*)alloc((size_t)N_EDGES * 8 * 4);
    f16x2* chidh1  = (f16x2*)alloc((size_t)N_EDGES * 8 * 4);
    float* hA      = (float*)alloc((size_t)N_NODES * C * 4);
    float* hB      = (float*)alloc((size_t)N_NODES * C * 4);
    float* hup     = (float*)alloc((size_t)N_NODES * C * 4);
    float* agg     = (float*)alloc((size_t)N_NODES * CSH * 4);

    hipMemsetAsync(cnt, 0, 4, stream);
    hipMemsetAsync(deg, 0, (size_t)N_NODES * 4, stream);

    k_edge<<<(N_NODES * C) / 256, 256, 0, stream>>>(pos, shifts, ei, na, We, ae,
                                                    cnt, deg, act_snd, act_rcv,
                                                    act_u, act_ef, hA, out);
    k_scan<<<1, 256, 0, stream>>>(deg, rowptr, cursor);
    k_rank<<<N_EDGES / 256, 256, 0, stream>>>(cnt, act_rcv, Wr2, rowptr,
                                              cursor, wstart, wlth, perm);
    k_permute<<<N_EDGES / 256, 256, 0, stream>>>(cnt, perm, act_snd, act_rcv,
                                                 act_u, act_ef, Wr1,
                                                 csnd, crcv, csh, chidh0, chidh1);

    // ---- layer t = 0 ----
    k_up<<<N_NODES / 4, 256, 0, stream>>>(hA, Wup, hup);
    k_msg5<<<GRID_MSG, 256, 0, stream>>>(rowptr, wstart, csnd, crcv, csh,
                                         chidh0, wlth, hup, agg);
    k_mix<0><<<N_NODES / 16, 256, 0, stream>>>(agg, hA, Wmix, Wself, hB,
                                               wread, Wm1, wm2, out + N_NODES);

    // ---- layer t = 1 ----
    k_up<<<N_NODES / 4, 256, 0, stream>>>(hB, Wup + C * C, hup);
    k_msg5<<<GRID_MSG, 256, 0, stream>>>(rowptr, wstart, csnd, crcv, csh,
                                         chidh1, wlth + 8 * CSH, hup, agg);
    k_mix<1><<<N_NODES / 16, 256, 0, stream>>>(agg, hB, Wmix + C * SHD * C,
                                               Wself + C * C, hA,
                                               wread, Wm1, wm2, out + 2 * N_NODES);
}

// Round 10
// 178.012 us; speedup vs baseline: 1.8321x; 1.2530x over previous
//
#include <hip/hip_runtime.h>
#include <math.h>

#define N_NODES 10000
#define N_EDGES 160000
#define NEL 10
#define C 64
#define NB 8
#define SHD 9
#define MLPH 16
#define CSH 576
#define R_MAX 5.0f
#define INV_AVG 0.03125f
#define SCAN_CH 40     // 256*40 = 10240 >= N_NODES
#define GRID_MSG 1024  // 4 blocks/CU (18KB LDS)
#define NWAVES (GRID_MSG * 4)
#define WBASE (N_EDGES - 2 * 8 * CSH)   // wlth side-job region in k_rank
#define WB2   (WBASE - 10240)           // wmixf side-job region in k_rank

typedef _Float16 f16x2 __attribute__((ext_vector_type(2)));
typedef _Float16 f16x8 __attribute__((ext_vector_type(8)));
typedef float    f32x4 __attribute__((ext_vector_type(4)));
typedef _Float16 half_t;

__device__ __forceinline__ float silu_f(float v) {
    return v / (1.0f + __expf(-v));
}

__device__ __forceinline__ float dot2f(f16x2 a, f16x2 b, float c) {
#if __has_builtin(__builtin_amdgcn_fdot2)
    return __builtin_amdgcn_fdot2(a, b, c, false);
#else
    return c + (float)a.x * (float)b.x + (float)a.y * (float)b.y;
#endif
}

// lower_bound over rowptr[0..N_NODES]
__device__ __forceinline__ int lbound_rp(const int* __restrict__ rp, int target) {
    int lo = 0, hi = N_NODES;
    while (lo < hi) { int mid = (lo + hi) >> 1; if (rp[mid] < target) lo = mid + 1; else hi = mid; }
    return lo;
}

// ---------------------------------------------------------------------------
// K1: per-edge geometry + radial basis, compact active edges, degree histo,
//     FUSED node embedding (grid 2500; edge work on blocks < 625)
// ---------------------------------------------------------------------------
__global__ __launch_bounds__(256) void k_edge(
    const float* __restrict__ pos, const float* __restrict__ shifts,
    const int* __restrict__ ei,
    const float* __restrict__ na, const float* __restrict__ We,
    const float* __restrict__ ae,
    int* __restrict__ cnt, int* __restrict__ deg,
    int* __restrict__ act_snd, int* __restrict__ act_rcv,
    float* __restrict__ act_u, float* __restrict__ act_ef,
    float* __restrict__ h, float* __restrict__ out)
{
    int i = blockIdx.x * 256 + threadIdx.x;

    // ---- fused embed: h = na @ We ; out = na @ ae ----
    {
        int n = i >> 6, c = i & 63;
        float acc = 0.0f, e0 = 0.0f;
        #pragma unroll
        for (int k = 0; k < NEL; k++) {
            float a = na[n * NEL + k];
            acc += a * We[k * C + c];
            e0 += a * ae[k];
        }
        h[i] = acc;
        if (c == 0) out[n] = e0;
    }

    if (blockIdx.x >= N_EDGES / 256) return;
    int e = i;
    int snd = ei[e];
    int rcv = ei[N_EDGES + e];
    float vx = pos[rcv * 3 + 0] - pos[snd * 3 + 0] + shifts[e * 3 + 0];
    float vy = pos[rcv * 3 + 1] - pos[snd * 3 + 1] + shifts[e * 3 + 1];
    float vz = pos[rcv * 3 + 2] - pos[snd * 3 + 2] + shifts[e * 3 + 2];
    float r = sqrtf(vx * vx + vy * vy + vz * vz) + 1e-9f;
    float x = r / R_MAX;
    bool active = x < 1.0f;

    unsigned long long m = __ballot(active);
    int lane = threadIdx.x & 63;
    int base = 0;
    if (m) {
        int leader = __ffsll((unsigned long long)m) - 1;
        if (lane == leader) base = atomicAdd(cnt, __popcll(m));
        base = __shfl(base, leader);
    }
    if (!active) return;

    int p = base + __popcll(m & ((1ull << lane) - 1ull));
    act_snd[p] = snd;
    act_rcv[p] = rcv;
    atomicAdd(&deg[rcv], 1);

    float inv_r = 1.0f / r;
    *(float4*)&act_u[p * 4] = make_float4(vx * inv_r, vy * inv_r, vz * inv_r, r);

    // radial: bessel * polynomial cutoff (p=6)
    float x6 = x * x * x; x6 = x6 * x6;
    float x7 = x6 * x;
    float x8 = x7 * x;
    float fc = 1.0f - 28.0f * x6 + 48.0f * x7 - 21.0f * x8;
    float theta = 3.14159265358979323846f * r / R_MAX;
    float s1 = sinf(theta), c1 = cosf(theta);
    float sn = s1, cn = c1;
    float scale = 0.6324555320336759f * inv_r * fc;   // sqrt(2/R_MAX)/r*fc
    float ef[NB];
    ef[0] = scale * sn;
    #pragma unroll
    for (int n = 1; n < NB; n++) {
        float sn1 = sn * c1 + cn * s1;
        float cn1 = cn * c1 - sn * s1;
        sn = sn1; cn = cn1;
        ef[n] = scale * sn;
    }
    *(float4*)&act_ef[p * 8 + 0] = make_float4(ef[0], ef[1], ef[2], ef[3]);
    *(float4*)&act_ef[p * 8 + 4] = make_float4(ef[4], ef[5], ef[6], ef[7]);
}

// ---------------------------------------------------------------------------
// K1b: exclusive scan of deg -> rowptr + cursor (single block, LDS-staged)
// ---------------------------------------------------------------------------
__global__ __launch_bounds__(256) void k_scan(
    const int* __restrict__ deg, int* __restrict__ rowptr, int* __restrict__ cursor)
{
    __shared__ int dl[N_NODES];   // 40 KB
    __shared__ int part[256];
    int tid = threadIdx.x;
    for (int i = tid; i < N_NODES; i += 256) dl[i] = deg[i];
    __syncthreads();

    int base = tid * SCAN_CH;
    int s = 0;
    #pragma unroll 8
    for (int i = 0; i < SCAN_CH; i++) {
        int idx = base + i;
        if (idx < N_NODES) s += dl[idx];
    }
    part[tid] = s;
    __syncthreads();
    for (int off = 1; off < 256; off <<= 1) {
        int v = (tid >= off) ? part[tid - off] : 0;
        __syncthreads();
        part[tid] += v;
        __syncthreads();
    }
    int run = part[tid] - s;
    for (int i = 0; i < SCAN_CH; i++) {
        int idx = base + i;
        if (idx < N_NODES) {
            int v = dl[idx];
            dl[idx] = run;
            run += v;
        }
    }
    __syncthreads();
    for (int i = tid; i < N_NODES; i += 256) {
        int r = dl[i];
        rowptr[i] = r;
        cursor[i] = r;
    }
    if (tid == 255) rowptr[N_NODES] = part[255];
}

// ---------------------------------------------------------------------------
// K1c: rank edges into CSR order (4B scatter only) + side jobs:
//  - wstart[]: per-wave node partition for k_msg5
//  - wlth: s-major, m-paired, f16x2-packed Wr2 (both layers) for k_msg5
//  - wmixf: MFMA B-fragment pack of [Wmix/32 ; Wself] (both layers) for k_mixm
// ---------------------------------------------------------------------------
__global__ __launch_bounds__(256) void k_rank(
    const int* __restrict__ cnt, const int* __restrict__ act_rcv,
    const float* __restrict__ Wr2, const float* __restrict__ Wmix,
    const float* __restrict__ Wself, const int* __restrict__ rowptr,
    int* __restrict__ cursor, int* __restrict__ wstart, f16x2* __restrict__ wlth,
    f16x8* __restrict__ wmixf, int* __restrict__ perm)
{
    int i = blockIdx.x * 256 + threadIdx.x;
    int nAct = *cnt;

    if (i <= NWAVES) {
        if (i == NWAVES) {
            wstart[NWAVES] = N_NODES;
        } else {
            int S = (nAct + NWAVES - 1) / NWAVES; if (S < 1) S = 1;
            wstart[i] = lbound_rp(rowptr, i * S);
        }
    }
    if (i >= WBASE) {
        int idx = i - WBASE;                  // 0 .. 9215
        int t = idx / (8 * CSH);
        int r = idx - t * (8 * CSH);
        int mq = r / CSH, j = r - mq * CSH;
        int c = j & 63, s = j >> 6;
        float lo = Wr2[t * MLPH * CSH + (2 * mq + 0) * CSH + c * SHD + s];
        float hi = Wr2[t * MLPH * CSH + (2 * mq + 1) * CSH + c * SHD + s];
        f16x2 v; v.x = (_Float16)lo; v.y = (_Float16)hi;
        wlth[idx] = v;
    } else if (i >= WB2) {
        // MFMA B-fragments: B'[k][col], k<576 -> Wmix(perm'd, /32); k>=576 -> Wself
        int idx = i - WB2;                    // 0 .. 10239
        int t = idx / 5120;
        int r = idx - t * 5120;
        int ks = r >> 8;                      // 0..19
        int rr = r & 255;
        int nt = rr >> 6;                     // 0..3
        int ln = rr & 63;
        f16x8 v;
        #pragma unroll
        for (int e = 0; e < 8; e++) {
            int k = ks * 32 + ((ln >> 4) << 3) + e;
            int col = nt * 16 + (ln & 15);
            float x;
            if (k < CSH)
                x = Wmix[(size_t)t * CSH * C + ((k & 63) * SHD + (k >> 6)) * C + col] * INV_AVG;
            else
                x = Wself[(size_t)t * C * C + (k - CSH) * C + col];
            v[e] = (_Float16)x;
        }
        wmixf[(size_t)((t * 20 + ks) * 4 + nt) * 64 + ln] = v;
    }
    if (i >= nAct) return;
    int pos = atomicAdd(&cursor[act_rcv[i]], 1);
    perm[pos] = i;
}

// ---------------------------------------------------------------------------
// K1d: permute payloads into CSR order: gathered reads, COALESCED writes.
// ---------------------------------------------------------------------------
__global__ __launch_bounds__(256) void k_permute(
    const int* __restrict__ cnt, const int* __restrict__ perm,
    const int* __restrict__ act_snd, const int* __restrict__ act_rcv,
    const float* __restrict__ act_u, const float* __restrict__ act_ef,
    const float* __restrict__ Wr1,
    int* __restrict__ csnd, int* __restrict__ crcv, float* __restrict__ csh,
    f16x2* __restrict__ chidh0, f16x2* __restrict__ chidh1)
{
    int p = blockIdx.x * 256 + threadIdx.x;
    if (p >= *cnt) return;
    int i = perm[p];

    csnd[p] = act_snd[i];
    crcv[p] = act_rcv[i];

    float4 u4 = *(const float4*)&act_u[i * 4];
    float ux = u4.x, uy = u4.y, uz = u4.z;
    const float s3 = 1.7320508075688772f;
    const float s5 = 2.23606797749979f;
    const float s15 = 3.872983346207417f;
    *(float4*)&csh[p * 16 + 0] = make_float4(1.0f, s3 * ux, s3 * uy, s3 * uz);
    *(float4*)&csh[p * 16 + 4] = make_float4(s15 * ux * uy, s15 * uy * uz,
                                             0.5f * s5 * (3.0f * uz * uz - 1.0f),
                                             s15 * ux * uz);
    csh[p * 16 + 8] = 0.5f * s15 * (ux * ux - uy * uy);

    float4 e0 = *(const float4*)&act_ef[i * 8 + 0];
    float4 e1 = *(const float4*)&act_ef[i * 8 + 4];
    float ef[NB] = {e0.x, e0.y, e0.z, e0.w, e1.x, e1.y, e1.z, e1.w};

    #pragma unroll
    for (int t = 0; t < 2; t++) {
        f16x2* dst = (t == 0) ? chidh0 : chidh1;
        const float* W = Wr1 + t * NB * MLPH;
        f16x2 hv2[8];
        #pragma unroll
        for (int mp = 0; mp < 8; mp++) {
            float a0 = 0.0f, a1 = 0.0f;
            #pragma unroll
            for (int b = 0; b < NB; b++) {
                float efb = ef[b];
                a0 += efb * W[b * MLPH + 2 * mp + 0];
                a1 += efb * W[b * MLPH + 2 * mp + 1];
            }
            f16x2 v; v.x = (_Float16)silu_f(a0); v.y = (_Float16)silu_f(a1);
            hv2[mp] = v;
        }
        *(float4*)&dst[p * 8 + 0] = *(float4*)&hv2[0];
        *(float4*)&dst[p * 8 + 4] = *(float4*)&hv2[4];
    }
}

// ---------------------------------------------------------------------------
// K3: h_up = h @ W_up[t]  +  f16 copy of h (A-extension for k_mixm)
// ---------------------------------------------------------------------------
__global__ __launch_bounds__(256) void k_up(
    const float* __restrict__ h, const float* __restrict__ Wup,
    float* __restrict__ hup, half_t* __restrict__ hh)
{
    __shared__ float Wl[C * C];
    for (int i = threadIdx.x; i < C * C; i += 256) Wl[i] = Wup[i];
    __syncthreads();
    int o = threadIdx.x & 63, g = threadIdx.x >> 6;
    int n = blockIdx.x * 4 + g;
    const float* hr = h + n * C;
    float acc = 0.0f;
    #pragma unroll 8
    for (int c = 0; c < C; c++) acc += hr[c] * Wl[c * C + o];
    hup[n * C + o] = acc;
    hh[n * C + o] = (half_t)hr[o];
}

// ---------------------------------------------------------------------------
// K4 (hot): segmented-CSR message pass, zero atomics, zero shuffles.
// agg written as f16 (s-major j) -> feeds k_mixm's MFMA A operand directly.
// ---------------------------------------------------------------------------
__global__ __launch_bounds__(256) void k_msg5(
    const int* __restrict__ rowptr, const int* __restrict__ wstart,
    const int* __restrict__ csnd, const int* __restrict__ crcv,
    const float* __restrict__ csh, const f16x2* __restrict__ chh,
    const f16x2* __restrict__ wlth, const float* __restrict__ hup,
    half_t* __restrict__ aggh)
{
    __shared__ f16x2 Wl[8 * CSH];   // 18 KB, [m-pair][j s-major]
    {
        const float4* src = (const float4*)wlth;
        float4* dst = (float4*)Wl;
        for (int i = threadIdx.x; i < (8 * CSH) / 4; i += 256) dst[i] = src[i];
    }
    __syncthreads();

    int lane = threadIdx.x & 63;
    int w = (blockIdx.x << 2) | (threadIdx.x >> 6);
    int nlo = wstart[w];
    int nhi = wstart[w + 1];
    if (nlo >= nhi) return;
    int beg = rowptr[nlo], end = rowptr[nhi];

    float acc[9];
    int curRcv = -1;

#define FLUSH() { half_t* ag = aggh + (size_t)curRcv * CSH + lane; \
    _Pragma("unroll") for (int jj = 0; jj < 9; jj++) ag[jj << 6] = (half_t)acc[jj]; }
#define ZFILL(FROM, TO) for (int zn = (FROM); zn < (TO); zn++) { \
    half_t* ag = aggh + (size_t)zn * CSH + lane; \
    _Pragma("unroll") for (int jj = 0; jj < 9; jj++) ag[jj << 6] = (half_t)0.0f; }

    for (int k0 = beg; k0 < end; k0 += 8) {
        int nv = end - k0; if (nv > 8) nv = 8;

#define PRE(Q) int kc##Q = (k0 + Q < end) ? k0 + Q : end - 1; \
        int rcvq##Q = crcv[kc##Q]; \
        float hupq##Q = hup[csnd[kc##Q] * C + lane];
        PRE(0) PRE(1) PRE(2) PRE(3) PRE(4) PRE(5) PRE(6) PRE(7)
#undef PRE

        float tw0[9], tw1[9], tw2[9], tw3[9], tw4[9], tw5[9], tw6[9], tw7[9];
        #pragma unroll
        for (int jj = 0; jj < 9; jj++) {
            tw0[jj] = 0.f; tw1[jj] = 0.f; tw2[jj] = 0.f; tw3[jj] = 0.f;
            tw4[jj] = 0.f; tw5[jj] = 0.f; tw6[jj] = 0.f; tw7[jj] = 0.f;
        }

        #pragma unroll
        for (int mq = 0; mq < 8; mq++) {
            f16x2 h0 = chh[kc0 * 8 + mq], h1 = chh[kc1 * 8 + mq];
            f16x2 h2 = chh[kc2 * 8 + mq], h3 = chh[kc3 * 8 + mq];
            f16x2 h4 = chh[kc4 * 8 + mq], h5 = chh[kc5 * 8 + mq];
            f16x2 h6 = chh[kc6 * 8 + mq], h7 = chh[kc7 * 8 + mq];
            #pragma unroll
            for (int jj = 0; jj < 9; jj++) {
                f16x2 wv = Wl[mq * CSH + (jj << 6) + lane];
                tw0[jj] = dot2f(h0, wv, tw0[jj]);
                tw1[jj] = dot2f(h1, wv, tw1[jj]);
                tw2[jj] = dot2f(h2, wv, tw2[jj]);
                tw3[jj] = dot2f(h3, wv, tw3[jj]);
                tw4[jj] = dot2f(h4, wv, tw4[jj]);
                tw5[jj] = dot2f(h5, wv, tw5[jj]);
                tw6[jj] = dot2f(h6, wv, tw6[jj]);
                tw7[jj] = dot2f(h7, wv, tw7[jj]);
            }
        }

#define SCAT(Q) if (Q < nv) { \
        int rcv = rcvq##Q; \
        float hupS = hupq##Q; \
        float4 sA = *(const float4*)&csh[kc##Q * 16]; \
        float4 sB = *(const float4*)&csh[kc##Q * 16 + 4]; \
        float s8v = csh[kc##Q * 16 + 8]; \
        float sh9[9] = {sA.x, sA.y, sA.z, sA.w, sB.x, sB.y, sB.z, sB.w, s8v}; \
        if (rcv != curRcv) { \
            if (curRcv >= 0) { FLUSH(); ZFILL(curRcv + 1, rcv) } else { ZFILL(nlo, rcv) } \
            curRcv = rcv; \
            _Pragma("unroll") for (int jj = 0; jj < 9; jj++) acc[jj] = tw##Q[jj] * (hupS * sh9[jj]); \
        } else { \
            _Pragma("unroll") for (int jj = 0; jj < 9; jj++) acc[jj] += tw##Q[jj] * (hupS * sh9[jj]); \
        } }
        SCAT(0) SCAT(1) SCAT(2) SCAT(3) SCAT(4) SCAT(5) SCAT(6) SCAT(7)
#undef SCAT
    }

    int zfrom = nlo;
    if (curRcv >= 0) { FLUSH(); zfrom = curRcv + 1; }
    ZFILL(zfrom, nhi)
#undef FLUSH
#undef ZFILL
}

// ---------------------------------------------------------------------------
// K5 (MFMA): hnew = [aggh | hh] @ [Wmix/32 ; Wself]  via mfma_f32_16x16x32_f16
// One wave per 16 nodes; K = 640 = 20 k-steps; 4 column-tiles of 16.
// A-frag: row = lane&15, k = ks*32 + (lane>>4)*8 + e (16B contiguous load).
// B-frag: pre-packed in wmixf. C/D: col = lane&15, row = (lane>>4)*4 + reg.
// ---------------------------------------------------------------------------
__global__ __launch_bounds__(64) void k_mixm(
    const half_t* __restrict__ aggh, const half_t* __restrict__ hh,
    const f16x8* __restrict__ wf, float* __restrict__ hnew)
{
    int lane = threadIdx.x & 63;
    int base = blockIdx.x * 16;
    int rowA = base + (lane & 15);
    int kg = (lane >> 4) << 3;     // 0,8,16,24

    f32x4 acc0 = {0.f, 0.f, 0.f, 0.f};
    f32x4 acc1 = {0.f, 0.f, 0.f, 0.f};
    f32x4 acc2 = {0.f, 0.f, 0.f, 0.f};
    f32x4 acc3 = {0.f, 0.f, 0.f, 0.f};

    const half_t* arow = aggh + (size_t)rowA * CSH + kg;
    const half_t* hrow = hh + (size_t)rowA * C + kg;

    #pragma unroll
    for (int ks = 0; ks < 20; ks++) {
        f16x8 a = (ks < 18) ? *(const f16x8*)(arow + ks * 32)
                            : *(const f16x8*)(hrow + (ks - 18) * 32);
        const f16x8* bp = wf + (size_t)(ks * 4) * 64 + lane;
        acc0 = __builtin_amdgcn_mfma_f32_16x16x32_f16(a, bp[0],   acc0, 0, 0, 0);
        acc1 = __builtin_amdgcn_mfma_f32_16x16x32_f16(a, bp[64],  acc1, 0, 0, 0);
        acc2 = __builtin_amdgcn_mfma_f32_16x16x32_f16(a, bp[128], acc2, 0, 0, 0);
        acc3 = __builtin_amdgcn_mfma_f32_16x16x32_f16(a, bp[192], acc3, 0, 0, 0);
    }

    int colb = lane & 15;
    int rowb = base + ((lane >> 4) << 2);
    #pragma unroll
    for (int r = 0; r < 4; r++) {
        float* hp = hnew + (size_t)(rowb + r) * C + colb;
        hp[0]  = acc0[r];
        hp[16] = acc1[r];
        hp[32] = acc2[r];
        hp[48] = acc3[r];
    }
}

// ---------------------------------------------------------------------------
// K6a: rep1[n] = h[n,:] . w_read
// ---------------------------------------------------------------------------
__global__ __launch_bounds__(256) void k_read(
    const float* __restrict__ h, const float* __restrict__ wread, float* __restrict__ out)
{
    int lane = threadIdx.x & 63;
    int n = blockIdx.x * 4 + (threadIdx.x >> 6);
    float v = h[n * C + lane] * wread[lane];
    #pragma unroll
    for (int off = 32; off; off >>= 1) v += __shfl_xor(v, off);
    if (lane == 0) out[n] = v;
}

// ---------------------------------------------------------------------------
// K6b: rep2[n] = silu(h[n,:] @ W_mlp1) . w_mlp2
// ---------------------------------------------------------------------------
__global__ __launch_bounds__(256) void k_read2(
    const float* __restrict__ h, const float* __restrict__ W1,
    const float* __restrict__ w2, float* __restrict__ out)
{
    int n = blockIdx.x * 256 + threadIdx.x;
    if (n >= N_NODES) return;
    float acc[MLPH];
    #pragma unroll
    for (int m = 0; m < MLPH; m++) acc[m] = 0.0f;
    for (int c = 0; c < C; c++) {
        float hv = h[n * C + c];
        #pragma unroll
        for (int m = 0; m < MLPH; m++) acc[m] += hv * W1[c * MLPH + m];
    }
    float o = 0.0f;
    #pragma unroll
    for (int m = 0; m < MLPH; m++) o += silu_f(acc[m]) * w2[m];
    out[n] = o;
}

// ---------------------------------------------------------------------------
extern "C" void kernel_launch(void* const* d_in, const int* in_sizes, int n_in,
                              void* d_out, int out_size, void* d_ws, size_t ws_size,
                              hipStream_t stream) {
    const float* pos    = (const float*)d_in[0];
    const float* na     = (const float*)d_in[1];
    const float* shifts = (const float*)d_in[2];
    const int*   ei     = (const int*)d_in[3];
    const float* ae     = (const float*)d_in[4];
    const float* We     = (const float*)d_in[5];
    const float* Wup    = (const float*)d_in[6];
    const float* Wr1    = (const float*)d_in[7];
    const float* Wr2    = (const float*)d_in[8];
    const float* Wmix   = (const float*)d_in[9];
    const float* Wself  = (const float*)d_in[10];
    const float* wread  = (const float*)d_in[11];
    const float* Wm1    = (const float*)d_in[12];
    const float* wm2    = (const float*)d_in[13];
    float* out = (float*)d_out;

    char* ws = (char*)d_ws;
    size_t off = 0;
    auto alloc = [&](size_t bytes) {
        off = (off + 255) & ~(size_t)255;
        void* p = ws + off;
        off += bytes;
        return p;
    };
    int*   cnt     = (int*)alloc(4);
    int*   deg     = (int*)alloc((size_t)N_NODES * 4);
    int*   rowptr  = (int*)alloc((size_t)(N_NODES + 1) * 4);
    int*   cursor  = (int*)alloc((size_t)N_NODES * 4);
    int*   wstart  = (int*)alloc((size_t)(NWAVES + 1) * 4);
    f16x2* wlth    = (f16x2*)alloc((size_t)2 * 8 * CSH * 4);
    f16x8* wmixf   = (f16x8*)alloc((size_t)2 * 5120 * 16);
    int*   perm    = (int*)alloc((size_t)N_EDGES * 4);
    int*   act_snd = (int*)alloc((size_t)N_EDGES * 4);
    int*   act_rcv = (int*)alloc((size_t)N_EDGES * 4);
    float* act_u   = (float*)alloc((size_t)N_EDGES * 4 * 4);
    float* act_ef  = (float*)alloc((size_t)N_EDGES * 8 * 4);
    int*   csnd    = (int*)alloc((size_t)N_EDGES * 4);
    int*   crcv    = (int*)alloc((size_t)N_EDGES * 4);
    float* csh     = (float*)alloc((size_t)N_EDGES * 16 * 4);
    f16x2* chidh0  = (f16x2*)alloc((size_t)N_EDGES * 8 * 4);
    f16x2* chidh1  = (f16x2*)alloc((size_t)N_EDGES * 8 * 4);
    float* hA      = (float*)alloc((size_t)N_NODES * C * 4);
    float* hB      = (float*)alloc((size_t)N_NODES * C * 4);
    float* hup     = (float*)alloc((size_t)N_NODES * C * 4);
    half_t* hh     = (half_t*)alloc((size_t)N_NODES * C * 2);
    half_t* aggh   = (half_t*)alloc((size_t)N_NODES * CSH * 2);

    hipMemsetAsync(cnt, 0, 4, stream);
    hipMemsetAsync(deg, 0, (size_t)N_NODES * 4, stream);

    k_edge<<<(N_NODES * C) / 256, 256, 0, stream>>>(pos, shifts, ei, na, We, ae,
                                                    cnt, deg, act_snd, act_rcv,
                                                    act_u, act_ef, hA, out);
    k_scan<<<1, 256, 0, stream>>>(deg, rowptr, cursor);
    k_rank<<<N_EDGES / 256, 256, 0, stream>>>(cnt, act_rcv, Wr2, Wmix, Wself,
                                              rowptr, cursor, wstart, wlth,
                                              wmixf, perm);
    k_permute<<<N_EDGES / 256, 256, 0, stream>>>(cnt, perm, act_snd, act_rcv,
                                                 act_u, act_ef, Wr1,
                                                 csnd, crcv, csh, chidh0, chidh1);

    // ---- layer t = 0 ----
    k_up<<<N_NODES / 4, 256, 0, stream>>>(hA, Wup, hup, hh);
    k_msg5<<<GRID_MSG, 256, 0, stream>>>(rowptr, wstart, csnd, crcv, csh,
                                         chidh0, wlth, hup, aggh);
    k_mixm<<<N_NODES / 16, 64, 0, stream>>>(aggh, hh, wmixf, hB);
    k_read<<<N_NODES / 4, 256, 0, stream>>>(hB, wread, out + N_NODES);

    // ---- layer t = 1 ----
    k_up<<<N_NODES / 4, 256, 0, stream>>>(hB, Wup + C * C, hup, hh);
    k_msg5<<<GRID_MSG, 256, 0, stream>>>(rowptr, wstart, csnd, crcv, csh,
                                         chidh1, wlth + 8 * CSH, hup, aggh);
    k_mixm<<<N_NODES / 16, 64, 0, stream>>>(aggh, hh, wmixf + 5120, hA);
    k_read2<<<(N_NODES + 255) / 256, 256, 0, stream>>>(hA, Wm1, wm2, out + 2 * N_NODES);
}

// Round 11
// 166.326 us; speedup vs baseline: 1.9608x; 1.0703x over previous
//
#include <hip/hip_runtime.h>
#include <math.h>

#define N_NODES 10000
#define N_EDGES 160000
#define NEL 10
#define C 64
#define NB 8
#define SHD 9
#define MLPH 16
#define CSH 576
#define R_MAX 5.0f
#define INV_AVG 0.03125f
#define SCAN_CH 40     // 256*40 = 10240 >= N_NODES
#define GRID_MSG 2048  // up to 8 blocks/CU by LDS (18KB)
#define NWAVES (GRID_MSG * 4)
#define WBASE (N_EDGES - 2 * 8 * CSH)   // wlth side-job region in k_rank
#define WB2   (WBASE - 10240)           // wmixf side-job region
#define WB3   (WB2 - 512)               // wupf (layer-1 Wup fragments)

typedef _Float16 f16x2 __attribute__((ext_vector_type(2)));
typedef _Float16 f16x8 __attribute__((ext_vector_type(8)));
typedef float    f32x4 __attribute__((ext_vector_type(4)));
typedef _Float16 half_t;

__device__ __forceinline__ float silu_f(float v) {
    return v / (1.0f + __expf(-v));
}

__device__ __forceinline__ float dot2f(f16x2 a, f16x2 b, float c) {
#if __has_builtin(__builtin_amdgcn_fdot2)
    return __builtin_amdgcn_fdot2(a, b, c, false);
#else
    return c + (float)a.x * (float)b.x + (float)a.y * (float)b.y;
#endif
}

__device__ __forceinline__ int lbound_rp(const int* __restrict__ rp, int target) {
    int lo = 0, hi = N_NODES;
    while (lo < hi) { int mid = (lo + hi) >> 1; if (rp[mid] < target) lo = mid + 1; else hi = mid; }
    return lo;
}

// ---------------------------------------------------------------------------
// K1: per-edge geometry + radial basis, compact active edges, degree histo,
//     FUSED node embedding
// ---------------------------------------------------------------------------
__global__ __launch_bounds__(256) void k_edge(
    const float* __restrict__ pos, const float* __restrict__ shifts,
    const int* __restrict__ ei,
    const float* __restrict__ na, const float* __restrict__ We,
    const float* __restrict__ ae,
    int* __restrict__ cnt, int* __restrict__ deg,
    int* __restrict__ act_snd, int* __restrict__ act_rcv,
    float* __restrict__ act_u, float* __restrict__ act_ef,
    float* __restrict__ h, float* __restrict__ out)
{
    int i = blockIdx.x * 256 + threadIdx.x;

    {
        int n = i >> 6, c = i & 63;
        float acc = 0.0f, e0 = 0.0f;
        #pragma unroll
        for (int k = 0; k < NEL; k++) {
            float a = na[n * NEL + k];
            acc += a * We[k * C + c];
            e0 += a * ae[k];
        }
        h[i] = acc;
        if (c == 0) out[n] = e0;
    }

    if (blockIdx.x >= N_EDGES / 256) return;
    int e = i;
    int snd = ei[e];
    int rcv = ei[N_EDGES + e];
    float vx = pos[rcv * 3 + 0] - pos[snd * 3 + 0] + shifts[e * 3 + 0];
    float vy = pos[rcv * 3 + 1] - pos[snd * 3 + 1] + shifts[e * 3 + 1];
    float vz = pos[rcv * 3 + 2] - pos[snd * 3 + 2] + shifts[e * 3 + 2];
    float r = sqrtf(vx * vx + vy * vy + vz * vz) + 1e-9f;
    float x = r / R_MAX;
    bool active = x < 1.0f;

    unsigned long long m = __ballot(active);
    int lane = threadIdx.x & 63;
    int base = 0;
    if (m) {
        int leader = __ffsll((unsigned long long)m) - 1;
        if (lane == leader) base = atomicAdd(cnt, __popcll(m));
        base = __shfl(base, leader);
    }
    if (!active) return;

    int p = base + __popcll(m & ((1ull << lane) - 1ull));
    act_snd[p] = snd;
    act_rcv[p] = rcv;
    atomicAdd(&deg[rcv], 1);

    float inv_r = 1.0f / r;
    *(float4*)&act_u[p * 4] = make_float4(vx * inv_r, vy * inv_r, vz * inv_r, r);

    float x6 = x * x * x; x6 = x6 * x6;
    float x7 = x6 * x;
    float x8 = x7 * x;
    float fc = 1.0f - 28.0f * x6 + 48.0f * x7 - 21.0f * x8;
    float theta = 3.14159265358979323846f * r / R_MAX;
    float s1 = sinf(theta), c1 = cosf(theta);
    float sn = s1, cn = c1;
    float scale = 0.6324555320336759f * inv_r * fc;   // sqrt(2/R_MAX)/r*fc
    float ef[NB];
    ef[0] = scale * sn;
    #pragma unroll
    for (int n = 1; n < NB; n++) {
        float sn1 = sn * c1 + cn * s1;
        float cn1 = cn * c1 - sn * s1;
        sn = sn1; cn = cn1;
        ef[n] = scale * sn;
    }
    *(float4*)&act_ef[p * 8 + 0] = make_float4(ef[0], ef[1], ef[2], ef[3]);
    *(float4*)&act_ef[p * 8 + 4] = make_float4(ef[4], ef[5], ef[6], ef[7]);
}

// ---------------------------------------------------------------------------
// K1b: exclusive scan of deg -> rowptr + cursor (single block, LDS-staged)
// ---------------------------------------------------------------------------
__global__ __launch_bounds__(256) void k_scan(
    const int* __restrict__ deg, int* __restrict__ rowptr, int* __restrict__ cursor)
{
    __shared__ int dl[N_NODES];   // 40 KB
    __shared__ int part[256];
    int tid = threadIdx.x;
    for (int i = tid; i < N_NODES; i += 256) dl[i] = deg[i];
    __syncthreads();

    int base = tid * SCAN_CH;
    int s = 0;
    #pragma unroll 8
    for (int i = 0; i < SCAN_CH; i++) {
        int idx = base + i;
        if (idx < N_NODES) s += dl[idx];
    }
    part[tid] = s;
    __syncthreads();
    for (int off = 1; off < 256; off <<= 1) {
        int v = (tid >= off) ? part[tid - off] : 0;
        __syncthreads();
        part[tid] += v;
        __syncthreads();
    }
    int run = part[tid] - s;
    for (int i = 0; i < SCAN_CH; i++) {
        int idx = base + i;
        if (idx < N_NODES) {
            int v = dl[idx];
            dl[idx] = run;
            run += v;
        }
    }
    __syncthreads();
    for (int i = tid; i < N_NODES; i += 256) {
        int r = dl[i];
        rowptr[i] = r;
        cursor[i] = r;
    }
    if (tid == 255) rowptr[N_NODES] = part[255];
}

// ---------------------------------------------------------------------------
// K1c: rank edges into CSR order (4B scatter) + side jobs:
//  wstart[], wlth (f16x2 Wr2), wmixf (MFMA B-frags [Wmix/32;Wself]),
//  wupf (MFMA B-frags of layer-1 Wup)
// ---------------------------------------------------------------------------
__global__ __launch_bounds__(256) void k_rank(
    const int* __restrict__ cnt, const int* __restrict__ act_rcv,
    const float* __restrict__ Wr2, const float* __restrict__ Wmix,
    const float* __restrict__ Wself, const float* __restrict__ Wup,
    const int* __restrict__ rowptr,
    int* __restrict__ cursor, int* __restrict__ wstart, f16x2* __restrict__ wlth,
    f16x8* __restrict__ wmixf, f16x8* __restrict__ wupf, int* __restrict__ perm)
{
    int i = blockIdx.x * 256 + threadIdx.x;
    int nAct = *cnt;

    if (i <= NWAVES) {
        if (i == NWAVES) {
            wstart[NWAVES] = N_NODES;
        } else {
            int S = (nAct + NWAVES - 1) / NWAVES; if (S < 1) S = 1;
            wstart[i] = lbound_rp(rowptr, i * S);
        }
    }
    if (i >= WBASE) {
        int idx = i - WBASE;                  // 0 .. 9215
        int t = idx / (8 * CSH);
        int r = idx - t * (8 * CSH);
        int mq = r / CSH, j = r - mq * CSH;
        int c = j & 63, s = j >> 6;
        float lo = Wr2[t * MLPH * CSH + (2 * mq + 0) * CSH + c * SHD + s];
        float hi = Wr2[t * MLPH * CSH + (2 * mq + 1) * CSH + c * SHD + s];
        f16x2 v; v.x = (_Float16)lo; v.y = (_Float16)hi;
        wlth[idx] = v;
    } else if (i >= WB2) {
        int idx = i - WB2;                    // 0 .. 10239
        int t = idx / 5120;
        int r = idx - t * 5120;
        int ks = r >> 8;                      // 0..19
        int rr = r & 255;
        int nt = rr >> 6;                     // 0..3
        int ln = rr & 63;
        f16x8 v;
        #pragma unroll
        for (int e = 0; e < 8; e++) {
            int k = ks * 32 + ((ln >> 4) << 3) + e;
            int col = nt * 16 + (ln & 15);
            float x;
            if (k < CSH)
                x = Wmix[(size_t)t * CSH * C + ((k & 63) * SHD + (k >> 6)) * C + col] * INV_AVG;
            else
                x = Wself[(size_t)t * C * C + (k - CSH) * C + col];
            v[e] = (_Float16)x;
        }
        wmixf[(size_t)((t * 20 + ks) * 4 + nt) * 64 + ln] = v;
    } else if (i >= WB3) {
        int idx = i - WB3;                    // 0 .. 511
        int ks = idx >> 8;                    // 0..1
        int rr = idx & 255;
        int nt = rr >> 6;
        int ln = rr & 63;
        f16x8 v;
        #pragma unroll
        for (int e = 0; e < 8; e++) {
            int k = ks * 32 + ((ln >> 4) << 3) + e;
            int col = nt * 16 + (ln & 15);
            v[e] = (_Float16)Wup[C * C + k * C + col];   // layer-1 Wup
        }
        wupf[(size_t)(ks * 4 + nt) * 64 + ln] = v;
    }
    if (i >= nAct) return;
    int pos = atomicAdd(&cursor[act_rcv[i]], 1);
    perm[pos] = i;
}

// ---------------------------------------------------------------------------
// K1d: permute payloads into CSR order: gathered reads, COALESCED writes.
// ---------------------------------------------------------------------------
__global__ __launch_bounds__(256) void k_permute(
    const int* __restrict__ cnt, const int* __restrict__ perm,
    const int* __restrict__ act_snd, const int* __restrict__ act_rcv,
    const float* __restrict__ act_u, const float* __restrict__ act_ef,
    const float* __restrict__ Wr1,
    int* __restrict__ csnd, int* __restrict__ crcv, float* __restrict__ csh,
    f16x2* __restrict__ chidh0, f16x2* __restrict__ chidh1)
{
    int p = blockIdx.x * 256 + threadIdx.x;
    if (p >= *cnt) return;
    int i = perm[p];

    csnd[p] = act_snd[i];
    crcv[p] = act_rcv[i];

    float4 u4 = *(const float4*)&act_u[i * 4];
    float ux = u4.x, uy = u4.y, uz = u4.z;
    const float s3 = 1.7320508075688772f;
    const float s5 = 2.23606797749979f;
    const float s15 = 3.872983346207417f;
    *(float4*)&csh[p * 16 + 0] = make_float4(1.0f, s3 * ux, s3 * uy, s3 * uz);
    *(float4*)&csh[p * 16 + 4] = make_float4(s15 * ux * uy, s15 * uy * uz,
                                             0.5f * s5 * (3.0f * uz * uz - 1.0f),
                                             s15 * ux * uz);
    csh[p * 16 + 8] = 0.5f * s15 * (ux * ux - uy * uy);

    float4 e0 = *(const float4*)&act_ef[i * 8 + 0];
    float4 e1 = *(const float4*)&act_ef[i * 8 + 4];
    float ef[NB] = {e0.x, e0.y, e0.z, e0.w, e1.x, e1.y, e1.z, e1.w};

    #pragma unroll
    for (int t = 0; t < 2; t++) {
        f16x2* dst = (t == 0) ? chidh0 : chidh1;
        const float* W = Wr1 + t * NB * MLPH;
        f16x2 hv2[8];
        #pragma unroll
        for (int mp = 0; mp < 8; mp++) {
            float a0 = 0.0f, a1 = 0.0f;
            #pragma unroll
            for (int b = 0; b < NB; b++) {
                float efb = ef[b];
                a0 += efb * W[b * MLPH + 2 * mp + 0];
                a1 += efb * W[b * MLPH + 2 * mp + 1];
            }
            f16x2 v; v.x = (_Float16)silu_f(a0); v.y = (_Float16)silu_f(a1);
            hv2[mp] = v;
        }
        *(float4*)&dst[p * 8 + 0] = *(float4*)&hv2[0];
        *(float4*)&dst[p * 8 + 4] = *(float4*)&hv2[4];
    }
}

// ---------------------------------------------------------------------------
// K3: h_up = h @ W_up[0]  +  f16 copy of h  (layer 0 only)
// ---------------------------------------------------------------------------
__global__ __launch_bounds__(256) void k_up(
    const float* __restrict__ h, const float* __restrict__ Wup,
    float* __restrict__ hup, half_t* __restrict__ hh)
{
    __shared__ float Wl[C * C];
    for (int i = threadIdx.x; i < C * C; i += 256) Wl[i] = Wup[i];
    __syncthreads();
    int o = threadIdx.x & 63, g = threadIdx.x >> 6;
    int n = blockIdx.x * 4 + g;
    const float* hr = h + n * C;
    float acc = 0.0f;
    #pragma unroll 8
    for (int c = 0; c < C; c++) acc += hr[c] * Wl[c * C + o];
    hup[n * C + o] = acc;
    hh[n * C + o] = (half_t)hr[o];
}

// ---------------------------------------------------------------------------
// K4 (hot): segmented-CSR message pass, zero atomics, zero shuffles.
// agg written as f16 (s-major j) -> feeds k_mixm's MFMA A operand directly.
// ---------------------------------------------------------------------------
__global__ __launch_bounds__(256) void k_msg5(
    const int* __restrict__ rowptr, const int* __restrict__ wstart,
    const int* __restrict__ csnd, const int* __restrict__ crcv,
    const float* __restrict__ csh, const f16x2* __restrict__ chh,
    const f16x2* __restrict__ wlth, const float* __restrict__ hup,
    half_t* __restrict__ aggh)
{
    __shared__ f16x2 Wl[8 * CSH];   // 18 KB, [m-pair][j s-major]
    {
        const float4* src = (const float4*)wlth;
        float4* dst = (float4*)Wl;
        for (int i = threadIdx.x; i < (8 * CSH) / 4; i += 256) dst[i] = src[i];
    }
    __syncthreads();

    int lane = threadIdx.x & 63;
    int w = (blockIdx.x << 2) | (threadIdx.x >> 6);
    int nlo = wstart[w];
    int nhi = wstart[w + 1];
    if (nlo >= nhi) return;
    int beg = rowptr[nlo], end = rowptr[nhi];

    float acc[9];
    int curRcv = -1;

#define FLUSH() { half_t* ag = aggh + (size_t)curRcv * CSH + lane; \
    _Pragma("unroll") for (int jj = 0; jj < 9; jj++) ag[jj << 6] = (half_t)acc[jj]; }
#define ZFILL(FROM, TO) for (int zn = (FROM); zn < (TO); zn++) { \
    half_t* ag = aggh + (size_t)zn * CSH + lane; \
    _Pragma("unroll") for (int jj = 0; jj < 9; jj++) ag[jj << 6] = (half_t)0.0f; }

    for (int k0 = beg; k0 < end; k0 += 8) {
        int nv = end - k0; if (nv > 8) nv = 8;

#define PRE(Q) int kc##Q = (k0 + Q < end) ? k0 + Q : end - 1; \
        int rcvq##Q = crcv[kc##Q]; \
        float hupq##Q = hup[csnd[kc##Q] * C + lane];
        PRE(0) PRE(1) PRE(2) PRE(3) PRE(4) PRE(5) PRE(6) PRE(7)
#undef PRE

        float tw0[9], tw1[9], tw2[9], tw3[9], tw4[9], tw5[9], tw6[9], tw7[9];
        #pragma unroll
        for (int jj = 0; jj < 9; jj++) {
            tw0[jj] = 0.f; tw1[jj] = 0.f; tw2[jj] = 0.f; tw3[jj] = 0.f;
            tw4[jj] = 0.f; tw5[jj] = 0.f; tw6[jj] = 0.f; tw7[jj] = 0.f;
        }

        #pragma unroll
        for (int mq = 0; mq < 8; mq++) {
            f16x2 h0 = chh[kc0 * 8 + mq], h1 = chh[kc1 * 8 + mq];
            f16x2 h2 = chh[kc2 * 8 + mq], h3 = chh[kc3 * 8 + mq];
            f16x2 h4 = chh[kc4 * 8 + mq], h5 = chh[kc5 * 8 + mq];
            f16x2 h6 = chh[kc6 * 8 + mq], h7 = chh[kc7 * 8 + mq];
            #pragma unroll
            for (int jj = 0; jj < 9; jj++) {
                f16x2 wv = Wl[mq * CSH + (jj << 6) + lane];
                tw0[jj] = dot2f(h0, wv, tw0[jj]);
                tw1[jj] = dot2f(h1, wv, tw1[jj]);
                tw2[jj] = dot2f(h2, wv, tw2[jj]);
                tw3[jj] = dot2f(h3, wv, tw3[jj]);
                tw4[jj] = dot2f(h4, wv, tw4[jj]);
                tw5[jj] = dot2f(h5, wv, tw5[jj]);
                tw6[jj] = dot2f(h6, wv, tw6[jj]);
                tw7[jj] = dot2f(h7, wv, tw7[jj]);
            }
        }

#define SCAT(Q) if (Q < nv) { \
        int rcv = rcvq##Q; \
        float hupS = hupq##Q; \
        float4 sA = *(const float4*)&csh[kc##Q * 16]; \
        float4 sB = *(const float4*)&csh[kc##Q * 16 + 4]; \
        float s8v = csh[kc##Q * 16 + 8]; \
        float sh9[9] = {sA.x, sA.y, sA.z, sA.w, sB.x, sB.y, sB.z, sB.w, s8v}; \
        if (rcv != curRcv) { \
            if (curRcv >= 0) { FLUSH(); ZFILL(curRcv + 1, rcv) } else { ZFILL(nlo, rcv) } \
            curRcv = rcv; \
            _Pragma("unroll") for (int jj = 0; jj < 9; jj++) acc[jj] = tw##Q[jj] * (hupS * sh9[jj]); \
        } else { \
            _Pragma("unroll") for (int jj = 0; jj < 9; jj++) acc[jj] += tw##Q[jj] * (hupS * sh9[jj]); \
        } }
        SCAT(0) SCAT(1) SCAT(2) SCAT(3) SCAT(4) SCAT(5) SCAT(6) SCAT(7)
#undef SCAT
    }

    int zfrom = nlo;
    if (curRcv >= 0) { FLUSH(); zfrom = curRcv + 1; }
    ZFILL(zfrom, nhi)
#undef FLUSH
#undef ZFILL
}

// ---------------------------------------------------------------------------
// K5 (MFMA, fused epilogues): hnew = [aggh | hh] @ [Wmix/32 ; Wself]
// RMODE 0: epilogue writes rep1 = hnew.wread, hh = f16(hnew), and
//          hup = hnew @ Wup[1] via a second MFMA stage. (no f32 hnew write)
// RMODE 1: epilogue writes rep2 = silu(hnew @ Wm1).wm2 only.
// One wave per 16 nodes. A-frag row=lane&15, k=ks*32+(lane>>4)*8+e.
// C/D: col=lane&15, row=(lane>>4)*4+reg (m89-verified).
// ---------------------------------------------------------------------------
template <int RMODE>
__global__ __launch_bounds__(64) void k_mixm(
    const half_t* __restrict__ aggh, half_t* __restrict__ hh,
    const f16x8* __restrict__ wf, const f16x8* __restrict__ wupf,
    const float* __restrict__ wread, const float* __restrict__ Wm1,
    const float* __restrict__ wm2,
    float* __restrict__ hup, float* __restrict__ rep)
{
    __shared__ half_t Hs[16 * 72];   // RMODE0: f16 hnew tile (pad 72)
    __shared__ float  Hn[16 * 68];   // RMODE1: f32 hnew tile (pad 68)
    __shared__ float  W1l[C * MLPH]; // RMODE1: Wm1 stage

    int lane = threadIdx.x & 63;
    int base = blockIdx.x * 16;
    int rowA = base + (lane & 15);
    int kg = (lane >> 4) << 3;     // 0,8,16,24

    if (RMODE == 1) {
        #pragma unroll
        for (int it = 0; it < 16; it++) W1l[lane + 64 * it] = Wm1[lane + 64 * it];
    }

    f32x4 acc0 = {0.f, 0.f, 0.f, 0.f};
    f32x4 acc1 = {0.f, 0.f, 0.f, 0.f};
    f32x4 acc2 = {0.f, 0.f, 0.f, 0.f};
    f32x4 acc3 = {0.f, 0.f, 0.f, 0.f};

    const half_t* arow = aggh + (size_t)rowA * CSH + kg;
    const half_t* hrow = hh + (size_t)rowA * C + kg;

    #pragma unroll
    for (int ks = 0; ks < 20; ks++) {
        f16x8 a = (ks < 18) ? *(const f16x8*)(arow + ks * 32)
                            : *(const f16x8*)(hrow + (ks - 18) * 32);
        const f16x8* bp = wf + (size_t)(ks * 4) * 64 + lane;
        acc0 = __builtin_amdgcn_mfma_f32_16x16x32_f16(a, bp[0],   acc0, 0, 0, 0);
        acc1 = __builtin_amdgcn_mfma_f32_16x16x32_f16(a, bp[64],  acc1, 0, 0, 0);
        acc2 = __builtin_amdgcn_mfma_f32_16x16x32_f16(a, bp[128], acc2, 0, 0, 0);
        acc3 = __builtin_amdgcn_mfma_f32_16x16x32_f16(a, bp[192], acc3, 0, 0, 0);
    }

    int colb = lane & 15;
    int rowb = base + ((lane >> 4) << 2);
    int rloc = (lane >> 4) << 2;

    if (RMODE == 0) {
        // rep1 = hnew . wread (register dot + 16-lane xor reduce)
        float wr0 = wread[colb], wr1 = wread[colb + 16];
        float wr2 = wread[colb + 32], wr3 = wread[colb + 48];
        #pragma unroll
        for (int r = 0; r < 4; r++) {
            float v = acc0[r] * wr0 + acc1[r] * wr1 + acc2[r] * wr2 + acc3[r] * wr3;
            v += __shfl_xor(v, 1); v += __shfl_xor(v, 2);
            v += __shfl_xor(v, 4); v += __shfl_xor(v, 8);
            if (colb == 0) rep[rowb + r] = v;
        }

        // stage f16 hnew tile
        #pragma unroll
        for (int r = 0; r < 4; r++) {
            Hs[(rloc + r) * 72 + colb +  0] = (half_t)acc0[r];
            Hs[(rloc + r) * 72 + colb + 16] = (half_t)acc1[r];
            Hs[(rloc + r) * 72 + colb + 32] = (half_t)acc2[r];
            Hs[(rloc + r) * 72 + colb + 48] = (half_t)acc3[r];
        }
        __syncthreads();

        // hh (next layer A-extension): coalesced copy out
        #pragma unroll
        for (int it = 0; it < 2; it++) {
            int idx = lane + 64 * it;         // 0..127 chunks of 8 f16
            int row = idx >> 3, cq = idx & 7;
            *(float4*)&hh[(size_t)(base + row) * C + cq * 8] =
                *(const float4*)&Hs[row * 72 + cq * 8];
        }

        // second MFMA stage: hup = hnew @ Wup[1]
        f32x4 u0 = {0.f,0.f,0.f,0.f}, u1 = {0.f,0.f,0.f,0.f};
        f32x4 u2 = {0.f,0.f,0.f,0.f}, u3 = {0.f,0.f,0.f,0.f};
        #pragma unroll
        for (int ks = 0; ks < 2; ks++) {
            f16x8 a = *(const f16x8*)&Hs[(lane & 15) * 72 + kg + ks * 32];
            const f16x8* bp = wupf + (size_t)(ks * 4) * 64 + lane;
            u0 = __builtin_amdgcn_mfma_f32_16x16x32_f16(a, bp[0],   u0, 0, 0, 0);
            u1 = __builtin_amdgcn_mfma_f32_16x16x32_f16(a, bp[64],  u1, 0, 0, 0);
            u2 = __builtin_amdgcn_mfma_f32_16x16x32_f16(a, bp[128], u2, 0, 0, 0);
            u3 = __builtin_amdgcn_mfma_f32_16x16x32_f16(a, bp[192], u3, 0, 0, 0);
        }
        #pragma unroll
        for (int r = 0; r < 4; r++) {
            float* hp = hup + (size_t)(rowb + r) * C + colb;
            hp[0]  = u0[r];
            hp[16] = u1[r];
            hp[32] = u2[r];
            hp[48] = u3[r];
        }
    } else {
        // rep2 = silu(hnew @ Wm1) . wm2
        #pragma unroll
        for (int r = 0; r < 4; r++) {
            Hn[(rloc + r) * 68 + colb +  0] = acc0[r];
            Hn[(rloc + r) * 68 + colb + 16] = acc1[r];
            Hn[(rloc + r) * 68 + colb + 32] = acc2[r];
            Hn[(rloc + r) * 68 + colb + 48] = acc3[r];
        }
        __syncthreads();
        int n = lane & 15, q = lane >> 4;
        float a2[4] = {0.f, 0.f, 0.f, 0.f};
        #pragma unroll 8
        for (int c = 0; c < C; c++) {
            float hv = Hn[n * 68 + c];
            #pragma unroll
            for (int j = 0; j < 4; j++) a2[j] += hv * W1l[c * MLPH + 4 * q + j];
        }
        float rv = 0.0f;
        #pragma unroll
        for (int j = 0; j < 4; j++) rv += silu_f(a2[j]) * wm2[4 * q + j];
        rv += __shfl_xor(rv, 16);
        rv += __shfl_xor(rv, 32);
        if (lane < 16) rep[base + n] = rv;
    }
}

// ---------------------------------------------------------------------------
extern "C" void kernel_launch(void* const* d_in, const int* in_sizes, int n_in,
                              void* d_out, int out_size, void* d_ws, size_t ws_size,
                              hipStream_t stream) {
    const float* pos    = (const float*)d_in[0];
    const float* na     = (const float*)d_in[1];
    const float* shifts = (const float*)d_in[2];
    const int*   ei     = (const int*)d_in[3];
    const float* ae     = (const float*)d_in[4];
    const float* We     = (const float*)d_in[5];
    const float* Wup    = (const float*)d_in[6];
    const float* Wr1    = (const float*)d_in[7];
    const float* Wr2    = (const float*)d_in[8];
    const float* Wmix   = (const float*)d_in[9];
    const float* Wself  = (const float*)d_in[10];
    const float* wread  = (const float*)d_in[11];
    const float* Wm1    = (const float*)d_in[12];
    const float* wm2    = (const float*)d_in[13];
    float* out = (float*)d_out;

    char* ws = (char*)d_ws;
    size_t off = 0;
    auto alloc = [&](size_t bytes) {
        off = (off + 255) & ~(size_t)255;
        void* p = ws + off;
        off += bytes;
        return p;
    };
    int*   cnt     = (int*)alloc(4);
    int*   deg     = (int*)alloc((size_t)N_NODES * 4);
    int*   rowptr  = (int*)alloc((size_t)(N_NODES + 1) * 4);
    int*   cursor  = (int*)alloc((size_t)N_NODES * 4);
    int*   wstart  = (int*)alloc((size_t)(NWAVES + 1) * 4);
    f16x2* wlth    = (f16x2*)alloc((size_t)2 * 8 * CSH * 4);
    f16x8* wmixf   = (f16x8*)alloc((size_t)2 * 5120 * 16);
    f16x8* wupf    = (f16x8*)alloc((size_t)512 * 16);
    int*   perm    = (int*)alloc((size_t)N_EDGES * 4);
    int*   act_snd = (int*)alloc((size_t)N_EDGES * 4);
    int*   act_rcv = (int*)alloc((size_t)N_EDGES * 4);
    float* act_u   = (float*)alloc((size_t)N_EDGES * 4 * 4);
    float* act_ef  = (float*)alloc((size_t)N_EDGES * 8 * 4);
    int*   csnd    = (int*)alloc((size_t)N_EDGES * 4);
    int*   crcv    = (int*)alloc((size_t)N_EDGES * 4);
    float* csh     = (float*)alloc((size_t)N_EDGES * 16 * 4);
    f16x2* chidh0  = (f16x2*)alloc((size_t)N_EDGES * 8 * 4);
    f16x2* chidh1  = (f16x2*)alloc((size_t)N_EDGES * 8 * 4);
    float* hA      = (float*)alloc((size_t)N_NODES * C * 4);
    float* hup     = (float*)alloc((size_t)N_NODES * C * 4);
    half_t* hh     = (half_t*)alloc((size_t)N_NODES * C * 2);
    half_t* aggh   = (half_t*)alloc((size_t)N_NODES * CSH * 2);

    hipMemsetAsync(cnt, 0, 4, stream);
    hipMemsetAsync(deg, 0, (size_t)N_NODES * 4, stream);

    k_edge<<<(N_NODES * C) / 256, 256, 0, stream>>>(pos, shifts, ei, na, We, ae,
                                                    cnt, deg, act_snd, act_rcv,
                                                    act_u, act_ef, hA, out);
    k_scan<<<1, 256, 0, stream>>>(deg, rowptr, cursor);
    k_rank<<<N_EDGES / 256, 256, 0, stream>>>(cnt, act_rcv, Wr2, Wmix, Wself, Wup,
                                              rowptr, cursor, wstart, wlth,
                                              wmixf, wupf, perm);
    k_permute<<<N_EDGES / 256, 256, 0, stream>>>(cnt, perm, act_snd, act_rcv,
                                                 act_u, act_ef, Wr1,
                                                 csnd, crcv, csh, chidh0, chidh1);

    // ---- layer t = 0 ----
    k_up<<<N_NODES / 4, 256, 0, stream>>>(hA, Wup, hup, hh);
    k_msg5<<<GRID_MSG, 256, 0, stream>>>(rowptr, wstart, csnd, crcv, csh,
                                         chidh0, wlth, hup, aggh);
    k_mixm<0><<<N_NODES / 16, 64, 0, stream>>>(aggh, hh, wmixf, wupf,
                                               wread, Wm1, wm2,
                                               hup, out + N_NODES);

    // ---- layer t = 1 ----
    k_msg5<<<GRID_MSG, 256, 0, stream>>>(rowptr, wstart, csnd, crcv, csh,
                                         chidh1, wlth + 8 * CSH, hup, aggh);
    k_mixm<1><<<N_NODES / 16, 64, 0, stream>>>(aggh, hh, wmixf + 5120, wupf,
                                               wread, Wm1, wm2,
                                               hup, out + 2 * N_NODES);
}

// Round 12
// 148.391 us; speedup vs baseline: 2.1978x; 1.1209x over previous
//
#include <hip/hip_runtime.h>
#include <math.h>

#define N_NODES 10000
#define N_EDGES 160000
#define NEL 10
#define C 64
#define NB 8
#define SHD 9
#define MLPH 16
#define CSH 576
#define R_MAX 5.0f
#define INV_AVG 0.03125f
#define SCAN_CH 40     // 256*40 = 10240 >= N_NODES
#define GRID_MSG 2048
#define NWAVES (GRID_MSG * 4)
#define WBASE (N_EDGES - 2 * 8 * CSH)   // wlth side-job region in k_rank
#define WB2   (WBASE - 10240)           // wmixf side-job region
#define WB3   (WB2 - 512)               // wupf (layer-1 Wup fragments)

typedef _Float16 f16x2 __attribute__((ext_vector_type(2)));
typedef _Float16 f16x8 __attribute__((ext_vector_type(8)));
typedef float    f32x4 __attribute__((ext_vector_type(4)));
typedef _Float16 half_t;

__device__ __forceinline__ float silu_f(float v) {
    return v / (1.0f + __expf(-v));
}

__device__ __forceinline__ float dot2f(f16x2 a, f16x2 b, float c) {
#if __has_builtin(__builtin_amdgcn_fdot2)
    return __builtin_amdgcn_fdot2(a, b, c, false);
#else
    return c + (float)a.x * (float)b.x + (float)a.y * (float)b.y;
#endif
}

__device__ __forceinline__ int lbound_rp(const int* __restrict__ rp, int target) {
    int lo = 0, hi = N_NODES;
    while (lo < hi) { int mid = (lo + hi) >> 1; if (rp[mid] < target) lo = mid + 1; else hi = mid; }
    return lo;
}

// ---------------------------------------------------------------------------
// K1: per-edge geometry + radial basis + active-edge compaction + degree
// histogram + FUSED embed AND h_up (layer 0): wave owns node n (lane = c),
// h row staged in LDS, hup = h @ Wup[0] computed inline; hh = f16(h).
// ---------------------------------------------------------------------------
__global__ __launch_bounds__(256) void k_edge(
    const float* __restrict__ pos, const float* __restrict__ shifts,
    const int* __restrict__ ei,
    const float* __restrict__ na, const float* __restrict__ We,
    const float* __restrict__ ae, const float* __restrict__ Wup,
    int* __restrict__ cnt, int* __restrict__ deg,
    int* __restrict__ act_snd, int* __restrict__ act_rcv,
    float* __restrict__ act_u, float* __restrict__ act_ef,
    float* __restrict__ hup, half_t* __restrict__ hh, float* __restrict__ out)
{
    __shared__ float Wl[C * C];     // 16 KB
    __shared__ float Hrow[4][C];    // 1 KB
    int i = blockIdx.x * 256 + threadIdx.x;
    int lane = threadIdx.x & 63;
    int wv = threadIdx.x >> 6;

    for (int t = threadIdx.x; t < C * C; t += 256) Wl[t] = Wup[t];

    // ---- embed: h = na @ We ; out = na @ ae ----
    {
        int n = i >> 6;
        float acc = 0.0f, e0 = 0.0f;
        #pragma unroll
        for (int k = 0; k < NEL; k++) {
            float a = na[n * NEL + k];
            acc += a * We[k * C + lane];
            e0 += a * ae[k];
        }
        Hrow[wv][lane] = acc;
        hh[i] = (half_t)acc;
        if (lane == 0) out[n] = e0;
    }
    __syncthreads();

    // ---- hup = h @ Wup[0] ----
    {
        float up = 0.0f;
        #pragma unroll 8
        for (int c = 0; c < C; c++) up += Hrow[wv][c] * Wl[c * C + lane];
        hup[i] = up;
    }

    if (blockIdx.x >= N_EDGES / 256) return;
    int e = i;
    int snd = ei[e];
    int rcv = ei[N_EDGES + e];
    float vx = pos[rcv * 3 + 0] - pos[snd * 3 + 0] + shifts[e * 3 + 0];
    float vy = pos[rcv * 3 + 1] - pos[snd * 3 + 1] + shifts[e * 3 + 1];
    float vz = pos[rcv * 3 + 2] - pos[snd * 3 + 2] + shifts[e * 3 + 2];
    float r = sqrtf(vx * vx + vy * vy + vz * vz) + 1e-9f;
    float x = r / R_MAX;
    bool active = x < 1.0f;

    unsigned long long m = __ballot(active);
    int base = 0;
    if (m) {
        int leader = __ffsll((unsigned long long)m) - 1;
        if (lane == leader) base = atomicAdd(cnt, __popcll(m));
        base = __shfl(base, leader);
    }
    if (!active) return;

    int p = base + __popcll(m & ((1ull << lane) - 1ull));
    act_snd[p] = snd;
    act_rcv[p] = rcv;
    atomicAdd(&deg[rcv], 1);

    float inv_r = 1.0f / r;
    *(float4*)&act_u[p * 4] = make_float4(vx * inv_r, vy * inv_r, vz * inv_r, r);

    float x6 = x * x * x; x6 = x6 * x6;
    float x7 = x6 * x;
    float x8 = x7 * x;
    float fc = 1.0f - 28.0f * x6 + 48.0f * x7 - 21.0f * x8;
    float theta = 3.14159265358979323846f * r / R_MAX;
    float s1 = sinf(theta), c1 = cosf(theta);
    float sn = s1, cn = c1;
    float scale = 0.6324555320336759f * inv_r * fc;   // sqrt(2/R_MAX)/r*fc
    float ef[NB];
    ef[0] = scale * sn;
    #pragma unroll
    for (int n = 1; n < NB; n++) {
        float sn1 = sn * c1 + cn * s1;
        float cn1 = cn * c1 - sn * s1;
        sn = sn1; cn = cn1;
        ef[n] = scale * sn;
    }
    *(float4*)&act_ef[p * 8 + 0] = make_float4(ef[0], ef[1], ef[2], ef[3]);
    *(float4*)&act_ef[p * 8 + 4] = make_float4(ef[4], ef[5], ef[6], ef[7]);
}

// ---------------------------------------------------------------------------
// K1b: exclusive scan of deg -> rowptr + cursor (single block, LDS-staged)
// ---------------------------------------------------------------------------
__global__ __launch_bounds__(256) void k_scan(
    const int* __restrict__ deg, int* __restrict__ rowptr, int* __restrict__ cursor)
{
    __shared__ int dl[N_NODES];   // 40 KB
    __shared__ int part[256];
    int tid = threadIdx.x;
    for (int i = tid; i < N_NODES; i += 256) dl[i] = deg[i];
    __syncthreads();

    int base = tid * SCAN_CH;
    int s = 0;
    #pragma unroll 8
    for (int i = 0; i < SCAN_CH; i++) {
        int idx = base + i;
        if (idx < N_NODES) s += dl[idx];
    }
    part[tid] = s;
    __syncthreads();
    for (int off = 1; off < 256; off <<= 1) {
        int v = (tid >= off) ? part[tid - off] : 0;
        __syncthreads();
        part[tid] += v;
        __syncthreads();
    }
    int run = part[tid] - s;
    for (int i = 0; i < SCAN_CH; i++) {
        int idx = base + i;
        if (idx < N_NODES) {
            int v = dl[idx];
            dl[idx] = run;
            run += v;
        }
    }
    __syncthreads();
    for (int i = tid; i < N_NODES; i += 256) {
        int r = dl[i];
        rowptr[i] = r;
        cursor[i] = r;
    }
    if (tid == 255) rowptr[N_NODES] = part[255];
}

// ---------------------------------------------------------------------------
// K1c: rank edges into CSR order (4B scatter) + side jobs:
//  wstart[], wlth (f16x2 Wr2), wmixf (MFMA B-frags [Wmix/32;Wself]),
//  wupf (MFMA B-frags of layer-1 Wup)
// ---------------------------------------------------------------------------
__global__ __launch_bounds__(256) void k_rank(
    const int* __restrict__ cnt, const int* __restrict__ act_rcv,
    const float* __restrict__ Wr2, const float* __restrict__ Wmix,
    const float* __restrict__ Wself, const float* __restrict__ Wup,
    const int* __restrict__ rowptr,
    int* __restrict__ cursor, int* __restrict__ wstart, f16x2* __restrict__ wlth,
    f16x8* __restrict__ wmixf, f16x8* __restrict__ wupf, int* __restrict__ perm)
{
    int i = blockIdx.x * 256 + threadIdx.x;
    int nAct = *cnt;

    if (i <= NWAVES) {
        if (i == NWAVES) {
            wstart[NWAVES] = N_NODES;
        } else {
            int S = (nAct + NWAVES - 1) / NWAVES; if (S < 1) S = 1;
            wstart[i] = lbound_rp(rowptr, i * S);
        }
    }
    if (i >= WBASE) {
        int idx = i - WBASE;                  // 0 .. 9215
        int t = idx / (8 * CSH);
        int r = idx - t * (8 * CSH);
        int mq = r / CSH, j = r - mq * CSH;
        int c = j & 63, s = j >> 6;
        float lo = Wr2[t * MLPH * CSH + (2 * mq + 0) * CSH + c * SHD + s];
        float hi = Wr2[t * MLPH * CSH + (2 * mq + 1) * CSH + c * SHD + s];
        f16x2 v; v.x = (_Float16)lo; v.y = (_Float16)hi;
        wlth[idx] = v;
    } else if (i >= WB2) {
        int idx = i - WB2;                    // 0 .. 10239
        int t = idx / 5120;
        int r = idx - t * 5120;
        int ks = r >> 8;                      // 0..19
        int rr = r & 255;
        int nt = rr >> 6;                     // 0..3
        int ln = rr & 63;
        f16x8 v;
        #pragma unroll
        for (int e = 0; e < 8; e++) {
            int k = ks * 32 + ((ln >> 4) << 3) + e;
            int col = nt * 16 + (ln & 15);
            float x;
            if (k < CSH)
                x = Wmix[(size_t)t * CSH * C + ((k & 63) * SHD + (k >> 6)) * C + col] * INV_AVG;
            else
                x = Wself[(size_t)t * C * C + (k - CSH) * C + col];
            v[e] = (_Float16)x;
        }
        wmixf[(size_t)((t * 20 + ks) * 4 + nt) * 64 + ln] = v;
    } else if (i >= WB3) {
        int idx = i - WB3;                    // 0 .. 511
        int ks = idx >> 8;                    // 0..1
        int rr = idx & 255;
        int nt = rr >> 6;
        int ln = rr & 63;
        f16x8 v;
        #pragma unroll
        for (int e = 0; e < 8; e++) {
            int k = ks * 32 + ((ln >> 4) << 3) + e;
            int col = nt * 16 + (ln & 15);
            v[e] = (_Float16)Wup[C * C + k * C + col];   // layer-1 Wup
        }
        wupf[(size_t)(ks * 4 + nt) * 64 + ln] = v;
    }
    if (i >= nAct) return;
    int pos = atomicAdd(&cursor[act_rcv[i]], 1);
    perm[pos] = i;
}

// ---------------------------------------------------------------------------
// K1d: permute payloads into CSR order: gathered reads, COALESCED writes.
// ---------------------------------------------------------------------------
__global__ __launch_bounds__(256) void k_permute(
    const int* __restrict__ cnt, const int* __restrict__ perm,
    const int* __restrict__ act_snd, const int* __restrict__ act_rcv,
    const float* __restrict__ act_u, const float* __restrict__ act_ef,
    const float* __restrict__ Wr1,
    int* __restrict__ csnd, int* __restrict__ crcv, float* __restrict__ csh,
    f16x2* __restrict__ chidh0, f16x2* __restrict__ chidh1)
{
    int p = blockIdx.x * 256 + threadIdx.x;
    if (p >= *cnt) return;
    int i = perm[p];

    csnd[p] = act_snd[i];
    crcv[p] = act_rcv[i];

    float4 u4 = *(const float4*)&act_u[i * 4];
    float ux = u4.x, uy = u4.y, uz = u4.z;
    const float s3 = 1.7320508075688772f;
    const float s5 = 2.23606797749979f;
    const float s15 = 3.872983346207417f;
    *(float4*)&csh[p * 16 + 0] = make_float4(1.0f, s3 * ux, s3 * uy, s3 * uz);
    *(float4*)&csh[p * 16 + 4] = make_float4(s15 * ux * uy, s15 * uy * uz,
                                             0.5f * s5 * (3.0f * uz * uz - 1.0f),
                                             s15 * ux * uz);
    csh[p * 16 + 8] = 0.5f * s15 * (ux * ux - uy * uy);

    float4 e0 = *(const float4*)&act_ef[i * 8 + 0];
    float4 e1 = *(const float4*)&act_ef[i * 8 + 4];
    float ef[NB] = {e0.x, e0.y, e0.z, e0.w, e1.x, e1.y, e1.z, e1.w};

    #pragma unroll
    for (int t = 0; t < 2; t++) {
        f16x2* dst = (t == 0) ? chidh0 : chidh1;
        const float* W = Wr1 + t * NB * MLPH;
        f16x2 hv2[8];
        #pragma unroll
        for (int mp = 0; mp < 8; mp++) {
            float a0 = 0.0f, a1 = 0.0f;
            #pragma unroll
            for (int b = 0; b < NB; b++) {
                float efb = ef[b];
                a0 += efb * W[b * MLPH + 2 * mp + 0];
                a1 += efb * W[b * MLPH + 2 * mp + 1];
            }
            f16x2 v; v.x = (_Float16)silu_f(a0); v.y = (_Float16)silu_f(a1);
            hv2[mp] = v;
        }
        *(float4*)&dst[p * 8 + 0] = *(float4*)&hv2[0];
        *(float4*)&dst[p * 8 + 4] = *(float4*)&hv2[4];
    }
}

// ---------------------------------------------------------------------------
// K4 (hot): segmented-CSR message pass, zero atomics, zero shuffles.
// 4-edge groups (tw = 36 VGPRs, targeting <=128 total for 16 waves/CU).
// agg written as f16 (s-major j) -> feeds k_mixm's MFMA A operand directly.
// ---------------------------------------------------------------------------
__global__ __launch_bounds__(256) void k_msg5(
    const int* __restrict__ rowptr, const int* __restrict__ wstart,
    const int* __restrict__ csnd, const int* __restrict__ crcv,
    const float* __restrict__ csh, const f16x2* __restrict__ chh,
    const f16x2* __restrict__ wlth, const float* __restrict__ hup,
    half_t* __restrict__ aggh)
{
    __shared__ f16x2 Wl[8 * CSH];   // 18 KB, [m-pair][j s-major]
    {
        const float4* src = (const float4*)wlth;
        float4* dst = (float4*)Wl;
        for (int i = threadIdx.x; i < (8 * CSH) / 4; i += 256) dst[i] = src[i];
    }
    __syncthreads();

    int lane = threadIdx.x & 63;
    int w = (blockIdx.x << 2) | (threadIdx.x >> 6);
    int nlo = wstart[w];
    int nhi = wstart[w + 1];
    if (nlo >= nhi) return;
    int beg = rowptr[nlo], end = rowptr[nhi];

    float acc[9];
    int curRcv = -1;

#define FLUSH() { half_t* ag = aggh + (size_t)curRcv * CSH + lane; \
    _Pragma("unroll") for (int jj = 0; jj < 9; jj++) ag[jj << 6] = (half_t)acc[jj]; }
#define ZFILL(FROM, TO) for (int zn = (FROM); zn < (TO); zn++) { \
    half_t* ag = aggh + (size_t)zn * CSH + lane; \
    _Pragma("unroll") for (int jj = 0; jj < 9; jj++) ag[jj << 6] = (half_t)0.0f; }

    for (int k0 = beg; k0 < end; k0 += 4) {
        int nv = end - k0; if (nv > 4) nv = 4;

#define PRE(Q) int kc##Q = (k0 + Q < end) ? k0 + Q : end - 1; \
        int rcvq##Q = crcv[kc##Q]; \
        float hupq##Q = hup[csnd[kc##Q] * C + lane];
        PRE(0) PRE(1) PRE(2) PRE(3)
#undef PRE

        float tw0[9], tw1[9], tw2[9], tw3[9];
        #pragma unroll
        for (int jj = 0; jj < 9; jj++) {
            tw0[jj] = 0.f; tw1[jj] = 0.f; tw2[jj] = 0.f; tw3[jj] = 0.f;
        }

        #pragma unroll
        for (int mq = 0; mq < 8; mq++) {
            f16x2 h0 = chh[kc0 * 8 + mq], h1 = chh[kc1 * 8 + mq];
            f16x2 h2 = chh[kc2 * 8 + mq], h3 = chh[kc3 * 8 + mq];
            #pragma unroll
            for (int jj = 0; jj < 9; jj++) {
                f16x2 wv = Wl[mq * CSH + (jj << 6) + lane];
                tw0[jj] = dot2f(h0, wv, tw0[jj]);
                tw1[jj] = dot2f(h1, wv, tw1[jj]);
                tw2[jj] = dot2f(h2, wv, tw2[jj]);
                tw3[jj] = dot2f(h3, wv, tw3[jj]);
            }
        }

#define SCAT(Q) if (Q < nv) { \
        int rcv = rcvq##Q; \
        float hupS = hupq##Q; \
        float4 sA = *(const float4*)&csh[kc##Q * 16]; \
        float4 sB = *(const float4*)&csh[kc##Q * 16 + 4]; \
        float s8v = csh[kc##Q * 16 + 8]; \
        float sh9[9] = {sA.x, sA.y, sA.z, sA.w, sB.x, sB.y, sB.z, sB.w, s8v}; \
        if (rcv != curRcv) { \
            if (curRcv >= 0) { FLUSH(); ZFILL(curRcv + 1, rcv) } else { ZFILL(nlo, rcv) } \
            curRcv = rcv; \
            _Pragma("unroll") for (int jj = 0; jj < 9; jj++) acc[jj] = tw##Q[jj] * (hupS * sh9[jj]); \
        } else { \
            _Pragma("unroll") for (int jj = 0; jj < 9; jj++) acc[jj] += tw##Q[jj] * (hupS * sh9[jj]); \
        } }
        SCAT(0) SCAT(1) SCAT(2) SCAT(3)
#undef SCAT
    }

    int zfrom = nlo;
    if (curRcv >= 0) { FLUSH(); zfrom = curRcv + 1; }
    ZFILL(zfrom, nhi)
#undef FLUSH
#undef ZFILL
}

// ---------------------------------------------------------------------------
// K5 (MFMA, fused epilogues): hnew = [aggh | hh] @ [Wmix/32 ; Wself]
// RMODE 0: writes rep1, hh = f16(hnew), hup = hnew @ Wup[1] (2nd MFMA stage)
// RMODE 1: writes rep2 = silu(hnew @ Wm1).wm2 only
// ---------------------------------------------------------------------------
template <int RMODE>
__global__ __launch_bounds__(64) void k_mixm(
    const half_t* __restrict__ aggh, half_t* __restrict__ hh,
    const f16x8* __restrict__ wf, const f16x8* __restrict__ wupf,
    const float* __restrict__ wread, const float* __restrict__ Wm1,
    const float* __restrict__ wm2,
    float* __restrict__ hup, float* __restrict__ rep)
{
    __shared__ half_t Hs[16 * 72];   // RMODE0: f16 hnew tile (pad 72)
    __shared__ float  Hn[16 * 68];   // RMODE1: f32 hnew tile (pad 68)
    __shared__ float  W1l[C * MLPH]; // RMODE1: Wm1 stage

    int lane = threadIdx.x & 63;
    int base = blockIdx.x * 16;
    int rowA = base + (lane & 15);
    int kg = (lane >> 4) << 3;     // 0,8,16,24

    if (RMODE == 1) {
        #pragma unroll
        for (int it = 0; it < 16; it++) W1l[lane + 64 * it] = Wm1[lane + 64 * it];
    }

    f32x4 acc0 = {0.f, 0.f, 0.f, 0.f};
    f32x4 acc1 = {0.f, 0.f, 0.f, 0.f};
    f32x4 acc2 = {0.f, 0.f, 0.f, 0.f};
    f32x4 acc3 = {0.f, 0.f, 0.f, 0.f};

    const half_t* arow = aggh + (size_t)rowA * CSH + kg;
    const half_t* hrow = hh + (size_t)rowA * C + kg;

    #pragma unroll
    for (int ks = 0; ks < 20; ks++) {
        f16x8 a = (ks < 18) ? *(const f16x8*)(arow + ks * 32)
                            : *(const f16x8*)(hrow + (ks - 18) * 32);
        const f16x8* bp = wf + (size_t)(ks * 4) * 64 + lane;
        acc0 = __builtin_amdgcn_mfma_f32_16x16x32_f16(a, bp[0],   acc0, 0, 0, 0);
        acc1 = __builtin_amdgcn_mfma_f32_16x16x32_f16(a, bp[64],  acc1, 0, 0, 0);
        acc2 = __builtin_amdgcn_mfma_f32_16x16x32_f16(a, bp[128], acc2, 0, 0, 0);
        acc3 = __builtin_amdgcn_mfma_f32_16x16x32_f16(a, bp[192], acc3, 0, 0, 0);
    }

    int colb = lane & 15;
    int rowb = base + ((lane >> 4) << 2);
    int rloc = (lane >> 4) << 2;

    if (RMODE == 0) {
        float wr0 = wread[colb], wr1 = wread[colb + 16];
        float wr2 = wread[colb + 32], wr3 = wread[colb + 48];
        #pragma unroll
        for (int r = 0; r < 4; r++) {
            float v = acc0[r] * wr0 + acc1[r] * wr1 + acc2[r] * wr2 + acc3[r] * wr3;
            v += __shfl_xor(v, 1); v += __shfl_xor(v, 2);
            v += __shfl_xor(v, 4); v += __shfl_xor(v, 8);
            if (colb == 0) rep[rowb + r] = v;
        }

        #pragma unroll
        for (int r = 0; r < 4; r++) {
            Hs[(rloc + r) * 72 + colb +  0] = (half_t)acc0[r];
            Hs[(rloc + r) * 72 + colb + 16] = (half_t)acc1[r];
            Hs[(rloc + r) * 72 + colb + 32] = (half_t)acc2[r];
            Hs[(rloc + r) * 72 + colb + 48] = (half_t)acc3[r];
        }
        __syncthreads();

        #pragma unroll
        for (int it = 0; it < 2; it++) {
            int idx = lane + 64 * it;         // 0..127 chunks of 8 f16
            int row = idx >> 3, cq = idx & 7;
            *(float4*)&hh[(size_t)(base + row) * C + cq * 8] =
                *(const float4*)&Hs[row * 72 + cq * 8];
        }

        f32x4 u0 = {0.f,0.f,0.f,0.f}, u1 = {0.f,0.f,0.f,0.f};
        f32x4 u2 = {0.f,0.f,0.f,0.f}, u3 = {0.f,0.f,0.f,0.f};
        #pragma unroll
        for (int ks = 0; ks < 2; ks++) {
            f16x8 a = *(const f16x8*)&Hs[(lane & 15) * 72 + kg + ks * 32];
            const f16x8* bp = wupf + (size_t)(ks * 4) * 64 + lane;
            u0 = __builtin_amdgcn_mfma_f32_16x16x32_f16(a, bp[0],   u0, 0, 0, 0);
            u1 = __builtin_amdgcn_mfma_f32_16x16x32_f16(a, bp[64],  u1, 0, 0, 0);
            u2 = __builtin_amdgcn_mfma_f32_16x16x32_f16(a, bp[128], u2, 0, 0, 0);
            u3 = __builtin_amdgcn_mfma_f32_16x16x32_f16(a, bp[192], u3, 0, 0, 0);
        }
        #pragma unroll
        for (int r = 0; r < 4; r++) {
            float* hp = hup + (size_t)(rowb + r) * C + colb;
            hp[0]  = u0[r];
            hp[16] = u1[r];
            hp[32] = u2[r];
            hp[48] = u3[r];
        }
    } else {
        #pragma unroll
        for (int r = 0; r < 4; r++) {
            Hn[(rloc + r) * 68 + colb +  0] = acc0[r];
            Hn[(rloc + r) * 68 + colb + 16] = acc1[r];
            Hn[(rloc + r) * 68 + colb + 32] = acc2[r];
            Hn[(rloc + r) * 68 + colb + 48] = acc3[r];
        }
        __syncthreads();
        int n = lane & 15, q = lane >> 4;
        float a2[4] = {0.f, 0.f, 0.f, 0.f};
        #pragma unroll 8
        for (int c = 0; c < C; c++) {
            float hv = Hn[n * 68 + c];
            #pragma unroll
            for (int j = 0; j < 4; j++) a2[j] += hv * W1l[c * MLPH + 4 * q + j];
        }
        float rv = 0.0f;
        #pragma unroll
        for (int j = 0; j < 4; j++) rv += silu_f(a2[j]) * wm2[4 * q + j];
        rv += __shfl_xor(rv, 16);
        rv += __shfl_xor(rv, 32);
        if (lane < 16) rep[base + n] = rv;
    }
}

// ---------------------------------------------------------------------------
extern "C" void kernel_launch(void* const* d_in, const int* in_sizes, int n_in,
                              void* d_out, int out_size, void* d_ws, size_t ws_size,
                              hipStream_t stream) {
    const float* pos    = (const float*)d_in[0];
    const float* na     = (const float*)d_in[1];
    const float* shifts = (const float*)d_in[2];
    const int*   ei     = (const int*)d_in[3];
    const float* ae     = (const float*)d_in[4];
    const float* We     = (const float*)d_in[5];
    const float* Wup    = (const float*)d_in[6];
    const float* Wr1    = (const float*)d_in[7];
    const float* Wr2    = (const float*)d_in[8];
    const float* Wmix   = (const float*)d_in[9];
    const float* Wself  = (const float*)d_in[10];
    const float* wread  = (const float*)d_in[11];
    const float* Wm1    = (const float*)d_in[12];
    const float* wm2    = (const float*)d_in[13];
    float* out = (float*)d_out;

    char* ws = (char*)d_ws;
    size_t off = 0;
    auto alloc = [&](size_t bytes) {
        off = (off + 255) & ~(size_t)255;
        void* p = ws + off;
        off += bytes;
        return p;
    };
    int*   cnt     = (int*)alloc(4);
    int*   deg     = (int*)alloc((size_t)N_NODES * 4);
    int*   rowptr  = (int*)alloc((size_t)(N_NODES + 1) * 4);
    int*   cursor  = (int*)alloc((size_t)N_NODES * 4);
    int*   wstart  = (int*)alloc((size_t)(NWAVES + 1) * 4);
    f16x2* wlth    = (f16x2*)alloc((size_t)2 * 8 * CSH * 4);
    f16x8* wmixf   = (f16x8*)alloc((size_t)2 * 5120 * 16);
    f16x8* wupf    = (f16x8*)alloc((size_t)512 * 16);
    int*   perm    = (int*)alloc((size_t)N_EDGES * 4);
    int*   act_snd = (int*)alloc((size_t)N_EDGES * 4);
    int*   act_rcv = (int*)alloc((size_t)N_EDGES * 4);
    float* act_u   = (float*)alloc((size_t)N_EDGES * 4 * 4);
    float* act_ef  = (float*)alloc((size_t)N_EDGES * 8 * 4);
    int*   csnd    = (int*)alloc((size_t)N_EDGES * 4);
    int*   crcv    = (int*)alloc((size_t)N_EDGES * 4);
    float* csh     = (float*)alloc((size_t)N_EDGES * 16 * 4);
    f16x2* chidh0  = (f16x2*)alloc((size_t)N_EDGES * 8 * 4);
    f16x2* chidh1  = (f16x2*)alloc((size_t)N_EDGES * 8 * 4);
    float* hup     = (float*)alloc((size_t)N_NODES * C * 4);
    half_t* hh     = (half_t*)alloc((size_t)N_NODES * C * 2);
    half_t* aggh   = (half_t*)alloc((size_t)N_NODES * CSH * 2);

    hipMemsetAsync(cnt, 0, 4, stream);
    hipMemsetAsync(deg, 0, (size_t)N_NODES * 4, stream);

    k_edge<<<(N_NODES * C) / 256, 256, 0, stream>>>(pos, shifts, ei, na, We, ae, Wup,
                                                    cnt, deg, act_snd, act_rcv,
                                                    act_u, act_ef, hup, hh, out);
    k_scan<<<1, 256, 0, stream>>>(deg, rowptr, cursor);
    k_rank<<<N_EDGES / 256, 256, 0, stream>>>(cnt, act_rcv, Wr2, Wmix, Wself, Wup,
                                              rowptr, cursor, wstart, wlth,
                                              wmixf, wupf, perm);
    k_permute<<<N_EDGES / 256, 256, 0, stream>>>(cnt, perm, act_snd, act_rcv,
                                                 act_u, act_ef, Wr1,
                                                 csnd, crcv, csh, chidh0, chidh1);

    // ---- layer t = 0 ----
    k_msg5<<<GRID_MSG, 256, 0, stream>>>(rowptr, wstart, csnd, crcv, csh,
                                         chidh0, wlth, hup, aggh);
    k_mixm<0><<<N_NODES / 16, 64, 0, stream>>>(aggh, hh, wmixf, wupf,
                                               wread, Wm1, wm2,
                                               hup, out + N_NODES);

    // ---- layer t = 1 ----
    k_msg5<<<GRID_MSG, 256, 0, stream>>>(rowptr, wstart, csnd, crcv, csh,
                                         chidh1, wlth + 8 * CSH, hup, aggh);
    k_mixm<1><<<N_NODES / 16, 64, 0, stream>>>(aggh, hh, wmixf + 5120, wupf,
                                               wread, Wm1, wm2,
                                               hup, out + 2 * N_NODES);
}

// Round 13
// 134.898 us; speedup vs baseline: 2.4176x; 1.1000x over previous
//
#include <hip/hip_runtime.h>
#include <math.h>

#define N_NODES 10000
#define N_EDGES 160000
#define NEL 10
#define C 64
#define NB 8
#define SHD 9
#define MLPH 16
#define CSH 576
#define R_MAX 5.0f
#define INV_AVG 0.03125f
#define SCAN_CH 40     // 256*40 = 10240 >= N_NODES
#define GRID_MSG 768   // ~3 blocks/CU (VGPR-limited), ~15 edges/wave
#define NWAVES (GRID_MSG * 4)
#define WBASE (N_EDGES - 2 * 8 * CSH)   // wlth side-job region in k_rank
#define WB2   (WBASE - 10240)           // wmixf side-job region
#define WB3   (WB2 - 1024)              // wupf (BOTH layers' Wup fragments)

typedef _Float16 f16x2 __attribute__((ext_vector_type(2)));
typedef _Float16 f16x8 __attribute__((ext_vector_type(8)));
typedef float    f32x4 __attribute__((ext_vector_type(4)));
typedef _Float16 half_t;

__device__ __forceinline__ float silu_f(float v) {
    return v / (1.0f + __expf(-v));
}

__device__ __forceinline__ float dot2f(f16x2 a, f16x2 b, float c) {
#if __has_builtin(__builtin_amdgcn_fdot2)
    return __builtin_amdgcn_fdot2(a, b, c, false);
#else
    return c + (float)a.x * (float)b.x + (float)a.y * (float)b.y;
#endif
}

__device__ __forceinline__ int lbound_rp(const int* __restrict__ rp, int target) {
    int lo = 0, hi = N_NODES;
    while (lo < hi) { int mid = (lo + hi) >> 1; if (rp[mid] < target) lo = mid + 1; else hi = mid; }
    return lo;
}

// ---------------------------------------------------------------------------
// K1: per-edge geometry + radial basis + active-edge compaction + degree
// histogram + fused embed (h as f16 only; hup moved to k_upm MFMA kernel).
// ---------------------------------------------------------------------------
__global__ __launch_bounds__(256) void k_edge(
    const float* __restrict__ pos, const float* __restrict__ shifts,
    const int* __restrict__ ei,
    const float* __restrict__ na, const float* __restrict__ We,
    const float* __restrict__ ae,
    int* __restrict__ cnt, int* __restrict__ deg,
    int* __restrict__ act_snd, int* __restrict__ act_rcv,
    float* __restrict__ act_u, float* __restrict__ act_ef,
    half_t* __restrict__ hh, float* __restrict__ out)
{
    int i = blockIdx.x * 256 + threadIdx.x;
    int lane = threadIdx.x & 63;

    // ---- embed: h = na @ We ; out = na @ ae ----
    {
        int n = i >> 6;
        float acc = 0.0f, e0 = 0.0f;
        #pragma unroll
        for (int k = 0; k < NEL; k++) {
            float a = na[n * NEL + k];
            acc += a * We[k * C + lane];
            e0 += a * ae[k];
        }
        hh[i] = (half_t)acc;
        if (lane == 0) out[n] = e0;
    }

    if (blockIdx.x >= N_EDGES / 256) return;
    int e = i;
    int snd = ei[e];
    int rcv = ei[N_EDGES + e];
    float vx = pos[rcv * 3 + 0] - pos[snd * 3 + 0] + shifts[e * 3 + 0];
    float vy = pos[rcv * 3 + 1] - pos[snd * 3 + 1] + shifts[e * 3 + 1];
    float vz = pos[rcv * 3 + 2] - pos[snd * 3 + 2] + shifts[e * 3 + 2];
    float r = sqrtf(vx * vx + vy * vy + vz * vz) + 1e-9f;
    float x = r / R_MAX;
    bool active = x < 1.0f;

    unsigned long long m = __ballot(active);
    int base = 0;
    if (m) {
        int leader = __ffsll((unsigned long long)m) - 1;
        if (lane == leader) base = atomicAdd(cnt, __popcll(m));
        base = __shfl(base, leader);
    }
    if (!active) return;

    int p = base + __popcll(m & ((1ull << lane) - 1ull));
    act_snd[p] = snd;
    act_rcv[p] = rcv;
    atomicAdd(&deg[rcv], 1);

    float inv_r = 1.0f / r;
    *(float4*)&act_u[p * 4] = make_float4(vx * inv_r, vy * inv_r, vz * inv_r, r);

    float x6 = x * x * x; x6 = x6 * x6;
    float x7 = x6 * x;
    float x8 = x7 * x;
    float fc = 1.0f - 28.0f * x6 + 48.0f * x7 - 21.0f * x8;
    float theta = 3.14159265358979323846f * r / R_MAX;
    float s1 = sinf(theta), c1 = cosf(theta);
    float sn = s1, cn = c1;
    float scale = 0.6324555320336759f * inv_r * fc;   // sqrt(2/R_MAX)/r*fc
    float ef[NB];
    ef[0] = scale * sn;
    #pragma unroll
    for (int n = 1; n < NB; n++) {
        float sn1 = sn * c1 + cn * s1;
        float cn1 = cn * c1 - sn * s1;
        sn = sn1; cn = cn1;
        ef[n] = scale * sn;
    }
    *(float4*)&act_ef[p * 8 + 0] = make_float4(ef[0], ef[1], ef[2], ef[3]);
    *(float4*)&act_ef[p * 8 + 4] = make_float4(ef[4], ef[5], ef[6], ef[7]);
}

// ---------------------------------------------------------------------------
// K1b: exclusive scan of deg -> rowptr + cursor (single block, LDS-staged)
// ---------------------------------------------------------------------------
__global__ __launch_bounds__(256) void k_scan(
    const int* __restrict__ deg, int* __restrict__ rowptr, int* __restrict__ cursor)
{
    __shared__ int dl[N_NODES];   // 40 KB
    __shared__ int part[256];
    int tid = threadIdx.x;
    for (int i = tid; i < N_NODES; i += 256) dl[i] = deg[i];
    __syncthreads();

    int base = tid * SCAN_CH;
    int s = 0;
    #pragma unroll 8
    for (int i = 0; i < SCAN_CH; i++) {
        int idx = base + i;
        if (idx < N_NODES) s += dl[idx];
    }
    part[tid] = s;
    __syncthreads();
    for (int off = 1; off < 256; off <<= 1) {
        int v = (tid >= off) ? part[tid - off] : 0;
        __syncthreads();
        part[tid] += v;
        __syncthreads();
    }
    int run = part[tid] - s;
    for (int i = 0; i < SCAN_CH; i++) {
        int idx = base + i;
        if (idx < N_NODES) {
            int v = dl[idx];
            dl[idx] = run;
            run += v;
        }
    }
    __syncthreads();
    for (int i = tid; i < N_NODES; i += 256) {
        int r = dl[i];
        rowptr[i] = r;
        cursor[i] = r;
    }
    if (tid == 255) rowptr[N_NODES] = part[255];
}

// ---------------------------------------------------------------------------
// K1c: rank edges into CSR order (4B scatter) + side jobs:
//  wstart[], wlth (f16x2 Wr2), wmixf (MFMA B-frags [Wmix/32;Wself]),
//  wupf (MFMA B-frags of BOTH layers' Wup)
// ---------------------------------------------------------------------------
__global__ __launch_bounds__(256) void k_rank(
    const int* __restrict__ cnt, const int* __restrict__ act_rcv,
    const float* __restrict__ Wr2, const float* __restrict__ Wmix,
    const float* __restrict__ Wself, const float* __restrict__ Wup,
    const int* __restrict__ rowptr,
    int* __restrict__ cursor, int* __restrict__ wstart, f16x2* __restrict__ wlth,
    f16x8* __restrict__ wmixf, f16x8* __restrict__ wupf, int* __restrict__ perm)
{
    int i = blockIdx.x * 256 + threadIdx.x;
    int nAct = *cnt;

    if (i <= NWAVES) {
        if (i == NWAVES) {
            wstart[NWAVES] = N_NODES;
        } else {
            int S = (nAct + NWAVES - 1) / NWAVES; if (S < 1) S = 1;
            wstart[i] = lbound_rp(rowptr, i * S);
        }
    }
    if (i >= WBASE) {
        int idx = i - WBASE;                  // 0 .. 9215
        int t = idx / (8 * CSH);
        int r = idx - t * (8 * CSH);
        int mq = r / CSH, j = r - mq * CSH;
        int c = j & 63, s = j >> 6;
        float lo = Wr2[t * MLPH * CSH + (2 * mq + 0) * CSH + c * SHD + s];
        float hi = Wr2[t * MLPH * CSH + (2 * mq + 1) * CSH + c * SHD + s];
        f16x2 v; v.x = (_Float16)lo; v.y = (_Float16)hi;
        wlth[idx] = v;
    } else if (i >= WB2) {
        int idx = i - WB2;                    // 0 .. 10239
        int t = idx / 5120;
        int r = idx - t * 5120;
        int ks = r >> 8;                      // 0..19
        int rr = r & 255;
        int nt = rr >> 6;                     // 0..3
        int ln = rr & 63;
        f16x8 v;
        #pragma unroll
        for (int e = 0; e < 8; e++) {
            int k = ks * 32 + ((ln >> 4) << 3) + e;
            int col = nt * 16 + (ln & 15);
            float x;
            if (k < CSH)
                x = Wmix[(size_t)t * CSH * C + ((k & 63) * SHD + (k >> 6)) * C + col] * INV_AVG;
            else
                x = Wself[(size_t)t * C * C + (k - CSH) * C + col];
            v[e] = (_Float16)x;
        }
        wmixf[(size_t)((t * 20 + ks) * 4 + nt) * 64 + ln] = v;
    } else if (i >= WB3) {
        int idx = i - WB3;                    // 0 .. 1023
        int t = idx >> 9;                     // layer
        int r = idx & 511;
        int ks = r >> 8;                      // 0..1
        int rr = r & 255;
        int nt = rr >> 6;
        int ln = rr & 63;
        f16x8 v;
        #pragma unroll
        for (int e = 0; e < 8; e++) {
            int k = ks * 32 + ((ln >> 4) << 3) + e;
            int col = nt * 16 + (ln & 15);
            v[e] = (_Float16)Wup[(size_t)t * C * C + k * C + col];
        }
        wupf[(size_t)((t * 2 + ks) * 4 + nt) * 64 + ln] = v;
    }
    if (i >= nAct) return;
    int pos = atomicAdd(&cursor[act_rcv[i]], 1);
    perm[pos] = i;
}

// ---------------------------------------------------------------------------
// K1d: permute payloads into CSR order: gathered reads, COALESCED writes.
// ---------------------------------------------------------------------------
__global__ __launch_bounds__(256) void k_permute(
    const int* __restrict__ cnt, const int* __restrict__ perm,
    const int* __restrict__ act_snd, const int* __restrict__ act_rcv,
    const float* __restrict__ act_u, const float* __restrict__ act_ef,
    const float* __restrict__ Wr1,
    int* __restrict__ csnd, int* __restrict__ crcv, float* __restrict__ csh,
    f16x2* __restrict__ chidh0, f16x2* __restrict__ chidh1)
{
    int p = blockIdx.x * 256 + threadIdx.x;
    if (p >= *cnt) return;
    int i = perm[p];

    csnd[p] = act_snd[i];
    crcv[p] = act_rcv[i];

    float4 u4 = *(const float4*)&act_u[i * 4];
    float ux = u4.x, uy = u4.y, uz = u4.z;
    const float s3 = 1.7320508075688772f;
    const float s5 = 2.23606797749979f;
    const float s15 = 3.872983346207417f;
    *(float4*)&csh[p * 16 + 0] = make_float4(1.0f, s3 * ux, s3 * uy, s3 * uz);
    *(float4*)&csh[p * 16 + 4] = make_float4(s15 * ux * uy, s15 * uy * uz,
                                             0.5f * s5 * (3.0f * uz * uz - 1.0f),
                                             s15 * ux * uz);
    csh[p * 16 + 8] = 0.5f * s15 * (ux * ux - uy * uy);

    float4 e0 = *(const float4*)&act_ef[i * 8 + 0];
    float4 e1 = *(const float4*)&act_ef[i * 8 + 4];
    float ef[NB] = {e0.x, e0.y, e0.z, e0.w, e1.x, e1.y, e1.z, e1.w};

    #pragma unroll
    for (int t = 0; t < 2; t++) {
        f16x2* dst = (t == 0) ? chidh0 : chidh1;
        const float* W = Wr1 + t * NB * MLPH;
        f16x2 hv2[8];
        #pragma unroll
        for (int mp = 0; mp < 8; mp++) {
            float a0 = 0.0f, a1 = 0.0f;
            #pragma unroll
            for (int b = 0; b < NB; b++) {
                float efb = ef[b];
                a0 += efb * W[b * MLPH + 2 * mp + 0];
                a1 += efb * W[b * MLPH + 2 * mp + 1];
            }
            f16x2 v; v.x = (_Float16)silu_f(a0); v.y = (_Float16)silu_f(a1);
            hv2[mp] = v;
        }
        *(float4*)&dst[p * 8 + 0] = *(float4*)&hv2[0];
        *(float4*)&dst[p * 8 + 4] = *(float4*)&hv2[4];
    }
}

// ---------------------------------------------------------------------------
// K2: hup = hh @ Wup[0] via MFMA (one wave per 16 nodes, 8 MFMAs)
// ---------------------------------------------------------------------------
__global__ __launch_bounds__(64) void k_upm(
    const half_t* __restrict__ hh, const f16x8* __restrict__ wupf,
    float* __restrict__ hup)
{
    int lane = threadIdx.x & 63;
    int base = blockIdx.x * 16;
    int rowA = base + (lane & 15);
    int kg = (lane >> 4) << 3;

    f32x4 u0 = {0.f,0.f,0.f,0.f}, u1 = {0.f,0.f,0.f,0.f};
    f32x4 u2 = {0.f,0.f,0.f,0.f}, u3 = {0.f,0.f,0.f,0.f};
    const half_t* hrow = hh + (size_t)rowA * C + kg;
    #pragma unroll
    for (int ks = 0; ks < 2; ks++) {
        f16x8 a = *(const f16x8*)(hrow + ks * 32);
        const f16x8* bp = wupf + (size_t)(ks * 4) * 64 + lane;
        u0 = __builtin_amdgcn_mfma_f32_16x16x32_f16(a, bp[0],   u0, 0, 0, 0);
        u1 = __builtin_amdgcn_mfma_f32_16x16x32_f16(a, bp[64],  u1, 0, 0, 0);
        u2 = __builtin_amdgcn_mfma_f32_16x16x32_f16(a, bp[128], u2, 0, 0, 0);
        u3 = __builtin_amdgcn_mfma_f32_16x16x32_f16(a, bp[192], u3, 0, 0, 0);
    }
    int colb = lane & 15;
    int rowb = base + ((lane >> 4) << 2);
    #pragma unroll
    for (int r = 0; r < 4; r++) {
        float* hp = hup + (size_t)(rowb + r) * C + colb;
        hp[0]  = u0[r];
        hp[16] = u1[r];
        hp[32] = u2[r];
        hp[48] = u3[r];
    }
}

// ---------------------------------------------------------------------------
// K4 (hot): segmented-CSR message pass, zero atomics, zero shuffles,
// ZERO LDS: W cached in registers (72 f16x2/lane), loaded once per wave.
// 4-edge groups. agg written as f16 (s-major j).
// ---------------------------------------------------------------------------
__global__ __launch_bounds__(256) void k_msg5(
    const int* __restrict__ rowptr, const int* __restrict__ wstart,
    const int* __restrict__ csnd, const int* __restrict__ crcv,
    const float* __restrict__ csh, const f16x2* __restrict__ chh,
    const f16x2* __restrict__ wlth, const float* __restrict__ hup,
    half_t* __restrict__ aggh)
{
    int lane = threadIdx.x & 63;
    int w = (blockIdx.x << 2) | (threadIdx.x >> 6);
    int nlo = wstart[w];
    int nhi = wstart[w + 1];
    if (nlo >= nhi) return;
    int beg = rowptr[nlo], end = rowptr[nhi];

    // W working set for this lane: 72 f16x2 in registers, loaded once
    f16x2 wreg[8][9];
    #pragma unroll
    for (int mq = 0; mq < 8; mq++)
        #pragma unroll
        for (int jj = 0; jj < 9; jj++)
            wreg[mq][jj] = wlth[mq * CSH + (jj << 6) + lane];

    float acc[9];
    int curRcv = -1;

#define FLUSH() { half_t* ag = aggh + (size_t)curRcv * CSH + lane; \
    _Pragma("unroll") for (int jj = 0; jj < 9; jj++) ag[jj << 6] = (half_t)acc[jj]; }
#define ZFILL(FROM, TO) for (int zn = (FROM); zn < (TO); zn++) { \
    half_t* ag = aggh + (size_t)zn * CSH + lane; \
    _Pragma("unroll") for (int jj = 0; jj < 9; jj++) ag[jj << 6] = (half_t)0.0f; }

    for (int k0 = beg; k0 < end; k0 += 4) {
        int nv = end - k0; if (nv > 4) nv = 4;

#define PRE(Q) int kc##Q = (k0 + Q < end) ? k0 + Q : end - 1; \
        int rcvq##Q = crcv[kc##Q]; \
        float hupq##Q = hup[csnd[kc##Q] * C + lane];
        PRE(0) PRE(1) PRE(2) PRE(3)
#undef PRE

        float tw0[9], tw1[9], tw2[9], tw3[9];
        #pragma unroll
        for (int jj = 0; jj < 9; jj++) {
            tw0[jj] = 0.f; tw1[jj] = 0.f; tw2[jj] = 0.f; tw3[jj] = 0.f;
        }

        #pragma unroll
        for (int mq = 0; mq < 8; mq++) {
            f16x2 h0 = chh[kc0 * 8 + mq], h1 = chh[kc1 * 8 + mq];
            f16x2 h2 = chh[kc2 * 8 + mq], h3 = chh[kc3 * 8 + mq];
            #pragma unroll
            for (int jj = 0; jj < 9; jj++) {
                f16x2 wv = wreg[mq][jj];
                tw0[jj] = dot2f(h0, wv, tw0[jj]);
                tw1[jj] = dot2f(h1, wv, tw1[jj]);
                tw2[jj] = dot2f(h2, wv, tw2[jj]);
                tw3[jj] = dot2f(h3, wv, tw3[jj]);
            }
        }

#define SCAT(Q) if (Q < nv) { \
        int rcv = rcvq##Q; \
        float hupS = hupq##Q; \
        float4 sA = *(const float4*)&csh[kc##Q * 16]; \
        float4 sB = *(const float4*)&csh[kc##Q * 16 + 4]; \
        float s8v = csh[kc##Q * 16 + 8]; \
        float sh9[9] = {sA.x, sA.y, sA.z, sA.w, sB.x, sB.y, sB.z, sB.w, s8v}; \
        if (rcv != curRcv) { \
            if (curRcv >= 0) { FLUSH(); ZFILL(curRcv + 1, rcv) } else { ZFILL(nlo, rcv) } \
            curRcv = rcv; \
            _Pragma("unroll") for (int jj = 0; jj < 9; jj++) acc[jj] = tw##Q[jj] * (hupS * sh9[jj]); \
        } else { \
            _Pragma("unroll") for (int jj = 0; jj < 9; jj++) acc[jj] += tw##Q[jj] * (hupS * sh9[jj]); \
        } }
        SCAT(0) SCAT(1) SCAT(2) SCAT(3)
#undef SCAT
    }

    int zfrom = nlo;
    if (curRcv >= 0) { FLUSH(); zfrom = curRcv + 1; }
    ZFILL(zfrom, nhi)
#undef FLUSH
#undef ZFILL
}

// ---------------------------------------------------------------------------
// K5 (MFMA, fused epilogues): hnew = [aggh | hh] @ [Wmix/32 ; Wself]
// RMODE 0: writes rep1, hh = f16(hnew), hup = hnew @ Wup[1] (2nd MFMA stage)
// RMODE 1: writes rep2 = silu(hnew @ Wm1).wm2 only
// ---------------------------------------------------------------------------
template <int RMODE>
__global__ __launch_bounds__(64) void k_mixm(
    const half_t* __restrict__ aggh, half_t* __restrict__ hh,
    const f16x8* __restrict__ wf, const f16x8* __restrict__ wupf,
    const float* __restrict__ wread, const float* __restrict__ Wm1,
    const float* __restrict__ wm2,
    float* __restrict__ hup, float* __restrict__ rep)
{
    __shared__ half_t Hs[16 * 72];   // RMODE0: f16 hnew tile (pad 72)
    __shared__ float  Hn[16 * 68];   // RMODE1: f32 hnew tile (pad 68)
    __shared__ float  W1l[C * MLPH]; // RMODE1: Wm1 stage

    int lane = threadIdx.x & 63;
    int base = blockIdx.x * 16;
    int rowA = base + (lane & 15);
    int kg = (lane >> 4) << 3;     // 0,8,16,24

    if (RMODE == 1) {
        #pragma unroll
        for (int it = 0; it < 16; it++) W1l[lane + 64 * it] = Wm1[lane + 64 * it];
    }

    f32x4 acc0 = {0.f, 0.f, 0.f, 0.f};
    f32x4 acc1 = {0.f, 0.f, 0.f, 0.f};
    f32x4 acc2 = {0.f, 0.f, 0.f, 0.f};
    f32x4 acc3 = {0.f, 0.f, 0.f, 0.f};

    const half_t* arow = aggh + (size_t)rowA * CSH + kg;
    const half_t* hrow = hh + (size_t)rowA * C + kg;

    #pragma unroll
    for (int ks = 0; ks < 20; ks++) {
        f16x8 a = (ks < 18) ? *(const f16x8*)(arow + ks * 32)
                            : *(const f16x8*)(hrow + (ks - 18) * 32);
        const f16x8* bp = wf + (size_t)(ks * 4) * 64 + lane;
        acc0 = __builtin_amdgcn_mfma_f32_16x16x32_f16(a, bp[0],   acc0, 0, 0, 0);
        acc1 = __builtin_amdgcn_mfma_f32_16x16x32_f16(a, bp[64],  acc1, 0, 0, 0);
        acc2 = __builtin_amdgcn_mfma_f32_16x16x32_f16(a, bp[128], acc2, 0, 0, 0);
        acc3 = __builtin_amdgcn_mfma_f32_16x16x32_f16(a, bp[192], acc3, 0, 0, 0);
    }

    int colb = lane & 15;
    int rowb = base + ((lane >> 4) << 2);
    int rloc = (lane >> 4) << 2;

    if (RMODE == 0) {
        float wr0 = wread[colb], wr1 = wread[colb + 16];
        float wr2 = wread[colb + 32], wr3 = wread[colb + 48];
        #pragma unroll
        for (int r = 0; r < 4; r++) {
            float v = acc0[r] * wr0 + acc1[r] * wr1 + acc2[r] * wr2 + acc3[r] * wr3;
            v += __shfl_xor(v, 1); v += __shfl_xor(v, 2);
            v += __shfl_xor(v, 4); v += __shfl_xor(v, 8);
            if (colb == 0) rep[rowb + r] = v;
        }

        #pragma unroll
        for (int r = 0; r < 4; r++) {
            Hs[(rloc + r) * 72 + colb +  0] = (half_t)acc0[r];
            Hs[(rloc + r) * 72 + colb + 16] = (half_t)acc1[r];
            Hs[(rloc + r) * 72 + colb + 32] = (half_t)acc2[r];
            Hs[(rloc + r) * 72 + colb + 48] = (half_t)acc3[r];
        }
        __syncthreads();

        #pragma unroll
        for (int it = 0; it < 2; it++) {
            int idx = lane + 64 * it;         // 0..127 chunks of 8 f16
            int row = idx >> 3, cq = idx & 7;
            *(float4*)&hh[(size_t)(base + row) * C + cq * 8] =
                *(const float4*)&Hs[row * 72 + cq * 8];
        }

        f32x4 u0 = {0.f,0.f,0.f,0.f}, u1 = {0.f,0.f,0.f,0.f};
        f32x4 u2 = {0.f,0.f,0.f,0.f}, u3 = {0.f,0.f,0.f,0.f};
        #pragma unroll
        for (int ks = 0; ks < 2; ks++) {
            f16x8 a = *(const f16x8*)&Hs[(lane & 15) * 72 + kg + ks * 32];
            const f16x8* bp = wupf + (size_t)(ks * 4) * 64 + lane;
            u0 = __builtin_amdgcn_mfma_f32_16x16x32_f16(a, bp[0],   u0, 0, 0, 0);
            u1 = __builtin_amdgcn_mfma_f32_16x16x32_f16(a, bp[64],  u1, 0, 0, 0);
            u2 = __builtin_amdgcn_mfma_f32_16x16x32_f16(a, bp[128], u2, 0, 0, 0);
            u3 = __builtin_amdgcn_mfma_f32_16x16x32_f16(a, bp[192], u3, 0, 0, 0);
        }
        #pragma unroll
        for (int r = 0; r < 4; r++) {
            float* hp = hup + (size_t)(rowb + r) * C + colb;
            hp[0]  = u0[r];
            hp[16] = u1[r];
            hp[32] = u2[r];
            hp[48] = u3[r];
        }
    } else {
        #pragma unroll
        for (int r = 0; r < 4; r++) {
            Hn[(rloc + r) * 68 + colb +  0] = acc0[r];
            Hn[(rloc + r) * 68 + colb + 16] = acc1[r];
            Hn[(rloc + r) * 68 + colb + 32] = acc2[r];
            Hn[(rloc + r) * 68 + colb + 48] = acc3[r];
        }
        __syncthreads();
        int n = lane & 15, q = lane >> 4;
        float a2[4] = {0.f, 0.f, 0.f, 0.f};
        #pragma unroll 8
        for (int c = 0; c < C; c++) {
            float hv = Hn[n * 68 + c];
            #pragma unroll
            for (int j = 0; j < 4; j++) a2[j] += hv * W1l[c * MLPH + 4 * q + j];
        }
        float rv = 0.0f;
        #pragma unroll
        for (int j = 0; j < 4; j++) rv += silu_f(a2[j]) * wm2[4 * q + j];
        rv += __shfl_xor(rv, 16);
        rv += __shfl_xor(rv, 32);
        if (lane < 16) rep[base + n] = rv;
    }
}

// ---------------------------------------------------------------------------
extern "C" void kernel_launch(void* const* d_in, const int* in_sizes, int n_in,
                              void* d_out, int out_size, void* d_ws, size_t ws_size,
                              hipStream_t stream) {
    const float* pos    = (const float*)d_in[0];
    const float* na     = (const float*)d_in[1];
    const float* shifts = (const float*)d_in[2];
    const int*   ei     = (const int*)d_in[3];
    const float* ae     = (const float*)d_in[4];
    const float* We     = (const float*)d_in[5];
    const float* Wup    = (const float*)d_in[6];
    const float* Wr1    = (const float*)d_in[7];
    const float* Wr2    = (const float*)d_in[8];
    const float* Wmix   = (const float*)d_in[9];
    const float* Wself  = (const float*)d_in[10];
    const float* wread  = (const float*)d_in[11];
    const float* Wm1    = (const float*)d_in[12];
    const float* wm2    = (const float*)d_in[13];
    float* out = (float*)d_out;

    char* ws = (char*)d_ws;
    size_t off = 0;
    auto alloc = [&](size_t bytes) {
        off = (off + 255) & ~(size_t)255;
        void* p = ws + off;
        off += bytes;
        return p;
    };
    int*   cnt     = (int*)alloc(4);
    int*   deg     = (int*)alloc((size_t)N_NODES * 4);
    int*   rowptr  = (int*)alloc((size_t)(N_NODES + 1) * 4);
    int*   cursor  = (int*)alloc((size_t)N_NODES * 4);
    int*   wstart  = (int*)alloc((size_t)(NWAVES + 1) * 4);
    f16x2* wlth    = (f16x2*)alloc((size_t)2 * 8 * CSH * 4);
    f16x8* wmixf   = (f16x8*)alloc((size_t)2 * 5120 * 16);
    f16x8* wupf    = (f16x8*)alloc((size_t)1024 * 16);
    int*   perm    = (int*)alloc((size_t)N_EDGES * 4);
    int*   act_snd = (int*)alloc((size_t)N_EDGES * 4);
    int*   act_rcv = (int*)alloc((size_t)N_EDGES * 4);
    float* act_u   = (float*)alloc((size_t)N_EDGES * 4 * 4);
    float* act_ef  = (float*)alloc((size_t)N_EDGES * 8 * 4);
    int*   csnd    = (int*)alloc((size_t)N_EDGES * 4);
    int*   crcv    = (int*)alloc((size_t)N_EDGES * 4);
    float* csh     = (float*)alloc((size_t)N_EDGES * 16 * 4);
    f16x2* chidh0  = (f16x2*)alloc((size_t)N_EDGES * 8 * 4);
    f16x2* chidh1  = (f16x2*)alloc((size_t)N_EDGES * 8 * 4);
    float* hup     = (float*)alloc((size_t)N_NODES * C * 4);
    half_t* hh     = (half_t*)alloc((size_t)N_NODES * C * 2);
    half_t* aggh   = (half_t*)alloc((size_t)N_NODES * CSH * 2);

    hipMemsetAsync(cnt, 0, 4, stream);
    hipMemsetAsync(deg, 0, (size_t)N_NODES * 4, stream);

    k_edge<<<(N_NODES * C) / 256, 256, 0, stream>>>(pos, shifts, ei, na, We, ae,
                                                    cnt, deg, act_snd, act_rcv,
                                                    act_u, act_ef, hh, out);
    k_scan<<<1, 256, 0, stream>>>(deg, rowptr, cursor);
    k_rank<<<N_EDGES / 256, 256, 0, stream>>>(cnt, act_rcv, Wr2, Wmix, Wself, Wup,
                                              rowptr, cursor, wstart, wlth,
                                              wmixf, wupf, perm);
    k_permute<<<N_EDGES / 256, 256, 0, stream>>>(cnt, perm, act_snd, act_rcv,
                                                 act_u, act_ef, Wr1,
                                                 csnd, crcv, csh, chidh0, chidh1);
    k_upm<<<N_NODES / 16, 64, 0, stream>>>(hh, wupf, hup);

    // ---- layer t = 0 ----
    k_msg5<<<GRID_MSG, 256, 0, stream>>>(rowptr, wstart, csnd, crcv, csh,
                                         chidh0, wlth, hup, aggh);
    k_mixm<0><<<N_NODES / 16, 64, 0, stream>>>(aggh, hh, wmixf, wupf + 512,
                                               wread, Wm1, wm2,
                                               hup, out + N_NODES);

    // ---- layer t = 1 ----
    k_msg5<<<GRID_MSG, 256, 0, stream>>>(rowptr, wstart, csnd, crcv, csh,
                                         chidh1, wlth + 8 * CSH, hup, aggh);
    k_mixm<1><<<N_NODES / 16, 64, 0, stream>>>(aggh, hh, wmixf + 5120, wupf + 512,
                                               wread, Wm1, wm2,
                                               hup, out + 2 * N_NODES);
}

// Round 14
// 124.896 us; speedup vs baseline: 2.6112x; 1.0801x over previous
//
#include <hip/hip_runtime.h>
#include <math.h>

#define N_NODES 10000
#define N_EDGES 160000
#define NEL 10
#define C 64
#define NB 8
#define SHD 9
#define MLPH 16
#define CSH 576
#define R_MAX 5.0f
#define INV_AVG 0.03125f
#define SCAN_CH 40     // 256*40 = 10240 >= N_NODES
#define WBASE (N_EDGES - 2 * 8 * CSH)   // wlth side-job region in k_rank
#define WB2   (WBASE - 10240)           // wmixf side-job region
#define WB3   (WB2 - 1024)              // wupf (BOTH layers' Wup fragments)
#define ROWP  584                       // f16 row pitch of LDS agg tile (bank-safe)

typedef _Float16 f16x2 __attribute__((ext_vector_type(2)));
typedef _Float16 f16x8 __attribute__((ext_vector_type(8)));
typedef float    f32x4 __attribute__((ext_vector_type(4)));
typedef _Float16 half_t;

__device__ __forceinline__ float silu_f(float v) {
    return v / (1.0f + __expf(-v));
}

__device__ __forceinline__ float dot2f(f16x2 a, f16x2 b, float c) {
#if __has_builtin(__builtin_amdgcn_fdot2)
    return __builtin_amdgcn_fdot2(a, b, c, false);
#else
    return c + (float)a.x * (float)b.x + (float)a.y * (float)b.y;
#endif
}

// ---------------------------------------------------------------------------
// K1: per-edge geometry + radial basis + active-edge compaction + degree
// histogram + fused embed (h as f16 only).
// ---------------------------------------------------------------------------
__global__ __launch_bounds__(256) void k_edge(
    const float* __restrict__ pos, const float* __restrict__ shifts,
    const int* __restrict__ ei,
    const float* __restrict__ na, const float* __restrict__ We,
    const float* __restrict__ ae,
    int* __restrict__ cnt, int* __restrict__ deg,
    int* __restrict__ act_snd, int* __restrict__ act_rcv,
    float* __restrict__ act_u, float* __restrict__ act_ef,
    half_t* __restrict__ hh, float* __restrict__ out)
{
    int i = blockIdx.x * 256 + threadIdx.x;
    int lane = threadIdx.x & 63;

    // ---- embed: h = na @ We ; out = na @ ae ----
    {
        int n = i >> 6;
        float acc = 0.0f, e0 = 0.0f;
        #pragma unroll
        for (int k = 0; k < NEL; k++) {
            float a = na[n * NEL + k];
            acc += a * We[k * C + lane];
            e0 += a * ae[k];
        }
        hh[i] = (half_t)acc;
        if (lane == 0) out[n] = e0;
    }

    if (blockIdx.x >= N_EDGES / 256) return;
    int e = i;
    int snd = ei[e];
    int rcv = ei[N_EDGES + e];
    float vx = pos[rcv * 3 + 0] - pos[snd * 3 + 0] + shifts[e * 3 + 0];
    float vy = pos[rcv * 3 + 1] - pos[snd * 3 + 1] + shifts[e * 3 + 1];
    float vz = pos[rcv * 3 + 2] - pos[snd * 3 + 2] + shifts[e * 3 + 2];
    float r = sqrtf(vx * vx + vy * vy + vz * vz) + 1e-9f;
    float x = r / R_MAX;
    bool active = x < 1.0f;

    unsigned long long m = __ballot(active);
    int base = 0;
    if (m) {
        int leader = __ffsll((unsigned long long)m) - 1;
        if (lane == leader) base = atomicAdd(cnt, __popcll(m));
        base = __shfl(base, leader);
    }
    if (!active) return;

    int p = base + __popcll(m & ((1ull << lane) - 1ull));
    act_snd[p] = snd;
    act_rcv[p] = rcv;
    atomicAdd(&deg[rcv], 1);

    float inv_r = 1.0f / r;
    *(float4*)&act_u[p * 4] = make_float4(vx * inv_r, vy * inv_r, vz * inv_r, r);

    float x6 = x * x * x; x6 = x6 * x6;
    float x7 = x6 * x;
    float x8 = x7 * x;
    float fc = 1.0f - 28.0f * x6 + 48.0f * x7 - 21.0f * x8;
    float theta = 3.14159265358979323846f * r / R_MAX;
    float s1 = sinf(theta), c1 = cosf(theta);
    float sn = s1, cn = c1;
    float scale = 0.6324555320336759f * inv_r * fc;   // sqrt(2/R_MAX)/r*fc
    float ef[NB];
    ef[0] = scale * sn;
    #pragma unroll
    for (int n = 1; n < NB; n++) {
        float sn1 = sn * c1 + cn * s1;
        float cn1 = cn * c1 - sn * s1;
        sn = sn1; cn = cn1;
        ef[n] = scale * sn;
    }
    *(float4*)&act_ef[p * 8 + 0] = make_float4(ef[0], ef[1], ef[2], ef[3]);
    *(float4*)&act_ef[p * 8 + 4] = make_float4(ef[4], ef[5], ef[6], ef[7]);
}

// ---------------------------------------------------------------------------
// K1b: exclusive scan of deg -> rowptr + cursor (single block, LDS-staged)
// ---------------------------------------------------------------------------
__global__ __launch_bounds__(256) void k_scan(
    const int* __restrict__ deg, int* __restrict__ rowptr, int* __restrict__ cursor)
{
    __shared__ int dl[N_NODES];   // 40 KB
    __shared__ int part[256];
    int tid = threadIdx.x;
    for (int i = tid; i < N_NODES; i += 256) dl[i] = deg[i];
    __syncthreads();

    int base = tid * SCAN_CH;
    int s = 0;
    #pragma unroll 8
    for (int i = 0; i < SCAN_CH; i++) {
        int idx = base + i;
        if (idx < N_NODES) s += dl[idx];
    }
    part[tid] = s;
    __syncthreads();
    for (int off = 1; off < 256; off <<= 1) {
        int v = (tid >= off) ? part[tid - off] : 0;
        __syncthreads();
        part[tid] += v;
        __syncthreads();
    }
    int run = part[tid] - s;
    for (int i = 0; i < SCAN_CH; i++) {
        int idx = base + i;
        if (idx < N_NODES) {
            int v = dl[idx];
            dl[idx] = run;
            run += v;
        }
    }
    __syncthreads();
    for (int i = tid; i < N_NODES; i += 256) {
        int r = dl[i];
        rowptr[i] = r;
        cursor[i] = r;
    }
    if (tid == 255) rowptr[N_NODES] = part[255];
}

// ---------------------------------------------------------------------------
// K1c: rank edges into CSR order (4B scatter) + side jobs:
//  wlth (f16x2 Wr2), wmixf (MFMA B-frags [Wmix/32;Wself]),
//  wupf (MFMA B-frags of BOTH layers' Wup)
// ---------------------------------------------------------------------------
__global__ __launch_bounds__(256) void k_rank(
    const int* __restrict__ cnt, const int* __restrict__ act_rcv,
    const float* __restrict__ Wr2, const float* __restrict__ Wmix,
    const float* __restrict__ Wself, const float* __restrict__ Wup,
    int* __restrict__ cursor, f16x2* __restrict__ wlth,
    f16x8* __restrict__ wmixf, f16x8* __restrict__ wupf, int* __restrict__ perm)
{
    int i = blockIdx.x * 256 + threadIdx.x;
    int nAct = *cnt;

    if (i >= WBASE) {
        int idx = i - WBASE;                  // 0 .. 9215
        int t = idx / (8 * CSH);
        int r = idx - t * (8 * CSH);
        int mq = r / CSH, j = r - mq * CSH;
        int c = j & 63, s = j >> 6;
        float lo = Wr2[t * MLPH * CSH + (2 * mq + 0) * CSH + c * SHD + s];
        float hi = Wr2[t * MLPH * CSH + (2 * mq + 1) * CSH + c * SHD + s];
        f16x2 v; v.x = (_Float16)lo; v.y = (_Float16)hi;
        wlth[idx] = v;
    } else if (i >= WB2) {
        int idx = i - WB2;                    // 0 .. 10239
        int t = idx / 5120;
        int r = idx - t * 5120;
        int ks = r >> 8;                      // 0..19
        int rr = r & 255;
        int nt = rr >> 6;                     // 0..3
        int ln = rr & 63;
        f16x8 v;
        #pragma unroll
        for (int e = 0; e < 8; e++) {
            int k = ks * 32 + ((ln >> 4) << 3) + e;
            int col = nt * 16 + (ln & 15);
            float x;
            if (k < CSH)
                x = Wmix[(size_t)t * CSH * C + ((k & 63) * SHD + (k >> 6)) * C + col] * INV_AVG;
            else
                x = Wself[(size_t)t * C * C + (k - CSH) * C + col];
            v[e] = (_Float16)x;
        }
        wmixf[(size_t)((t * 20 + ks) * 4 + nt) * 64 + ln] = v;
    } else if (i >= WB3) {
        int idx = i - WB3;                    // 0 .. 1023
        int t = idx >> 9;                     // layer
        int r = idx & 511;
        int ks = r >> 8;                      // 0..1
        int rr = r & 255;
        int nt = rr >> 6;
        int ln = rr & 63;
        f16x8 v;
        #pragma unroll
        for (int e = 0; e < 8; e++) {
            int k = ks * 32 + ((ln >> 4) << 3) + e;
            int col = nt * 16 + (ln & 15);
            v[e] = (_Float16)Wup[(size_t)t * C * C + k * C + col];
        }
        wupf[(size_t)((t * 2 + ks) * 4 + nt) * 64 + ln] = v;
    }
    if (i >= nAct) return;
    int pos = atomicAdd(&cursor[act_rcv[i]], 1);
    perm[pos] = i;
}

// ---------------------------------------------------------------------------
// K1d: permute payloads into CSR order: gathered reads, COALESCED writes.
// ---------------------------------------------------------------------------
__global__ __launch_bounds__(256) void k_permute(
    const int* __restrict__ cnt, const int* __restrict__ perm,
    const int* __restrict__ act_snd, const int* __restrict__ act_rcv,
    const float* __restrict__ act_u, const float* __restrict__ act_ef,
    const float* __restrict__ Wr1,
    int* __restrict__ csnd, int* __restrict__ crcv, float* __restrict__ csh,
    f16x2* __restrict__ chidh0, f16x2* __restrict__ chidh1)
{
    int p = blockIdx.x * 256 + threadIdx.x;
    if (p >= *cnt) return;
    int i = perm[p];

    csnd[p] = act_snd[i];
    crcv[p] = act_rcv[i];

    float4 u4 = *(const float4*)&act_u[i * 4];
    float ux = u4.x, uy = u4.y, uz = u4.z;
    const float s3 = 1.7320508075688772f;
    const float s5 = 2.23606797749979f;
    const float s15 = 3.872983346207417f;
    *(float4*)&csh[p * 16 + 0] = make_float4(1.0f, s3 * ux, s3 * uy, s3 * uz);
    *(float4*)&csh[p * 16 + 4] = make_float4(s15 * ux * uy, s15 * uy * uz,
                                             0.5f * s5 * (3.0f * uz * uz - 1.0f),
                                             s15 * ux * uz);
    csh[p * 16 + 8] = 0.5f * s15 * (ux * ux - uy * uy);

    float4 e0 = *(const float4*)&act_ef[i * 8 + 0];
    float4 e1 = *(const float4*)&act_ef[i * 8 + 4];
    float ef[NB] = {e0.x, e0.y, e0.z, e0.w, e1.x, e1.y, e1.z, e1.w};

    #pragma unroll
    for (int t = 0; t < 2; t++) {
        f16x2* dst = (t == 0) ? chidh0 : chidh1;
        const float* W = Wr1 + t * NB * MLPH;
        f16x2 hv2[8];
        #pragma unroll
        for (int mp = 0; mp < 8; mp++) {
            float a0 = 0.0f, a1 = 0.0f;
            #pragma unroll
            for (int b = 0; b < NB; b++) {
                float efb = ef[b];
                a0 += efb * W[b * MLPH + 2 * mp + 0];
                a1 += efb * W[b * MLPH + 2 * mp + 1];
            }
            f16x2 v; v.x = (_Float16)silu_f(a0); v.y = (_Float16)silu_f(a1);
            hv2[mp] = v;
        }
        *(float4*)&dst[p * 8 + 0] = *(float4*)&hv2[0];
        *(float4*)&dst[p * 8 + 4] = *(float4*)&hv2[4];
    }
}

// ---------------------------------------------------------------------------
// K2: hup = hh @ Wup[0] via MFMA (one wave per 16 nodes, 8 MFMAs)
// ---------------------------------------------------------------------------
__global__ __launch_bounds__(64) void k_upm(
    const half_t* __restrict__ hh, const f16x8* __restrict__ wupf,
    float* __restrict__ hup)
{
    int lane = threadIdx.x & 63;
    int base = blockIdx.x * 16;
    int rowA = base + (lane & 15);
    int kg = (lane >> 4) << 3;

    f32x4 u0 = {0.f,0.f,0.f,0.f}, u1 = {0.f,0.f,0.f,0.f};
    f32x4 u2 = {0.f,0.f,0.f,0.f}, u3 = {0.f,0.f,0.f,0.f};
    const half_t* hrow = hh + (size_t)rowA * C + kg;
    #pragma unroll
    for (int ks = 0; ks < 2; ks++) {
        f16x8 a = *(const f16x8*)(hrow + ks * 32);
        const f16x8* bp = wupf + (size_t)(ks * 4) * 64 + lane;
        u0 = __builtin_amdgcn_mfma_f32_16x16x32_f16(a, bp[0],   u0, 0, 0, 0);
        u1 = __builtin_amdgcn_mfma_f32_16x16x32_f16(a, bp[64],  u1, 0, 0, 0);
        u2 = __builtin_amdgcn_mfma_f32_16x16x32_f16(a, bp[128], u2, 0, 0, 0);
        u3 = __builtin_amdgcn_mfma_f32_16x16x32_f16(a, bp[192], u3, 0, 0, 0);
    }
    int colb = lane & 15;
    int rowb = base + ((lane >> 4) << 2);
    #pragma unroll
    for (int r = 0; r < 4; r++) {
        float* hp = hup + (size_t)(rowb + r) * C + colb;
        hp[0]  = u0[r];
        hp[16] = u1[r];
        hp[32] = u2[r];
        hp[48] = u3[r];
    }
}

// ---------------------------------------------------------------------------
// K3 (fused msg+mix): block = 16 nodes = one MFMA tile; wave w owns nodes
// [bbase+4w, bbase+4w+4) and streams their CSR edges with register-W
// (zero atomics/shuffles/LDS-W), accumulating agg rows into an LDS f16
// tile (row pitch 584: 2-way bank-free MFMA A-reads). Then the 4 waves
// each take one 16-col MFMA tile of hnew = [agg|hh] @ [Wmix/32;Wself].
// RMODE 0: epilogue rep1 + hh=f16(hnew) + hup_out = hnew @ Wup[1].
// RMODE 1: epilogue rep2 = silu(hnew @ Wm1).wm2.
// ---------------------------------------------------------------------------
template <int RMODE>
__global__ __launch_bounds__(256) void k_fuse(
    const int* __restrict__ rowptr, const int* __restrict__ csnd,
    const int* __restrict__ crcv, const float* __restrict__ csh,
    const f16x2* __restrict__ chh, const f16x2* __restrict__ wlth,
    const float* __restrict__ hup_in, const f16x8* __restrict__ wf,
    const f16x8* __restrict__ wupf1, half_t* __restrict__ hh,
    const float* __restrict__ wread, const float* __restrict__ Wm1,
    const float* __restrict__ wm2,
    float* __restrict__ hup_out, float* __restrict__ rep)
{
    __shared__ half_t Hs[16 * ROWP];   // 18688 B: f16 agg tile
    __shared__ half_t Hs2[16 * 72];    // 2304 B: f16 hnew tile (RMODE0)

    int lane = threadIdx.x & 63;
    int w = threadIdx.x >> 6;
    int bbase = blockIdx.x * 16;
    int n0 = bbase + w * 4;
    int beg = rowptr[n0], end = rowptr[n0 + 4];

    // per-lane W working set: 72 f16x2 in registers
    f16x2 wreg[8][9];
    #pragma unroll
    for (int mq = 0; mq < 8; mq++)
        #pragma unroll
        for (int jj = 0; jj < 9; jj++)
            wreg[mq][jj] = wlth[mq * CSH + (jj << 6) + lane];

    float acc[9];
    int curRcv = -1;

#define FLUSH() { half_t* ag = &Hs[(curRcv - bbase) * ROWP + lane]; \
    _Pragma("unroll") for (int jj = 0; jj < 9; jj++) ag[jj << 6] = (half_t)acc[jj]; }
#define ZFILL(FROM, TO) for (int zn = (FROM); zn < (TO); zn++) { \
    half_t* ag = &Hs[(zn - bbase) * ROWP + lane]; \
    _Pragma("unroll") for (int jj = 0; jj < 9; jj++) ag[jj << 6] = (half_t)0.0f; }

    for (int k0 = beg; k0 < end; k0 += 4) {
        int nv = end - k0; if (nv > 4) nv = 4;

#define PRE(Q) int kc##Q = (k0 + Q < end) ? k0 + Q : end - 1; \
        int rcvq##Q = crcv[kc##Q]; \
        float hupq##Q = hup_in[csnd[kc##Q] * C + lane];
        PRE(0) PRE(1) PRE(2) PRE(3)
#undef PRE

        float tw0[9], tw1[9], tw2[9], tw3[9];
        #pragma unroll
        for (int jj = 0; jj < 9; jj++) {
            tw0[jj] = 0.f; tw1[jj] = 0.f; tw2[jj] = 0.f; tw3[jj] = 0.f;
        }

        #pragma unroll
        for (int mq = 0; mq < 8; mq++) {
            f16x2 h0 = chh[kc0 * 8 + mq], h1 = chh[kc1 * 8 + mq];
            f16x2 h2 = chh[kc2 * 8 + mq], h3 = chh[kc3 * 8 + mq];
            #pragma unroll
            for (int jj = 0; jj < 9; jj++) {
                f16x2 wv = wreg[mq][jj];
                tw0[jj] = dot2f(h0, wv, tw0[jj]);
                tw1[jj] = dot2f(h1, wv, tw1[jj]);
                tw2[jj] = dot2f(h2, wv, tw2[jj]);
                tw3[jj] = dot2f(h3, wv, tw3[jj]);
            }
        }

#define SCAT(Q) if (Q < nv) { \
        int rcv = rcvq##Q; \
        float hupS = hupq##Q; \
        float4 sA = *(const float4*)&csh[kc##Q * 16]; \
        float4 sB = *(const float4*)&csh[kc##Q * 16 + 4]; \
        float s8v = csh[kc##Q * 16 + 8]; \
        float sh9[9] = {sA.x, sA.y, sA.z, sA.w, sB.x, sB.y, sB.z, sB.w, s8v}; \
        if (rcv != curRcv) { \
            if (curRcv >= 0) { FLUSH(); ZFILL(curRcv + 1, rcv) } else { ZFILL(n0, rcv) } \
            curRcv = rcv; \
            _Pragma("unroll") for (int jj = 0; jj < 9; jj++) acc[jj] = tw##Q[jj] * (hupS * sh9[jj]); \
        } else { \
            _Pragma("unroll") for (int jj = 0; jj < 9; jj++) acc[jj] += tw##Q[jj] * (hupS * sh9[jj]); \
        } }
        SCAT(0) SCAT(1) SCAT(2) SCAT(3)
#undef SCAT
    }

    int zfrom = n0;
    if (curRcv >= 0) { FLUSH(); zfrom = curRcv + 1; }
    ZFILL(zfrom, n0 + 4)
#undef FLUSH
#undef ZFILL

    __syncthreads();

    // ---- mix MFMA: wave w -> column tile nt = w ----
    int rowL = lane & 15;
    int kg = (lane >> 4) << 3;
    f32x4 acc4 = {0.f, 0.f, 0.f, 0.f};
    const half_t* hrow = hh + (size_t)(bbase + rowL) * C + kg;
    #pragma unroll
    for (int ks = 0; ks < 20; ks++) {
        f16x8 a = (ks < 18) ? *(const f16x8*)&Hs[rowL * ROWP + ks * 32 + kg]
                            : *(const f16x8*)(hrow + (ks - 18) * 32);
        f16x8 b = wf[(size_t)(ks * 4 + w) * 64 + lane];
        acc4 = __builtin_amdgcn_mfma_f32_16x16x32_f16(a, b, acc4, 0, 0, 0);
    }

    int colb = lane & 15;
    int rq = (lane >> 4) << 2;   // local C/D row base

    __syncthreads();   // all Hs/hh A-reads done before epilogue writes

    if (RMODE == 0) {
        // stage f16 hnew col-slice
        #pragma unroll
        for (int r = 0; r < 4; r++)
            Hs2[(rq + r) * 72 + w * 16 + colb] = (half_t)acc4[r];
        __syncthreads();

        // rep1 by wave 0: lane = seg*16 + row
        if (w == 0) {
            int row = lane & 15, seg = lane >> 4;
            float v = 0.0f;
            #pragma unroll
            for (int j = 0; j < 16; j++)
                v += (float)Hs2[row * 72 + seg * 16 + j] * wread[seg * 16 + j];
            v += __shfl_xor(v, 16);
            v += __shfl_xor(v, 32);
            if (seg == 0) rep[bbase + row] = v;
        }

        // hh (next layer) coalesced copy out
        {
            int idx = threadIdx.x;
            if (idx < 128) {
                int row = idx >> 3, cq = idx & 7;
                *(float4*)&hh[(size_t)(bbase + row) * C + cq * 8] =
                    *(const float4*)&Hs2[row * 72 + cq * 8];
            }
        }

        // hup_out = hnew @ Wup[1]; wave w -> col tile w
        f32x4 u = {0.f, 0.f, 0.f, 0.f};
        #pragma unroll
        for (int ks = 0; ks < 2; ks++) {
            f16x8 a = *(const f16x8*)&Hs2[rowL * 72 + ks * 32 + kg];
            f16x8 b = wupf1[(size_t)(ks * 4 + w) * 64 + lane];
            u = __builtin_amdgcn_mfma_f32_16x16x32_f16(a, b, u, 0, 0, 0);
        }
        #pragma unroll
        for (int r = 0; r < 4; r++)
            hup_out[(size_t)(bbase + rq + r) * C + w * 16 + colb] = u[r];
    } else {
        // reuse Hs space: Hn f32 [16][68] + W1l [64][16]
        float* Hn = (float*)Hs;
        float* W1l = (float*)Hs + 16 * 68;
        for (int t = threadIdx.x; t < C * MLPH; t += 256) W1l[t] = Wm1[t];
        #pragma unroll
        for (int r = 0; r < 4; r++)
            Hn[(rq + r) * 68 + w * 16 + colb] = acc4[r];
        __syncthreads();

        int n = threadIdx.x >> 4, m = threadIdx.x & 15;
        float a2 = 0.0f;
        #pragma unroll 8
        for (int c = 0; c < C; c++) a2 += Hn[n * 68 + c] * W1l[c * MLPH + m];
        float rv = silu_f(a2) * wm2[m];
        rv += __shfl_xor(rv, 1); rv += __shfl_xor(rv, 2);
        rv += __shfl_xor(rv, 4); rv += __shfl_xor(rv, 8);
        if (m == 0) rep[bbase + n] = rv;
    }
}

// ---------------------------------------------------------------------------
extern "C" void kernel_launch(void* const* d_in, const int* in_sizes, int n_in,
                              void* d_out, int out_size, void* d_ws, size_t ws_size,
                              hipStream_t stream) {
    const float* pos    = (const float*)d_in[0];
    const float* na     = (const float*)d_in[1];
    const float* shifts = (const float*)d_in[2];
    const int*   ei     = (const int*)d_in[3];
    const float* ae     = (const float*)d_in[4];
    const float* We     = (const float*)d_in[5];
    const float* Wup    = (const float*)d_in[6];
    const float* Wr1    = (const float*)d_in[7];
    const float* Wr2    = (const float*)d_in[8];
    const float* Wmix   = (const float*)d_in[9];
    const float* Wself  = (const float*)d_in[10];
    const float* wread  = (const float*)d_in[11];
    const float* Wm1    = (const float*)d_in[12];
    const float* wm2    = (const float*)d_in[13];
    float* out = (float*)d_out;

    char* ws = (char*)d_ws;
    size_t off = 0;
    auto alloc = [&](size_t bytes) {
        off = (off + 255) & ~(size_t)255;
        void* p = ws + off;
        off += bytes;
        return p;
    };
    int*   cnt     = (int*)alloc(4);
    int*   deg     = (int*)alloc((size_t)N_NODES * 4);
    int*   rowptr  = (int*)alloc((size_t)(N_NODES + 1) * 4);
    int*   cursor  = (int*)alloc((size_t)N_NODES * 4);
    f16x2* wlth    = (f16x2*)alloc((size_t)2 * 8 * CSH * 4);
    f16x8* wmixf   = (f16x8*)alloc((size_t)2 * 5120 * 16);
    f16x8* wupf    = (f16x8*)alloc((size_t)1024 * 16);
    int*   perm    = (int*)alloc((size_t)N_EDGES * 4);
    int*   act_snd = (int*)alloc((size_t)N_EDGES * 4);
    int*   act_rcv = (int*)alloc((size_t)N_EDGES * 4);
    float* act_u   = (float*)alloc((size_t)N_EDGES * 4 * 4);
    float* act_ef  = (float*)alloc((size_t)N_EDGES * 8 * 4);
    int*   csnd    = (int*)alloc((size_t)N_EDGES * 4);
    int*   crcv    = (int*)alloc((size_t)N_EDGES * 4);
    float* csh     = (float*)alloc((size_t)N_EDGES * 16 * 4);
    f16x2* chidh0  = (f16x2*)alloc((size_t)N_EDGES * 8 * 4);
    f16x2* chidh1  = (f16x2*)alloc((size_t)N_EDGES * 8 * 4);
    float* hup     = (float*)alloc((size_t)N_NODES * C * 4);
    float* hup2    = (float*)alloc((size_t)N_NODES * C * 4);
    half_t* hh     = (half_t*)alloc((size_t)N_NODES * C * 2);

    hipMemsetAsync(cnt, 0, 4, stream);
    hipMemsetAsync(deg, 0, (size_t)N_NODES * 4, stream);

    k_edge<<<(N_NODES * C) / 256, 256, 0, stream>>>(pos, shifts, ei, na, We, ae,
                                                    cnt, deg, act_snd, act_rcv,
                                                    act_u, act_ef, hh, out);
    k_scan<<<1, 256, 0, stream>>>(deg, rowptr, cursor);
    k_rank<<<N_EDGES / 256, 256, 0, stream>>>(cnt, act_rcv, Wr2, Wmix, Wself, Wup,
                                              cursor, wlth, wmixf, wupf, perm);
    k_permute<<<N_EDGES / 256, 256, 0, stream>>>(cnt, perm, act_snd, act_rcv,
                                                 act_u, act_ef, Wr1,
                                                 csnd, crcv, csh, chidh0, chidh1);
    k_upm<<<N_NODES / 16, 64, 0, stream>>>(hh, wupf, hup);

    // ---- layer t = 0 (fused msg+mix; epilogue: rep1, hh, hup2) ----
    k_fuse<0><<<N_NODES / 16, 256, 0, stream>>>(rowptr, csnd, crcv, csh,
                                                chidh0, wlth, hup,
                                                wmixf, wupf + 512, hh,
                                                wread, Wm1, wm2,
                                                hup2, out + N_NODES);

    // ---- layer t = 1 (fused msg+mix; epilogue: rep2) ----
    k_fuse<1><<<N_NODES / 16, 256, 0, stream>>>(rowptr, csnd, crcv, csh,
                                                chidh1, wlth + 8 * CSH, hup2,
                                                wmixf + 5120, wupf + 512, hh,
                                                wread, Wm1, wm2,
                                                hup, out + 2 * N_NODES);
}

// Round 15
// 123.386 us; speedup vs baseline: 2.6432x; 1.0122x over previous
//
#include <hip/hip_runtime.h>
#include <math.h>

#define N_NODES 10000
#define N_EDGES 160000
#define NEL 10
#define C 64
#define NB 8
#define SHD 9
#define MLPH 16
#define CSH 576
#define R_MAX 5.0f
#define INV_AVG 0.03125f
#define SCAN_CH 40     // 256*40 = 10240 >= N_NODES
#define WBASE (N_EDGES - 2 * 8 * CSH)   // wlth side-job region in k_rank
#define WB2   (WBASE - 10240)           // wmixf side-job region
#define WB3   (WB2 - 1024)              // wupf (BOTH layers' Wup fragments)
#define ROWP  584                       // f16 row pitch of LDS agg tile (bank-safe)

typedef _Float16 f16x2 __attribute__((ext_vector_type(2)));
typedef _Float16 f16x8 __attribute__((ext_vector_type(8)));
typedef float    f32x4 __attribute__((ext_vector_type(4)));
typedef _Float16 half_t;

__device__ __forceinline__ float silu_f(float v) {
    return v / (1.0f + __expf(-v));
}

__device__ __forceinline__ float dot2f(f16x2 a, f16x2 b, float c) {
#if __has_builtin(__builtin_amdgcn_fdot2)
    return __builtin_amdgcn_fdot2(a, b, c, false);
#else
    return c + (float)a.x * (float)b.x + (float)a.y * (float)b.y;
#endif
}

// ---------------------------------------------------------------------------
// K0: zero cnt + deg (replaces two hipMemsetAsync graph nodes that each
// cost ~40 us in graph replay per rocprof)
// ---------------------------------------------------------------------------
__global__ __launch_bounds__(256) void k_zero(
    int* __restrict__ cnt, int* __restrict__ deg)
{
    int i = blockIdx.x * 256 + threadIdx.x;
    if (i == 0) *cnt = 0;
    if (i < N_NODES) deg[i] = 0;
}

// ---------------------------------------------------------------------------
// K1: per-edge geometry + radial basis + active-edge compaction + degree
// histogram + fused embed (h as f16 only).
// ---------------------------------------------------------------------------
__global__ __launch_bounds__(256) void k_edge(
    const float* __restrict__ pos, const float* __restrict__ shifts,
    const int* __restrict__ ei,
    const float* __restrict__ na, const float* __restrict__ We,
    const float* __restrict__ ae,
    int* __restrict__ cnt, int* __restrict__ deg,
    int* __restrict__ act_snd, int* __restrict__ act_rcv,
    float* __restrict__ act_u, float* __restrict__ act_ef,
    half_t* __restrict__ hh, float* __restrict__ out)
{
    int i = blockIdx.x * 256 + threadIdx.x;
    int lane = threadIdx.x & 63;

    // ---- embed: h = na @ We ; out = na @ ae ----
    {
        int n = i >> 6;
        float acc = 0.0f, e0 = 0.0f;
        #pragma unroll
        for (int k = 0; k < NEL; k++) {
            float a = na[n * NEL + k];
            acc += a * We[k * C + lane];
            e0 += a * ae[k];
        }
        hh[i] = (half_t)acc;
        if (lane == 0) out[n] = e0;
    }

    if (blockIdx.x >= N_EDGES / 256) return;
    int e = i;
    int snd = ei[e];
    int rcv = ei[N_EDGES + e];
    float vx = pos[rcv * 3 + 0] - pos[snd * 3 + 0] + shifts[e * 3 + 0];
    float vy = pos[rcv * 3 + 1] - pos[snd * 3 + 1] + shifts[e * 3 + 1];
    float vz = pos[rcv * 3 + 2] - pos[snd * 3 + 2] + shifts[e * 3 + 2];
    float r = sqrtf(vx * vx + vy * vy + vz * vz) + 1e-9f;
    float x = r / R_MAX;
    bool active = x < 1.0f;

    unsigned long long m = __ballot(active);
    int base = 0;
    if (m) {
        int leader = __ffsll((unsigned long long)m) - 1;
        if (lane == leader) base = atomicAdd(cnt, __popcll(m));
        base = __shfl(base, leader);
    }
    if (!active) return;

    int p = base + __popcll(m & ((1ull << lane) - 1ull));
    act_snd[p] = snd;
    act_rcv[p] = rcv;
    atomicAdd(&deg[rcv], 1);

    float inv_r = 1.0f / r;
    *(float4*)&act_u[p * 4] = make_float4(vx * inv_r, vy * inv_r, vz * inv_r, r);

    float x6 = x * x * x; x6 = x6 * x6;
    float x7 = x6 * x;
    float x8 = x7 * x;
    float fc = 1.0f - 28.0f * x6 + 48.0f * x7 - 21.0f * x8;
    float theta = 3.14159265358979323846f * r / R_MAX;
    float s1 = sinf(theta), c1 = cosf(theta);
    float sn = s1, cn = c1;
    float scale = 0.6324555320336759f * inv_r * fc;   // sqrt(2/R_MAX)/r*fc
    float ef[NB];
    ef[0] = scale * sn;
    #pragma unroll
    for (int n = 1; n < NB; n++) {
        float sn1 = sn * c1 + cn * s1;
        float cn1 = cn * c1 - sn * s1;
        sn = sn1; cn = cn1;
        ef[n] = scale * sn;
    }
    *(float4*)&act_ef[p * 8 + 0] = make_float4(ef[0], ef[1], ef[2], ef[3]);
    *(float4*)&act_ef[p * 8 + 4] = make_float4(ef[4], ef[5], ef[6], ef[7]);
}

// ---------------------------------------------------------------------------
// K1b: exclusive scan of deg -> rowptr + cursor (single block, LDS-staged)
// ---------------------------------------------------------------------------
__global__ __launch_bounds__(256) void k_scan(
    const int* __restrict__ deg, int* __restrict__ rowptr, int* __restrict__ cursor)
{
    __shared__ int dl[N_NODES];   // 40 KB
    __shared__ int part[256];
    int tid = threadIdx.x;
    for (int i = tid; i < N_NODES; i += 256) dl[i] = deg[i];
    __syncthreads();

    int base = tid * SCAN_CH;
    int s = 0;
    #pragma unroll 8
    for (int i = 0; i < SCAN_CH; i++) {
        int idx = base + i;
        if (idx < N_NODES) s += dl[idx];
    }
    part[tid] = s;
    __syncthreads();
    for (int off = 1; off < 256; off <<= 1) {
        int v = (tid >= off) ? part[tid - off] : 0;
        __syncthreads();
        part[tid] += v;
        __syncthreads();
    }
    int run = part[tid] - s;
    for (int i = 0; i < SCAN_CH; i++) {
        int idx = base + i;
        if (idx < N_NODES) {
            int v = dl[idx];
            dl[idx] = run;
            run += v;
        }
    }
    __syncthreads();
    for (int i = tid; i < N_NODES; i += 256) {
        int r = dl[i];
        rowptr[i] = r;
        cursor[i] = r;
    }
    if (tid == 255) rowptr[N_NODES] = part[255];
}

// ---------------------------------------------------------------------------
// K1c: rank edges into CSR order (4B scatter) + side jobs:
//  wlth (f16x2 Wr2), wmixf (MFMA B-frags [Wmix/32;Wself]),
//  wupf (MFMA B-frags of BOTH layers' Wup)
// ---------------------------------------------------------------------------
__global__ __launch_bounds__(256) void k_rank(
    const int* __restrict__ cnt, const int* __restrict__ act_rcv,
    const float* __restrict__ Wr2, const float* __restrict__ Wmix,
    const float* __restrict__ Wself, const float* __restrict__ Wup,
    int* __restrict__ cursor, f16x2* __restrict__ wlth,
    f16x8* __restrict__ wmixf, f16x8* __restrict__ wupf, int* __restrict__ perm)
{
    int i = blockIdx.x * 256 + threadIdx.x;
    int nAct = *cnt;

    if (i >= WBASE) {
        int idx = i - WBASE;                  // 0 .. 9215
        int t = idx / (8 * CSH);
        int r = idx - t * (8 * CSH);
        int mq = r / CSH, j = r - mq * CSH;
        int c = j & 63, s = j >> 6;
        float lo = Wr2[t * MLPH * CSH + (2 * mq + 0) * CSH + c * SHD + s];
        float hi = Wr2[t * MLPH * CSH + (2 * mq + 1) * CSH + c * SHD + s];
        f16x2 v; v.x = (_Float16)lo; v.y = (_Float16)hi;
        wlth[idx] = v;
    } else if (i >= WB2) {
        int idx = i - WB2;                    // 0 .. 10239
        int t = idx / 5120;
        int r = idx - t * 5120;
        int ks = r >> 8;                      // 0..19
        int rr = r & 255;
        int nt = rr >> 6;                     // 0..3
        int ln = rr & 63;
        f16x8 v;
        #pragma unroll
        for (int e = 0; e < 8; e++) {
            int k = ks * 32 + ((ln >> 4) << 3) + e;
            int col = nt * 16 + (ln & 15);
            float x;
            if (k < CSH)
                x = Wmix[(size_t)t * CSH * C + ((k & 63) * SHD + (k >> 6)) * C + col] * INV_AVG;
            else
                x = Wself[(size_t)t * C * C + (k - CSH) * C + col];
            v[e] = (_Float16)x;
        }
        wmixf[(size_t)((t * 20 + ks) * 4 + nt) * 64 + ln] = v;
    } else if (i >= WB3) {
        int idx = i - WB3;                    // 0 .. 1023
        int t = idx >> 9;                     // layer
        int r = idx & 511;
        int ks = r >> 8;                      // 0..1
        int rr = r & 255;
        int nt = rr >> 6;
        int ln = rr & 63;
        f16x8 v;
        #pragma unroll
        for (int e = 0; e < 8; e++) {
            int k = ks * 32 + ((ln >> 4) << 3) + e;
            int col = nt * 16 + (ln & 15);
            v[e] = (_Float16)Wup[(size_t)t * C * C + k * C + col];
        }
        wupf[(size_t)((t * 2 + ks) * 4 + nt) * 64 + ln] = v;
    }
    if (i >= nAct) return;
    int pos = atomicAdd(&cursor[act_rcv[i]], 1);
    perm[pos] = i;
}

// ---------------------------------------------------------------------------
// K1d: permute payloads into CSR order: gathered reads, COALESCED writes.
// ---------------------------------------------------------------------------
__global__ __launch_bounds__(256) void k_permute(
    const int* __restrict__ cnt, const int* __restrict__ perm,
    const int* __restrict__ act_snd, const int* __restrict__ act_rcv,
    const float* __restrict__ act_u, const float* __restrict__ act_ef,
    const float* __restrict__ Wr1,
    int* __restrict__ csnd, int* __restrict__ crcv, float* __restrict__ csh,
    f16x2* __restrict__ chidh0, f16x2* __restrict__ chidh1)
{
    int p = blockIdx.x * 256 + threadIdx.x;
    if (p >= *cnt) return;
    int i = perm[p];

    csnd[p] = act_snd[i];
    crcv[p] = act_rcv[i];

    float4 u4 = *(const float4*)&act_u[i * 4];
    float ux = u4.x, uy = u4.y, uz = u4.z;
    const float s3 = 1.7320508075688772f;
    const float s5 = 2.23606797749979f;
    const float s15 = 3.872983346207417f;
    *(float4*)&csh[p * 16 + 0] = make_float4(1.0f, s3 * ux, s3 * uy, s3 * uz);
    *(float4*)&csh[p * 16 + 4] = make_float4(s15 * ux * uy, s15 * uy * uz,
                                             0.5f * s5 * (3.0f * uz * uz - 1.0f),
                                             s15 * ux * uz);
    csh[p * 16 + 8] = 0.5f * s15 * (ux * ux - uy * uy);

    float4 e0 = *(const float4*)&act_ef[i * 8 + 0];
    float4 e1 = *(const float4*)&act_ef[i * 8 + 4];
    float ef[NB] = {e0.x, e0.y, e0.z, e0.w, e1.x, e1.y, e1.z, e1.w};

    #pragma unroll
    for (int t = 0; t < 2; t++) {
        f16x2* dst = (t == 0) ? chidh0 : chidh1;
        const float* W = Wr1 + t * NB * MLPH;
        f16x2 hv2[8];
        #pragma unroll
        for (int mp = 0; mp < 8; mp++) {
            float a0 = 0.0f, a1 = 0.0f;
            #pragma unroll
            for (int b = 0; b < NB; b++) {
                float efb = ef[b];
                a0 += efb * W[b * MLPH + 2 * mp + 0];
                a1 += efb * W[b * MLPH + 2 * mp + 1];
            }
            f16x2 v; v.x = (_Float16)silu_f(a0); v.y = (_Float16)silu_f(a1);
            hv2[mp] = v;
        }
        *(float4*)&dst[p * 8 + 0] = *(float4*)&hv2[0];
        *(float4*)&dst[p * 8 + 4] = *(float4*)&hv2[4];
    }
}

// ---------------------------------------------------------------------------
// K2: hup = hh @ Wup[0] via MFMA (one wave per 16 nodes, 8 MFMAs)
// ---------------------------------------------------------------------------
__global__ __launch_bounds__(64) void k_upm(
    const half_t* __restrict__ hh, const f16x8* __restrict__ wupf,
    float* __restrict__ hup)
{
    int lane = threadIdx.x & 63;
    int base = blockIdx.x * 16;
    int rowA = base + (lane & 15);
    int kg = (lane >> 4) << 3;

    f32x4 u0 = {0.f,0.f,0.f,0.f}, u1 = {0.f,0.f,0.f,0.f};
    f32x4 u2 = {0.f,0.f,0.f,0.f}, u3 = {0.f,0.f,0.f,0.f};
    const half_t* hrow = hh + (size_t)rowA * C + kg;
    #pragma unroll
    for (int ks = 0; ks < 2; ks++) {
        f16x8 a = *(const f16x8*)(hrow + ks * 32);
        const f16x8* bp = wupf + (size_t)(ks * 4) * 64 + lane;
        u0 = __builtin_amdgcn_mfma_f32_16x16x32_f16(a, bp[0],   u0, 0, 0, 0);
        u1 = __builtin_amdgcn_mfma_f32_16x16x32_f16(a, bp[64],  u1, 0, 0, 0);
        u2 = __builtin_amdgcn_mfma_f32_16x16x32_f16(a, bp[128], u2, 0, 0, 0);
        u3 = __builtin_amdgcn_mfma_f32_16x16x32_f16(a, bp[192], u3, 0, 0, 0);
    }
    int colb = lane & 15;
    int rowb = base + ((lane >> 4) << 2);
    #pragma unroll
    for (int r = 0; r < 4; r++) {
        float* hp = hup + (size_t)(rowb + r) * C + colb;
        hp[0]  = u0[r];
        hp[16] = u1[r];
        hp[32] = u2[r];
        hp[48] = u3[r];
    }
}

// ---------------------------------------------------------------------------
// K3 (fused msg+mix): block = 16 nodes = one MFMA tile; wave w owns nodes
// [bbase+4w, bbase+4w+4) and streams their CSR edges with register-W,
// accumulating agg rows into an LDS f16 tile. Then 4 waves each take one
// 16-col MFMA tile of hnew = [agg|hh] @ [Wmix/32;Wself].
// RMODE 0: epilogue rep1 + hh=f16(hnew) + hup_out = hnew @ Wup[1].
// RMODE 1: epilogue rep2 = silu(hnew @ Wm1).wm2.
// ---------------------------------------------------------------------------
template <int RMODE>
__global__ __launch_bounds__(256) void k_fuse(
    const int* __restrict__ rowptr, const int* __restrict__ csnd,
    const int* __restrict__ crcv, const float* __restrict__ csh,
    const f16x2* __restrict__ chh, const f16x2* __restrict__ wlth,
    const float* __restrict__ hup_in, const f16x8* __restrict__ wf,
    const f16x8* __restrict__ wupf1, half_t* __restrict__ hh,
    const float* __restrict__ wread, const float* __restrict__ Wm1,
    const float* __restrict__ wm2,
    float* __restrict__ hup_out, float* __restrict__ rep)
{
    __shared__ half_t Hs[16 * ROWP];   // 18688 B: f16 agg tile
    __shared__ half_t Hs2[16 * 72];    // 2304 B: f16 hnew tile (RMODE0)

    int lane = threadIdx.x & 63;
    int w = threadIdx.x >> 6;
    int bbase = blockIdx.x * 16;
    int n0 = bbase + w * 4;
    int beg = rowptr[n0], end = rowptr[n0 + 4];

    // per-lane W working set: 72 f16x2 in registers
    f16x2 wreg[8][9];
    #pragma unroll
    for (int mq = 0; mq < 8; mq++)
        #pragma unroll
        for (int jj = 0; jj < 9; jj++)
            wreg[mq][jj] = wlth[mq * CSH + (jj << 6) + lane];

    float acc[9];
    int curRcv = -1;

#define FLUSH() { half_t* ag = &Hs[(curRcv - bbase) * ROWP + lane]; \
    _Pragma("unroll") for (int jj = 0; jj < 9; jj++) ag[jj << 6] = (half_t)acc[jj]; }
#define ZFILL(FROM, TO) for (int zn = (FROM); zn < (TO); zn++) { \
    half_t* ag = &Hs[(zn - bbase) * ROWP + lane]; \
    _Pragma("unroll") for (int jj = 0; jj < 9; jj++) ag[jj << 6] = (half_t)0.0f; }

    for (int k0 = beg; k0 < end; k0 += 4) {
        int nv = end - k0; if (nv > 4) nv = 4;

#define PRE(Q) int kc##Q = (k0 + Q < end) ? k0 + Q : end - 1; \
        int rcvq##Q = crcv[kc##Q]; \
        float hupq##Q = hup_in[csnd[kc##Q] * C + lane];
        PRE(0) PRE(1) PRE(2) PRE(3)
#undef PRE

        float tw0[9], tw1[9], tw2[9], tw3[9];
        #pragma unroll
        for (int jj = 0; jj < 9; jj++) {
            tw0[jj] = 0.f; tw1[jj] = 0.f; tw2[jj] = 0.f; tw3[jj] = 0.f;
        }

        #pragma unroll
        for (int mq = 0; mq < 8; mq++) {
            f16x2 h0 = chh[kc0 * 8 + mq], h1 = chh[kc1 * 8 + mq];
            f16x2 h2 = chh[kc2 * 8 + mq], h3 = chh[kc3 * 8 + mq];
            #pragma unroll
            for (int jj = 0; jj < 9; jj++) {
                f16x2 wv = wreg[mq][jj];
                tw0[jj] = dot2f(h0, wv, tw0[jj]);
                tw1[jj] = dot2f(h1, wv, tw1[jj]);
                tw2[jj] = dot2f(h2, wv, tw2[jj]);
                tw3[jj] = dot2f(h3, wv, tw3[jj]);
            }
        }

#define SCAT(Q) if (Q < nv) { \
        int rcv = rcvq##Q; \
        float hupS = hupq##Q; \
        float4 sA = *(const float4*)&csh[kc##Q * 16]; \
        float4 sB = *(const float4*)&csh[kc##Q * 16 + 4]; \
        float s8v = csh[kc##Q * 16 + 8]; \
        float sh9[9] = {sA.x, sA.y, sA.z, sA.w, sB.x, sB.y, sB.z, sB.w, s8v}; \
        if (rcv != curRcv) { \
            if (curRcv >= 0) { FLUSH(); ZFILL(curRcv + 1, rcv) } else { ZFILL(n0, rcv) } \
            curRcv = rcv; \
            _Pragma("unroll") for (int jj = 0; jj < 9; jj++) acc[jj] = tw##Q[jj] * (hupS * sh9[jj]); \
        } else { \
            _Pragma("unroll") for (int jj = 0; jj < 9; jj++) acc[jj] += tw##Q[jj] * (hupS * sh9[jj]); \
        } }
        SCAT(0) SCAT(1) SCAT(2) SCAT(3)
#undef SCAT
    }

    int zfrom = n0;
    if (curRcv >= 0) { FLUSH(); zfrom = curRcv + 1; }
    ZFILL(zfrom, n0 + 4)
#undef FLUSH
#undef ZFILL

    __syncthreads();

    // ---- mix MFMA: wave w -> column tile nt = w ----
    int rowL = lane & 15;
    int kg = (lane >> 4) << 3;
    f32x4 acc4 = {0.f, 0.f, 0.f, 0.f};
    const half_t* hrow = hh + (size_t)(bbase + rowL) * C + kg;
    #pragma unroll
    for (int ks = 0; ks < 20; ks++) {
        f16x8 a = (ks < 18) ? *(const f16x8*)&Hs[rowL * ROWP + ks * 32 + kg]
                            : *(const f16x8*)(hrow + (ks - 18) * 32);
        f16x8 b = wf[(size_t)(ks * 4 + w) * 64 + lane];
        acc4 = __builtin_amdgcn_mfma_f32_16x16x32_f16(a, b, acc4, 0, 0, 0);
    }

    int colb = lane & 15;
    int rq = (lane >> 4) << 2;   // local C/D row base

    __syncthreads();   // all Hs/hh A-reads done before epilogue writes

    if (RMODE == 0) {
        // stage f16 hnew col-slice
        #pragma unroll
        for (int r = 0; r < 4; r++)
            Hs2[(rq + r) * 72 + w * 16 + colb] = (half_t)acc4[r];
        __syncthreads();

        // rep1 by wave 0: lane = seg*16 + row
        if (w == 0) {
            int row = lane & 15, seg = lane >> 4;
            float v = 0.0f;
            #pragma unroll
            for (int j = 0; j < 16; j++)
                v += (float)Hs2[row * 72 + seg * 16 + j] * wread[seg * 16 + j];
            v += __shfl_xor(v, 16);
            v += __shfl_xor(v, 32);
            if (seg == 0) rep[bbase + row] = v;
        }

        // hh (next layer) coalesced copy out
        {
            int idx = threadIdx.x;
            if (idx < 128) {
                int row = idx >> 3, cq = idx & 7;
                *(float4*)&hh[(size_t)(bbase + row) * C + cq * 8] =
                    *(const float4*)&Hs2[row * 72 + cq * 8];
            }
        }

        // hup_out = hnew @ Wup[1]; wave w -> col tile w
        f32x4 u = {0.f, 0.f, 0.f, 0.f};
        #pragma unroll
        for (int ks = 0; ks < 2; ks++) {
            f16x8 a = *(const f16x8*)&Hs2[rowL * 72 + ks * 32 + kg];
            f16x8 b = wupf1[(size_t)(ks * 4 + w) * 64 + lane];
            u = __builtin_amdgcn_mfma_f32_16x16x32_f16(a, b, u, 0, 0, 0);
        }
        #pragma unroll
        for (int r = 0; r < 4; r++)
            hup_out[(size_t)(bbase + rq + r) * C + w * 16 + colb] = u[r];
    } else {
        // reuse Hs space: Hn f32 [16][68] + W1l [64][16]
        float* Hn = (float*)Hs;
        float* W1l = (float*)Hs + 16 * 68;
        for (int t = threadIdx.x; t < C * MLPH; t += 256) W1l[t] = Wm1[t];
        #pragma unroll
        for (int r = 0; r < 4; r++)
            Hn[(rq + r) * 68 + w * 16 + colb] = acc4[r];
        __syncthreads();

        int n = threadIdx.x >> 4, m = threadIdx.x & 15;
        float a2 = 0.0f;
        #pragma unroll 8
        for (int c = 0; c < C; c++) a2 += Hn[n * 68 + c] * W1l[c * MLPH + m];
        float rv = silu_f(a2) * wm2[m];
        rv += __shfl_xor(rv, 1); rv += __shfl_xor(rv, 2);
        rv += __shfl_xor(rv, 4); rv += __shfl_xor(rv, 8);
        if (m == 0) rep[bbase + n] = rv;
    }
}

// ---------------------------------------------------------------------------
extern "C" void kernel_launch(void* const* d_in, const int* in_sizes, int n_in,
                              void* d_out, int out_size, void* d_ws, size_t ws_size,
                              hipStream_t stream) {
    const float* pos    = (const float*)d_in[0];
    const float* na     = (const float*)d_in[1];
    const float* shifts = (const float*)d_in[2];
    const int*   ei     = (const int*)d_in[3];
    const float* ae     = (const float*)d_in[4];
    const float* We     = (const float*)d_in[5];
    const float* Wup    = (const float*)d_in[6];
    const float* Wr1    = (const float*)d_in[7];
    const float* Wr2    = (const float*)d_in[8];
    const float* Wmix   = (const float*)d_in[9];
    const float* Wself  = (const float*)d_in[10];
    const float* wread  = (const float*)d_in[11];
    const float* Wm1    = (const float*)d_in[12];
    const float* wm2    = (const float*)d_in[13];
    float* out = (float*)d_out;

    char* ws = (char*)d_ws;
    size_t off = 0;
    auto alloc = [&](size_t bytes) {
        off = (off + 255) & ~(size_t)255;
        void* p = ws + off;
        off += bytes;
        return p;
    };
    int*   cnt     = (int*)alloc(4);
    int*   deg     = (int*)alloc((size_t)N_NODES * 4);
    int*   rowptr  = (int*)alloc((size_t)(N_NODES + 1) * 4);
    int*   cursor  = (int*)alloc((size_t)N_NODES * 4);
    f16x2* wlth    = (f16x2*)alloc((size_t)2 * 8 * CSH * 4);
    f16x8* wmixf   = (f16x8*)alloc((size_t)2 * 5120 * 16);
    f16x8* wupf    = (f16x8*)alloc((size_t)1024 * 16);
    int*   perm    = (int*)alloc((size_t)N_EDGES * 4);
    int*   act_snd = (int*)alloc((size_t)N_EDGES * 4);
    int*   act_rcv = (int*)alloc((size_t)N_EDGES * 4);
    float* act_u   = (float*)alloc((size_t)N_EDGES * 4 * 4);
    float* act_ef  = (float*)alloc((size_t)N_EDGES * 8 * 4);
    int*   csnd    = (int*)alloc((size_t)N_EDGES * 4);
    int*   crcv    = (int*)alloc((size_t)N_EDGES * 4);
    float* csh     = (float*)alloc((size_t)N_EDGES * 16 * 4);
    f16x2* chidh0  = (f16x2*)alloc((size_t)N_EDGES * 8 * 4);
    f16x2* chidh1  = (f16x2*)alloc((size_t)N_EDGES * 8 * 4);
    float* hup     = (float*)alloc((size_t)N_NODES * C * 4);
    float* hup2    = (float*)alloc((size_t)N_NODES * C * 4);
    half_t* hh     = (half_t*)alloc((size_t)N_NODES * C * 2);

    k_zero<<<(N_NODES + 255) / 256, 256, 0, stream>>>(cnt, deg);

    k_edge<<<(N_NODES * C) / 256, 256, 0, stream>>>(pos, shifts, ei, na, We, ae,
                                                    cnt, deg, act_snd, act_rcv,
                                                    act_u, act_ef, hh, out);
    k_scan<<<1, 256, 0, stream>>>(deg, rowptr, cursor);
    k_rank<<<N_EDGES / 256, 256, 0, stream>>>(cnt, act_rcv, Wr2, Wmix, Wself, Wup,
                                              cursor, wlth, wmixf, wupf, perm);
    k_permute<<<N_EDGES / 256, 256, 0, stream>>>(cnt, perm, act_snd, act_rcv,
                                                 act_u, act_ef, Wr1,
                                                 csnd, crcv, csh, chidh0, chidh1);
    k_upm<<<N_NODES / 16, 64, 0, stream>>>(hh, wupf, hup);

    // ---- layer t = 0 (fused msg+mix; epilogue: rep1, hh, hup2) ----
    k_fuse<0><<<N_NODES / 16, 256, 0, stream>>>(rowptr, csnd, crcv, csh,
                                                chidh0, wlth, hup,
                                                wmixf, wupf + 512, hh,
                                                wread, Wm1, wm2,
                                                hup2, out + N_NODES);

    // ---- layer t = 1 (fused msg+mix; epilogue: rep2) ----
    k_fuse<1><<<N_NODES / 16, 256, 0, stream>>>(rowptr, csnd, crcv, csh,
                                                chidh1, wlth + 8 * CSH, hup2,
                                                wmixf + 5120, wupf + 512, hh,
                                                wread, Wm1, wm2,
                                                hup, out + 2 * N_NODES);
}